// Round 11
// baseline (1025.482 us; speedup 1.0000x reference)
//
#include <hip/hip_runtime.h>

#define DEV_INLINE __device__ __forceinline__

typedef short bf16x8 __attribute__((ext_vector_type(8)));
typedef float f32x4 __attribute__((ext_vector_type(4)));
typedef unsigned short u16x8 __attribute__((ext_vector_type(8)));
typedef _Float16 f16x8 __attribute__((ext_vector_type(8)));
typedef _Float16 f16x2 __attribute__((ext_vector_type(2)));

DEV_INLINE float sigmoidf_(float x) { return 1.f / (1.f + __expf(-x)); }
DEV_INLINE unsigned short f2bf(float x) {
    unsigned int u = __float_as_uint(x);
    unsigned int r = (u + 0x7FFFu + ((u >> 16) & 1u)) >> 16;
    return (unsigned short)r;
}
DEV_INLINE float bf2f(unsigned short u) {
    return __uint_as_float(((unsigned int)u) << 16);
}
DEV_INLINE float fdot2_(f16x2 a, f16x2 b, float c) {
#if __has_builtin(__builtin_amdgcn_fdot2)
    return __builtin_amdgcn_fdot2(a, b, c, false);
#else
    return c + (float)a[0] * (float)b[0] + (float)a[1] * (float)b[1];
#endif
}
#define SL(v, k) __builtin_shufflevector(v, v, 2 * (k), 2 * (k) + 1)

// ---------------------------------------------------------------------------
// mega-cast: all fp32->bf16 casts in one launch
// ---------------------------------------------------------------------------
struct CastJobs {
    const float4* src[11];
    ushort4* dst[11];
    int end[11];
};

__global__ __launch_bounds__(256) void cast_all_kernel(CastJobs jobs, int total4)
{
    int gi = blockIdx.x * 256 + threadIdx.x;
    if (gi >= total4) return;
    int s = 0, base = 0;
    while (gi >= jobs.end[s]) { base = jobs.end[s]; s++; }
    int li = gi - base;
    float4 v = jobs.src[s][li];
    ushort4 o = {f2bf(v.x), f2bf(v.y), f2bf(v.z), f2bf(v.w)};
    jobs.dst[s][li] = o;
}

// ---------------------------------------------------------------------------
// bf16 MFMA GEMM (m97 structure)
// ---------------------------------------------------------------------------
template<int ACT, int RES, int WF32, int WBF>
__global__ __launch_bounds__(256) void mfma_gemm(
    const unsigned short* __restrict__ A, const unsigned short* __restrict__ B,
    const float* __restrict__ bias, const float* __restrict__ res,
    float* __restrict__ C, unsigned short* __restrict__ Cb, int M, int N, int K)
{
    __shared__ __align__(16) unsigned short As[128 * 32];
    __shared__ __align__(16) unsigned short Bs[128 * 32];

    const int t = threadIdx.x;
    const int lane = t & 63, wave = t >> 6;
    const int wr = wave >> 1, wc = wave & 1;
    const int lr = lane & 15, lk = lane >> 4;
    const int m0 = blockIdx.y * 128, n0 = blockIdx.x * 128;

    f32x4 acc[4][4] = {};

    for (int k0 = 0; k0 < K; k0 += 32) {
#pragma unroll
        for (int c = 0; c < 2; c++) {
            int bo = t * 16 + c * 4096;
            int row = bo >> 6;
            int col = (bo & 63) >> 1;
            __builtin_amdgcn_global_load_lds(
                (const __attribute__((address_space(1))) void*)(A + (size_t)(m0 + row) * K + k0 + col),
                (__attribute__((address_space(3))) void*)(As + (bo >> 1)), 16, 0, 0);
            __builtin_amdgcn_global_load_lds(
                (const __attribute__((address_space(1))) void*)(B + (size_t)(n0 + row) * K + k0 + col),
                (__attribute__((address_space(3))) void*)(Bs + (bo >> 1)), 16, 0, 0);
        }
        __syncthreads();

        bf16x8 af[4], bfr[4];
#pragma unroll
        for (int mi = 0; mi < 4; mi++)
            af[mi] = *(const bf16x8*)(As + (wr * 64 + mi * 16 + lr) * 32 + lk * 8);
#pragma unroll
        for (int nj = 0; nj < 4; nj++)
            bfr[nj] = *(const bf16x8*)(Bs + (wc * 64 + nj * 16 + lr) * 32 + lk * 8);
#pragma unroll
        for (int mi = 0; mi < 4; mi++)
#pragma unroll
            for (int nj = 0; nj < 4; nj++)
                acc[mi][nj] = __builtin_amdgcn_mfma_f32_16x16x32_bf16(
                    af[mi], bfr[nj], acc[mi][nj], 0, 0, 0);
        __syncthreads();
    }

#pragma unroll
    for (int nj = 0; nj < 4; nj++) {
        int col = n0 + wc * 64 + nj * 16 + lr;
        float bv = bias ? bias[col] : 0.f;
#pragma unroll
        for (int mi = 0; mi < 4; mi++) {
            int row = m0 + wr * 64 + mi * 16 + lk * 4;
#pragma unroll
            for (int j = 0; j < 4; j++) {
                int r = row + j;
                if (r >= M) continue;
                float v = acc[mi][nj][j] + bv;
                if (ACT) v = v * sigmoidf_(v - 1.f);
                size_t off = (size_t)r * N + col;
                if (RES) v += res[off];
                if (WF32) C[off] = v;
                if (WBF) Cb[off] = f2bf(v);
            }
        }
    }
}

// ---------------------------------------------------------------------------
// Split qkv (L,N,768): qu/qv/k -> fp16 (N,H,L,d); v -> bf16 transposed (N,H,d,L)
// ---------------------------------------------------------------------------
__global__ __launch_bounds__(256) void split_kernel(
    const float* __restrict__ qkv,
    const float* __restrict__ pbu, const float* __restrict__ pbv,
    _Float16* __restrict__ quh, _Float16* __restrict__ qvh,
    _Float16* __restrict__ kh, unsigned short* __restrict__ vt)
{
    int idx = blockIdx.x * 256 + threadIdx.x;
    int dd = idx & 31;
    int l  = (idx >> 5) & 1023;
    int nh = idx >> 15;               // n*8+h
    int h  = nh & 7;
    int n  = nh >> 3;
    size_t base = ((size_t)l * 4 + n) * 768 + h * 32 + dd;
    float q = qkv[base];
    quh[idx] = (_Float16)(q + pbu[h * 32 + dd]);
    qvh[idx] = (_Float16)(q + pbv[h * 32 + dd]);
    kh[idx]  = (_Float16)qkv[base + 256];
    vt[(size_t)nh * 32768 + dd * 1024 + l] = f2bf(qkv[base + 512]);
}

// ---------------------------------------------------------------------------
// Repack p (m,h,d) fp32 -> p2 (h,m,d) fp16
// ---------------------------------------------------------------------------
__global__ __launch_bounds__(256) void repack_p_kernel(
    const float* __restrict__ pb, _Float16* __restrict__ p2h)
{
    int idx = blockIdx.x * 256 + threadIdx.x;
    if (idx >= 2047 * 256) return;
    int dd = idx & 31;
    int h  = (idx >> 5) & 7;
    int m  = idx >> 8;
    p2h[((size_t)h * 2047 + m) * 32 + dd] = (_Float16)pb[idx];
}

// ---------------------------------------------------------------------------
// scores_kernel v3 (fp16 fdot2): totb[n,h,i,j] = bf16((ac + bd) * scale)
// ---------------------------------------------------------------------------
__global__ __launch_bounds__(256) void scores_kernel(
    const _Float16* __restrict__ quh, const _Float16* __restrict__ qvh,
    const _Float16* __restrict__ kh, const _Float16* __restrict__ p2h,
    unsigned short* __restrict__ totb)
{
    __shared__ __align__(16) float4 Qu4h[64 * 5];
    __shared__ __align__(16) float4 Qv4h[64 * 5];
    __shared__ __align__(16) float4 K4h[64 * 5];
    __shared__ __align__(16) float4 P4h[127 * 5 + 3];
    __shared__ __align__(16) unsigned short staged[64][72];

    const int t = threadIdx.x;
    const int tx = t & 15, ty = t >> 4;
    const int j0 = blockIdx.x * 64, i0 = blockIdx.y * 64;
    const int nh = blockIdx.z;
    const int h = nh & 7;
    const int m_base = 960 - i0 + j0;   // >= 0 always

    const float4* qug = (const float4*)(quh + ((size_t)nh * 1024 + i0) * 32);
    const float4* qvg = (const float4*)(qvh + ((size_t)nh * 1024 + i0) * 32);
    const float4* kg  = (const float4*)(kh + ((size_t)nh * 1024 + j0) * 32);
    const float4* pg  = (const float4*)(p2h + ((size_t)h * 2047 + m_base) * 32);

    {
        int r = t >> 2, c = t & 3;
        Qu4h[r * 5 + c] = qug[t];
        Qv4h[r * 5 + c] = qvg[t];
        K4h[r * 5 + c]  = kg[t];
    }
#pragma unroll
    for (int cc = 0; cc < 2; cc++) {
        int fi = t + 256 * cc;
        if (fi < 508) {
            int r = fi >> 2, c = fi & 3;
            P4h[r * 5 + c] = pg[fi];
        }
    }
    __syncthreads();

    float acc[4][4] = {};
    const int pbase = 63 + tx - ty;

#pragma unroll
    for (int dg = 0; dg < 4; dg++) {
        f16x8 qu_[4], qv_[4], k_[4], p_[7];
#pragma unroll
        for (int ii = 0; ii < 4; ii++) {
            qu_[ii] = __builtin_bit_cast(f16x8, Qu4h[(ty + 16 * ii) * 5 + dg]);
            qv_[ii] = __builtin_bit_cast(f16x8, Qv4h[(ty + 16 * ii) * 5 + dg]);
        }
#pragma unroll
        for (int jj = 0; jj < 4; jj++)
            k_[jj] = __builtin_bit_cast(f16x8, K4h[(tx + 16 * jj) * 5 + dg]);
#pragma unroll
        for (int s = 0; s < 7; s++)
            p_[s] = __builtin_bit_cast(f16x8, P4h[(pbase + 16 * (s - 3)) * 5 + dg]);
#pragma unroll
        for (int ii = 0; ii < 4; ii++)
#pragma unroll
            for (int jj = 0; jj < 4; jj++) {
                f16x8 a = qu_[ii], b = k_[jj];
                f16x8 av = qv_[ii], pv = p_[jj - ii + 3];
                float r = acc[ii][jj];
                r = fdot2_(SL(a, 0), SL(b, 0), r);
                r = fdot2_(SL(a, 1), SL(b, 1), r);
                r = fdot2_(SL(a, 2), SL(b, 2), r);
                r = fdot2_(SL(a, 3), SL(b, 3), r);
                r = fdot2_(SL(av, 0), SL(pv, 0), r);
                r = fdot2_(SL(av, 1), SL(pv, 1), r);
                r = fdot2_(SL(av, 2), SL(pv, 2), r);
                r = fdot2_(SL(av, 3), SL(pv, 3), r);
                acc[ii][jj] = r;
            }
    }

    const float scale = 0.17677669529663687f;
#pragma unroll
    for (int ii = 0; ii < 4; ii++)
#pragma unroll
        for (int jj = 0; jj < 4; jj++)
            staged[ty + 16 * ii][tx + 16 * jj] = f2bf(acc[ii][jj] * scale);
    __syncthreads();

    unsigned short* o = totb + ((size_t)nh * 1024 + i0) * 1024 + j0;
    int r = t >> 2, q = t & 3;
    u16x8 v0 = *(const u16x8*)&staged[r][q * 16];
    u16x8 v1 = *(const u16x8*)&staged[r][q * 16 + 8];
    *(u16x8*)(o + (size_t)r * 1024 + q * 16) = v0;
    *(u16x8*)(o + (size_t)r * 1024 + q * 16 + 8) = v1;
}

// ---------------------------------------------------------------------------
// attn_finish_kernel: register-resident, no-max softmax, occupancy-forced
// ---------------------------------------------------------------------------
__global__ __launch_bounds__(256, 6) void attn_finish_kernel(
    unsigned short* __restrict__ totb, const float* __restrict__ as_,
    const float* __restrict__ proj_in, const float* __restrict__ proj_out,
    float* __restrict__ out_s)
{
    __shared__ float pin_s[64], po_s[64];
    __shared__ float redbuf[4][8];

    const int t = threadIdx.x;
    const int n = blockIdx.x >> 10;
    const int i = blockIdx.x & 1023;
    const int j0 = t * 4;
    const int wave = t >> 6, lane = t & 63;

    if (t < 64) { pin_s[t] = proj_in[t]; po_s[t] = proj_out[t]; }
    __syncthreads();

    float th[8][4];
#pragma unroll
    for (int h = 0; h < 8; h++) {
        ushort4 u = *(const ushort4*)(totb + ((size_t)(n * 8 + h) * 1024 + i) * 1024 + j0);
        th[h][0] = bf2f(u.x); th[h][1] = bf2f(u.y);
        th[h][2] = bf2f(u.z); th[h][3] = bf2f(u.w);
    }

    const float4* as4 = (const float4*)(as_ + (((size_t)n * 1024 + i) * 1024 + j0) * 8);
    float4* os4 = (float4*)(out_s + (((size_t)n * 1024 + i) * 1024 + j0) * 8);

#pragma unroll
    for (int jj = 0; jj < 4; jj++) {
        float4 alo = as4[jj * 2];
        float4 ahi = as4[jj * 2 + 1];
        float ag[8] = {alo.x, alo.y, alo.z, alo.w, ahi.x, ahi.y, ahi.z, ahi.w};
#pragma unroll
        for (int h = 0; h < 8; h++) {
            float si = 0.f;
#pragma unroll
            for (int g = 0; g < 8; g++) si += ag[g] * pin_s[g * 8 + h];
            th[h][jj] += si;
        }
        float so[8];
#pragma unroll
        for (int g = 0; g < 8; g++) {
            float s = ag[g];
#pragma unroll
            for (int h = 0; h < 8; h++) s += th[h][jj] * po_s[h * 8 + g];
            so[g] = s;
        }
        float4 o0 = {so[0], so[1], so[2], so[3]};
        float4 o1 = {so[4], so[5], so[6], so[7]};
        os4[jj * 2] = o0;
        os4[jj * 2 + 1] = o1;
    }

    // softmax WITHOUT max subtraction (|th| <~ 15 << 88, fp32-safe)
    float sm[8];
#pragma unroll
    for (int h = 0; h < 8; h++) {
        float s = 0.f;
#pragma unroll
        for (int jj = 0; jj < 4; jj++) {
            th[h][jj] = __expf(th[h][jj]);
            s += th[h][jj];
        }
        sm[h] = s;
    }
#pragma unroll
    for (int d = 1; d < 64; d <<= 1)
#pragma unroll
        for (int h = 0; h < 8; h++) sm[h] += __shfl_xor(sm[h], d);
    if (lane == 0)
#pragma unroll
        for (int h = 0; h < 8; h++) redbuf[wave][h] = sm[h];
    __syncthreads();

#pragma unroll
    for (int h = 0; h < 8; h++) {
        float rs = 1.f / (redbuf[0][h] + redbuf[1][h] + redbuf[2][h] + redbuf[3][h]);
        ushort4 o = {f2bf(th[h][0] * rs), f2bf(th[h][1] * rs),
                     f2bf(th[h][2] * rs), f2bf(th[h][3] * rs)};
        *(ushort4*)(totb + ((size_t)(n * 8 + h) * 1024 + i) * 1024 + j0) = o;
    }
}

// ---------------------------------------------------------------------------
// ctx_mfma_kernel: ctx[i,n,h*32+d] = sum_j attn[i,j]*vT[d,j] via MFMA
// 128x32 tile per block, BK=32; grid (8 i-tiles, 32 nh)
// ---------------------------------------------------------------------------
__global__ __launch_bounds__(256) void ctx_mfma_kernel(
    const unsigned short* __restrict__ attnb, const unsigned short* __restrict__ vt,
    unsigned short* __restrict__ ctx_b)
{
    __shared__ __align__(16) unsigned short As[128 * 32];
    __shared__ __align__(16) unsigned short Bs[32 * 32];

    const int t = threadIdx.x;
    const int lane = t & 63, wave = t >> 6;
    const int lr = lane & 15, lk = lane >> 4;
    const int i0 = blockIdx.x * 128;
    const int nh = blockIdx.y;
    const int n = nh >> 3, h = nh & 7;

    const unsigned short* Abase = attnb + ((size_t)nh * 1024 + i0) * 1024;
    const unsigned short* Bbase = vt + (size_t)nh * 32768;

    f32x4 acc[2][2] = {};

    for (int k0 = 0; k0 < 1024; k0 += 32) {
#pragma unroll
        for (int c = 0; c < 2; c++) {
            int bo = t * 16 + c * 4096;
            int row = bo >> 6;
            int col = (bo & 63) >> 1;
            __builtin_amdgcn_global_load_lds(
                (const __attribute__((address_space(1))) void*)(Abase + (size_t)row * 1024 + k0 + col),
                (__attribute__((address_space(3))) void*)(As + (bo >> 1)), 16, 0, 0);
        }
        if (t < 128) {
            int bo = t * 16;
            int row = bo >> 6;
            int col = (bo & 63) >> 1;
            __builtin_amdgcn_global_load_lds(
                (const __attribute__((address_space(1))) void*)(Bbase + (size_t)row * 1024 + k0 + col),
                (__attribute__((address_space(3))) void*)(Bs + (bo >> 1)), 16, 0, 0);
        }
        __syncthreads();

        bf16x8 af[2], bf_[2];
#pragma unroll
        for (int mi = 0; mi < 2; mi++)
            af[mi] = *(const bf16x8*)(As + (wave * 32 + mi * 16 + lr) * 32 + lk * 8);
#pragma unroll
        for (int nj = 0; nj < 2; nj++)
            bf_[nj] = *(const bf16x8*)(Bs + (nj * 16 + lr) * 32 + lk * 8);
#pragma unroll
        for (int mi = 0; mi < 2; mi++)
#pragma unroll
            for (int nj = 0; nj < 2; nj++)
                acc[mi][nj] = __builtin_amdgcn_mfma_f32_16x16x32_bf16(
                    af[mi], bf_[nj], acc[mi][nj], 0, 0, 0);
        __syncthreads();
    }

#pragma unroll
    for (int nj = 0; nj < 2; nj++) {
        int d = nj * 16 + lr;
#pragma unroll
        for (int mi = 0; mi < 2; mi++) {
            int ibase = i0 + wave * 32 + mi * 16 + lk * 4;
#pragma unroll
            for (int j = 0; j < 4; j++) {
                int i = ibase + j;
                ctx_b[((size_t)i * 4 + n) * 256 + h * 32 + d] = f2bf(acc[mi][nj][j]);
            }
        }
    }
}

// ---------------------------------------------------------------------------
// GLU (bf16 in -> bf16 out)
// ---------------------------------------------------------------------------
__global__ __launch_bounds__(256) void glu_kernel(
    const unsigned short* __restrict__ h1, unsigned short* __restrict__ g)
{
    int idx4 = blockIdx.x * 256 + threadIdx.x;     // over 4096*128
    int r = idx4 >> 7, c4 = idx4 & 127;
    const ushort4* row = (const ushort4*)(h1 + (size_t)r * 1024);
    ushort4 a = row[c4];
    ushort4 b = row[128 + c4];
    ushort4 o = {f2bf(bf2f(a.x) * sigmoidf_(bf2f(b.x))),
                 f2bf(bf2f(a.y) * sigmoidf_(bf2f(b.y))),
                 f2bf(bf2f(a.z) * sigmoidf_(bf2f(b.z))),
                 f2bf(bf2f(a.w) * sigmoidf_(bf2f(b.w)))};
    ((ushort4*)g)[idx4] = o;
}

// ---------------------------------------------------------------------------
// depthwise conv (K=31, pad 15) + bias + DoubleSwish; bf16 in -> bf16 out
// ---------------------------------------------------------------------------
__global__ __launch_bounds__(256) void dwconv_kernel(
    const unsigned short* __restrict__ g, const float* __restrict__ w_dw,
    const float* __restrict__ b_dw, unsigned short* __restrict__ out)
{
    int idx = blockIdx.x * 256 + threadIdx.x;
    int c = idx & 511;
    int r = idx >> 9;
    int nn = r & 3, l = r >> 2;
    float acc = b_dw[c];
#pragma unroll
    for (int kk = 0; kk < 31; kk++) {
        int l2 = l + kk - 15;
        if (l2 >= 0 && l2 < 1024)
            acc += bf2f(g[(((size_t)l2 * 4 + nn) << 9) + c]) * w_dw[c * 31 + kk];
    }
    out[idx] = f2bf(acc * sigmoidf_(acc - 1.f));
}

// ---------------------------------------------------------------------------
// BasicNorm
// ---------------------------------------------------------------------------
__global__ __launch_bounds__(256) void norm_kernel(
    const float* __restrict__ x, const float* __restrict__ eps_p,
    float* __restrict__ out)
{
    int r = blockIdx.x, t = threadIdx.x;
    float a = x[(size_t)r * 512 + t];
    float b = x[(size_t)r * 512 + 256 + t];
    float ss = a * a + b * b;
#pragma unroll
    for (int d = 1; d < 64; d <<= 1) ss += __shfl_xor(ss, d);
    __shared__ float red[4];
    if ((t & 63) == 0) red[t >> 6] = ss;
    __syncthreads();
    float tot = red[0] + red[1] + red[2] + red[3];
    float scale = rsqrtf(tot * (1.f / 512.f) + __expf(eps_p[0]));
    out[(size_t)r * 512 + t] = a * scale;
    out[(size_t)r * 512 + 256 + t] = b * scale;
}

// ---------------------------------------------------------------------------
extern "C" void kernel_launch(void* const* d_in, const int* in_sizes, int n_in,
                              void* d_out, int out_size, void* d_ws, size_t ws_size,
                              hipStream_t stream)
{
    const float* src   = (const float*)d_in[0];
    const float* pos   = (const float*)d_in[1];
    const float* as_   = (const float*)d_in[2];
    const float* w_in  = (const float*)d_in[3];
    const float* b_in  = (const float*)d_in[4];
    const float* w_pos = (const float*)d_in[5];
    const float* pbu   = (const float*)d_in[6];
    const float* pbv   = (const float*)d_in[7];
    const float* prin  = (const float*)d_in[8];
    const float* prout = (const float*)d_in[9];
    const float* w_out = (const float*)d_in[10];
    const float* b_out = (const float*)d_in[11];
    const float* w_ff1m = (const float*)d_in[12];
    const float* b_ff1m = (const float*)d_in[13];
    const float* w_ff2m = (const float*)d_in[14];
    const float* b_ff2m = (const float*)d_in[15];
    const float* w_ff1 = (const float*)d_in[16];
    const float* b_ff1 = (const float*)d_in[17];
    const float* w_ff2 = (const float*)d_in[18];
    const float* b_ff2 = (const float*)d_in[19];
    const float* w_pw1 = (const float*)d_in[20];
    const float* b_pw1 = (const float*)d_in[21];
    const float* w_dw  = (const float*)d_in[22];
    const float* b_dw  = (const float*)d_in[23];
    const float* w_pw2 = (const float*)d_in[24];
    const float* b_pw2 = (const float*)d_in[25];
    const float* neps  = (const float*)d_in[26];

    float* out_x = (float*)d_out;
    float* out_s = (float*)d_out + 2097152;

    // ---- workspace layout (float units) ----
    float* ws = (float*)d_ws;
    float* xbuf = ws;                               // 2,097,152
    float* U    = xbuf + 2097152;                   // 6,291,456
    float* sbbf = U + 6291456;                      // 1,048,576
    float* xb16f= sbbf + 1048576;                   // 1,048,576
    float* qkvb = xb16f + 1048576;                  // 3,145,728 (later p2h)
    float* qu   = qkvb + 3145728;                   // 1,048,576 (later ctxb)
    float* qv   = qu + 1048576;                     // 1,048,576
    float* kbuf = qv + 1048576;                     // 1,048,576
    float* vbuf = kbuf + 1048576;                   // 1,048,576 (vt bf16)
    float* pbuf = vbuf + 1048576;                   // 524,288
    float* posbf= pbuf + 524288;                    // 524,288
    float* totf = posbf + 524288;                   // 16,777,216
    float* Wreg = totf + 16777216;                  // weights bf16 region

    unsigned short* hb16  = (unsigned short*)U;
    unsigned short* gbuf  = (unsigned short*)(U + 4194304);
    unsigned short* sbb   = (unsigned short*)sbbf;
    unsigned short* dbufb = (unsigned short*)sbbf;
    unsigned short* xb16  = (unsigned short*)xb16f;
    unsigned short* ctxb  = (unsigned short*)qu;
    unsigned short* posb  = (unsigned short*)posbf;
    unsigned short* totb  = (unsigned short*)totf;
    unsigned short* vt    = (unsigned short*)vbuf;
    _Float16*       quh   = (_Float16*)qu;
    _Float16*       qvh   = (_Float16*)qv;
    _Float16*       kh    = (_Float16*)kbuf;
    _Float16*       p2h   = (_Float16*)qkvb;

    // per-weight bf16 buffers
    float* wp = Wreg;
    unsigned short* wff1m_b = (unsigned short*)wp; wp += 524288;
    unsigned short* wff2m_b = (unsigned short*)wp; wp += 524288;
    unsigned short* win_b   = (unsigned short*)wp; wp += 196608;
    unsigned short* wpos_b  = (unsigned short*)wp; wp += 65536;
    unsigned short* wout_b  = (unsigned short*)wp; wp += 65536;
    unsigned short* wpw1_b  = (unsigned short*)wp; wp += 262144;
    unsigned short* wpw2_b  = (unsigned short*)wp; wp += 131072;
    unsigned short* wff1_b  = (unsigned short*)wp; wp += 524288;
    unsigned short* wff2_b  = (unsigned short*)wp; wp += 524288;

    dim3 blk(256);
    const int M = 4096;

    // --- one mega-cast for src, pos, and all weights ---
    {
        CastJobs jobs;
        const float* srcs[11] = {src, pos, w_ff1m, w_ff2m, w_in, w_pos,
                                 w_out, w_pw1, w_pw2, w_ff1, w_ff2};
        unsigned short* dsts[11] = {sbb, posb, wff1m_b, wff2m_b, win_b, wpos_b,
                                    wout_b, wpw1_b, wpw2_b, wff1_b, wff2_b};
        int n4s[11] = {524288, 262016, 262144, 262144, 98304, 32768,
                       32768, 131072, 65536, 262144, 262144};
        int cum = 0;
        for (int s = 0; s < 11; s++) {
            jobs.src[s] = (const float4*)srcs[s];
            jobs.dst[s] = (ushort4*)dsts[s];
            cum += n4s[s];
            jobs.end[s] = cum;
        }
        cast_all_kernel<<<(cum + 255) / 256, blk, 0, stream>>>(jobs, cum);
    }

    // --- macaron FFN ---
    mfma_gemm<1,0,0,1><<<dim3(16, 32), blk, 0, stream>>>(
        sbb, wff1m_b, b_ff1m, nullptr, nullptr, hb16, M, 2048, 512);
    mfma_gemm<0,1,1,1><<<dim3(4, 32), blk, 0, stream>>>(
        hb16, wff2m_b, b_ff2m, src, xbuf, xb16, M, 512, 2048);

    // --- attention ---
    mfma_gemm<0,0,1,0><<<dim3(6, 32), blk, 0, stream>>>(
        xb16, win_b, b_in, nullptr, qkvb, nullptr, M, 768, 512);
    split_kernel<<<4096, blk, 0, stream>>>(qkvb, pbu, pbv, quh, qvh, kh, vt);
    mfma_gemm<0,0,1,0><<<dim3(2, 16), blk, 0, stream>>>(
        posb, wpos_b, nullptr, nullptr, pbuf, nullptr, 2047, 256, 512);
    repack_p_kernel<<<2047, blk, 0, stream>>>(pbuf, p2h);
    scores_kernel<<<dim3(16, 16, 32), blk, 0, stream>>>(quh, qvh, kh, p2h, totb);
    attn_finish_kernel<<<4096, blk, 0, stream>>>(totb, as_, prin, prout, out_s);
    ctx_mfma_kernel<<<dim3(8, 32), blk, 0, stream>>>(totb, vt, ctxb);
    mfma_gemm<0,1,1,1><<<dim3(4, 32), blk, 0, stream>>>(
        ctxb, wout_b, b_out, xbuf, xbuf, xb16, M, 512, 256);

    // --- conv module ---
    mfma_gemm<0,0,0,1><<<dim3(8, 32), blk, 0, stream>>>(
        xb16, wpw1_b, b_pw1, nullptr, nullptr, hb16, M, 1024, 512);
    glu_kernel<<<2048, blk, 0, stream>>>(hb16, gbuf);
    dwconv_kernel<<<8192, blk, 0, stream>>>(gbuf, w_dw, b_dw, dbufb);
    mfma_gemm<0,1,1,1><<<dim3(4, 32), blk, 0, stream>>>(
        dbufb, wpw2_b, b_pw2, xbuf, xbuf, xb16, M, 512, 512);

    // --- final FFN + BasicNorm ---
    mfma_gemm<1,0,0,1><<<dim3(16, 32), blk, 0, stream>>>(
        xb16, wff1_b, b_ff1, nullptr, nullptr, hb16, M, 2048, 512);
    mfma_gemm<0,1,1,0><<<dim3(4, 32), blk, 0, stream>>>(
        hb16, wff2_b, b_ff2, xbuf, xbuf, nullptr, M, 512, 2048);
    norm_kernel<<<4096, blk, 0, stream>>>(xbuf, neps, out_x);
}

// Round 12
// 595.670 us; speedup vs baseline: 1.7216x; 1.7216x over previous
//
#include <hip/hip_runtime.h>

#define DEV_INLINE __device__ __forceinline__

typedef short bf16x8 __attribute__((ext_vector_type(8)));
typedef float f32x4 __attribute__((ext_vector_type(4)));
typedef unsigned short u16x8 __attribute__((ext_vector_type(8)));
typedef _Float16 f16x8 __attribute__((ext_vector_type(8)));
typedef _Float16 f16x2 __attribute__((ext_vector_type(2)));

DEV_INLINE float sigmoidf_(float x) { return 1.f / (1.f + __expf(-x)); }
DEV_INLINE unsigned short f2bf(float x) {
    unsigned int u = __float_as_uint(x);
    unsigned int r = (u + 0x7FFFu + ((u >> 16) & 1u)) >> 16;
    return (unsigned short)r;
}
DEV_INLINE float bf2f(unsigned short u) {
    return __uint_as_float(((unsigned int)u) << 16);
}
DEV_INLINE float fdot2_(f16x2 a, f16x2 b, float c) {
#if __has_builtin(__builtin_amdgcn_fdot2)
    return __builtin_amdgcn_fdot2(a, b, c, false);
#else
    return c + (float)a[0] * (float)b[0] + (float)a[1] * (float)b[1];
#endif
}
#define SL(v, k) __builtin_shufflevector(v, v, 2 * (k), 2 * (k) + 1)

// ---------------------------------------------------------------------------
// mega-cast: all fp32->bf16 casts in one launch
// ---------------------------------------------------------------------------
struct CastJobs {
    const float4* src[11];
    ushort4* dst[11];
    int end[11];
};

__global__ __launch_bounds__(256) void cast_all_kernel(CastJobs jobs, int total4)
{
    int gi = blockIdx.x * 256 + threadIdx.x;
    if (gi >= total4) return;
    int s = 0, base = 0;
    while (gi >= jobs.end[s]) { base = jobs.end[s]; s++; }
    int li = gi - base;
    float4 v = jobs.src[s][li];
    ushort4 o = {f2bf(v.x), f2bf(v.y), f2bf(v.z), f2bf(v.w)};
    jobs.dst[s][li] = o;
}

// ---------------------------------------------------------------------------
// bf16 MFMA GEMM (m97 structure)
// ---------------------------------------------------------------------------
template<int ACT, int RES, int WF32, int WBF>
__global__ __launch_bounds__(256) void mfma_gemm(
    const unsigned short* __restrict__ A, const unsigned short* __restrict__ B,
    const float* __restrict__ bias, const float* __restrict__ res,
    float* __restrict__ C, unsigned short* __restrict__ Cb, int M, int N, int K)
{
    __shared__ __align__(16) unsigned short As[128 * 32];
    __shared__ __align__(16) unsigned short Bs[128 * 32];

    const int t = threadIdx.x;
    const int lane = t & 63, wave = t >> 6;
    const int wr = wave >> 1, wc = wave & 1;
    const int lr = lane & 15, lk = lane >> 4;
    const int m0 = blockIdx.y * 128, n0 = blockIdx.x * 128;

    f32x4 acc[4][4] = {};

    for (int k0 = 0; k0 < K; k0 += 32) {
#pragma unroll
        for (int c = 0; c < 2; c++) {
            int bo = t * 16 + c * 4096;
            int row = bo >> 6;
            int col = (bo & 63) >> 1;
            __builtin_amdgcn_global_load_lds(
                (const __attribute__((address_space(1))) void*)(A + (size_t)(m0 + row) * K + k0 + col),
                (__attribute__((address_space(3))) void*)(As + (bo >> 1)), 16, 0, 0);
            __builtin_amdgcn_global_load_lds(
                (const __attribute__((address_space(1))) void*)(B + (size_t)(n0 + row) * K + k0 + col),
                (__attribute__((address_space(3))) void*)(Bs + (bo >> 1)), 16, 0, 0);
        }
        __syncthreads();

        bf16x8 af[4], bfr[4];
#pragma unroll
        for (int mi = 0; mi < 4; mi++)
            af[mi] = *(const bf16x8*)(As + (wr * 64 + mi * 16 + lr) * 32 + lk * 8);
#pragma unroll
        for (int nj = 0; nj < 4; nj++)
            bfr[nj] = *(const bf16x8*)(Bs + (wc * 64 + nj * 16 + lr) * 32 + lk * 8);
#pragma unroll
        for (int mi = 0; mi < 4; mi++)
#pragma unroll
            for (int nj = 0; nj < 4; nj++)
                acc[mi][nj] = __builtin_amdgcn_mfma_f32_16x16x32_bf16(
                    af[mi], bfr[nj], acc[mi][nj], 0, 0, 0);
        __syncthreads();
    }

#pragma unroll
    for (int nj = 0; nj < 4; nj++) {
        int col = n0 + wc * 64 + nj * 16 + lr;
        float bv = bias ? bias[col] : 0.f;
#pragma unroll
        for (int mi = 0; mi < 4; mi++) {
            int row = m0 + wr * 64 + mi * 16 + lk * 4;
#pragma unroll
            for (int j = 0; j < 4; j++) {
                int r = row + j;
                if (r >= M) continue;
                float v = acc[mi][nj][j] + bv;
                if (ACT) v = v * sigmoidf_(v - 1.f);
                size_t off = (size_t)r * N + col;
                if (RES) v += res[off];
                if (WF32) C[off] = v;
                if (WBF) Cb[off] = f2bf(v);
            }
        }
    }
}

// ---------------------------------------------------------------------------
// Split qkv (L,N,768): qu/qv/k -> fp16 (N,H,L,d); v -> bf16 transposed (N,H,d,L)
// ---------------------------------------------------------------------------
__global__ __launch_bounds__(256) void split_kernel(
    const float* __restrict__ qkv,
    const float* __restrict__ pbu, const float* __restrict__ pbv,
    _Float16* __restrict__ quh, _Float16* __restrict__ qvh,
    _Float16* __restrict__ kh, unsigned short* __restrict__ vt)
{
    int idx = blockIdx.x * 256 + threadIdx.x;
    int dd = idx & 31;
    int l  = (idx >> 5) & 1023;
    int nh = idx >> 15;               // n*8+h
    int h  = nh & 7;
    int n  = nh >> 3;
    size_t base = ((size_t)l * 4 + n) * 768 + h * 32 + dd;
    float q = qkv[base];
    quh[idx] = (_Float16)(q + pbu[h * 32 + dd]);
    qvh[idx] = (_Float16)(q + pbv[h * 32 + dd]);
    kh[idx]  = (_Float16)qkv[base + 256];
    vt[(size_t)nh * 32768 + dd * 1024 + l] = f2bf(qkv[base + 512]);
}

// ---------------------------------------------------------------------------
// Repack p (m,h,d) fp32 -> p2 (h,m,d) fp16
// ---------------------------------------------------------------------------
__global__ __launch_bounds__(256) void repack_p_kernel(
    const float* __restrict__ pb, _Float16* __restrict__ p2h)
{
    int idx = blockIdx.x * 256 + threadIdx.x;
    if (idx >= 2047 * 256) return;
    int dd = idx & 31;
    int h  = (idx >> 5) & 7;
    int m  = idx >> 8;
    p2h[((size_t)h * 2047 + m) * 32 + dd] = (_Float16)pb[idx];
}

// ---------------------------------------------------------------------------
// scores_kernel v3 (fp16 fdot2): totb[n,h,i,j] = bf16((ac + bd) * scale)
// ---------------------------------------------------------------------------
__global__ __launch_bounds__(256) void scores_kernel(
    const _Float16* __restrict__ quh, const _Float16* __restrict__ qvh,
    const _Float16* __restrict__ kh, const _Float16* __restrict__ p2h,
    unsigned short* __restrict__ totb)
{
    __shared__ __align__(16) float4 Qu4h[64 * 5];
    __shared__ __align__(16) float4 Qv4h[64 * 5];
    __shared__ __align__(16) float4 K4h[64 * 5];
    __shared__ __align__(16) float4 P4h[127 * 5 + 3];
    __shared__ __align__(16) unsigned short staged[64][72];

    const int t = threadIdx.x;
    const int tx = t & 15, ty = t >> 4;
    const int j0 = blockIdx.x * 64, i0 = blockIdx.y * 64;
    const int nh = blockIdx.z;
    const int h = nh & 7;
    const int m_base = 960 - i0 + j0;   // >= 0 always

    const float4* qug = (const float4*)(quh + ((size_t)nh * 1024 + i0) * 32);
    const float4* qvg = (const float4*)(qvh + ((size_t)nh * 1024 + i0) * 32);
    const float4* kg  = (const float4*)(kh + ((size_t)nh * 1024 + j0) * 32);
    const float4* pg  = (const float4*)(p2h + ((size_t)h * 2047 + m_base) * 32);

    {
        int r = t >> 2, c = t & 3;
        Qu4h[r * 5 + c] = qug[t];
        Qv4h[r * 5 + c] = qvg[t];
        K4h[r * 5 + c]  = kg[t];
    }
#pragma unroll
    for (int cc = 0; cc < 2; cc++) {
        int fi = t + 256 * cc;
        if (fi < 508) {
            int r = fi >> 2, c = fi & 3;
            P4h[r * 5 + c] = pg[fi];
        }
    }
    __syncthreads();

    float acc[4][4] = {};
    const int pbase = 63 + tx - ty;

#pragma unroll
    for (int dg = 0; dg < 4; dg++) {
        f16x8 qu_[4], qv_[4], k_[4], p_[7];
#pragma unroll
        for (int ii = 0; ii < 4; ii++) {
            qu_[ii] = __builtin_bit_cast(f16x8, Qu4h[(ty + 16 * ii) * 5 + dg]);
            qv_[ii] = __builtin_bit_cast(f16x8, Qv4h[(ty + 16 * ii) * 5 + dg]);
        }
#pragma unroll
        for (int jj = 0; jj < 4; jj++)
            k_[jj] = __builtin_bit_cast(f16x8, K4h[(tx + 16 * jj) * 5 + dg]);
#pragma unroll
        for (int s = 0; s < 7; s++)
            p_[s] = __builtin_bit_cast(f16x8, P4h[(pbase + 16 * (s - 3)) * 5 + dg]);
#pragma unroll
        for (int ii = 0; ii < 4; ii++)
#pragma unroll
            for (int jj = 0; jj < 4; jj++) {
                f16x8 a = qu_[ii], b = k_[jj];
                f16x8 av = qv_[ii], pv = p_[jj - ii + 3];
                float r = acc[ii][jj];
                r = fdot2_(SL(a, 0), SL(b, 0), r);
                r = fdot2_(SL(a, 1), SL(b, 1), r);
                r = fdot2_(SL(a, 2), SL(b, 2), r);
                r = fdot2_(SL(a, 3), SL(b, 3), r);
                r = fdot2_(SL(av, 0), SL(pv, 0), r);
                r = fdot2_(SL(av, 1), SL(pv, 1), r);
                r = fdot2_(SL(av, 2), SL(pv, 2), r);
                r = fdot2_(SL(av, 3), SL(pv, 3), r);
                acc[ii][jj] = r;
            }
    }

    const float scale = 0.17677669529663687f;
#pragma unroll
    for (int ii = 0; ii < 4; ii++)
#pragma unroll
        for (int jj = 0; jj < 4; jj++)
            staged[ty + 16 * ii][tx + 16 * jj] = f2bf(acc[ii][jj] * scale);
    __syncthreads();

    unsigned short* o = totb + ((size_t)nh * 1024 + i0) * 1024 + j0;
    int r = t >> 2, q = t & 3;
    u16x8 v0 = *(const u16x8*)&staged[r][q * 16];
    u16x8 v1 = *(const u16x8*)&staged[r][q * 16 + 8];
    *(u16x8*)(o + (size_t)r * 1024 + q * 16) = v0;
    *(u16x8*)(o + (size_t)r * 1024 + q * 16 + 8) = v1;
}

// ---------------------------------------------------------------------------
// attn_finish_kernel: register-resident, no-max softmax (default occupancy)
// ---------------------------------------------------------------------------
__global__ __launch_bounds__(256) void attn_finish_kernel(
    unsigned short* __restrict__ totb, const float* __restrict__ as_,
    const float* __restrict__ proj_in, const float* __restrict__ proj_out,
    float* __restrict__ out_s)
{
    __shared__ float pin_s[64], po_s[64];
    __shared__ float redbuf[4][8];

    const int t = threadIdx.x;
    const int n = blockIdx.x >> 10;
    const int i = blockIdx.x & 1023;
    const int j0 = t * 4;
    const int wave = t >> 6, lane = t & 63;

    if (t < 64) { pin_s[t] = proj_in[t]; po_s[t] = proj_out[t]; }
    __syncthreads();

    float th[8][4];
#pragma unroll
    for (int h = 0; h < 8; h++) {
        ushort4 u = *(const ushort4*)(totb + ((size_t)(n * 8 + h) * 1024 + i) * 1024 + j0);
        th[h][0] = bf2f(u.x); th[h][1] = bf2f(u.y);
        th[h][2] = bf2f(u.z); th[h][3] = bf2f(u.w);
    }

    const float4* as4 = (const float4*)(as_ + (((size_t)n * 1024 + i) * 1024 + j0) * 8);
    float4* os4 = (float4*)(out_s + (((size_t)n * 1024 + i) * 1024 + j0) * 8);

#pragma unroll
    for (int jj = 0; jj < 4; jj++) {
        float4 alo = as4[jj * 2];
        float4 ahi = as4[jj * 2 + 1];
        float ag[8] = {alo.x, alo.y, alo.z, alo.w, ahi.x, ahi.y, ahi.z, ahi.w};
#pragma unroll
        for (int h = 0; h < 8; h++) {
            float si = 0.f;
#pragma unroll
            for (int g = 0; g < 8; g++) si += ag[g] * pin_s[g * 8 + h];
            th[h][jj] += si;
        }
        float so[8];
#pragma unroll
        for (int g = 0; g < 8; g++) {
            float s = ag[g];
#pragma unroll
            for (int h = 0; h < 8; h++) s += th[h][jj] * po_s[h * 8 + g];
            so[g] = s;
        }
        float4 o0 = {so[0], so[1], so[2], so[3]};
        float4 o1 = {so[4], so[5], so[6], so[7]};
        os4[jj * 2] = o0;
        os4[jj * 2 + 1] = o1;
    }

    // softmax WITHOUT max subtraction (|th| <~ 15 << 88, fp32-safe)
    float sm[8];
#pragma unroll
    for (int h = 0; h < 8; h++) {
        float s = 0.f;
#pragma unroll
        for (int jj = 0; jj < 4; jj++) {
            th[h][jj] = __expf(th[h][jj]);
            s += th[h][jj];
        }
        sm[h] = s;
    }
#pragma unroll
    for (int d = 1; d < 64; d <<= 1)
#pragma unroll
        for (int h = 0; h < 8; h++) sm[h] += __shfl_xor(sm[h], d);
    if (lane == 0)
#pragma unroll
        for (int h = 0; h < 8; h++) redbuf[wave][h] = sm[h];
    __syncthreads();

#pragma unroll
    for (int h = 0; h < 8; h++) {
        float rs = 1.f / (redbuf[0][h] + redbuf[1][h] + redbuf[2][h] + redbuf[3][h]);
        ushort4 o = {f2bf(th[h][0] * rs), f2bf(th[h][1] * rs),
                     f2bf(th[h][2] * rs), f2bf(th[h][3] * rs)};
        *(ushort4*)(totb + ((size_t)(n * 8 + h) * 1024 + i) * 1024 + j0) = o;
    }
}

// ---------------------------------------------------------------------------
// ctx_mfma_kernel: ctx[i,n,h*32+d] = sum_j attn[i,j]*vT[d,j] via MFMA
// 128x32 tile per block, BK=32; grid (8 i-tiles, 32 nh)
// ---------------------------------------------------------------------------
__global__ __launch_bounds__(256) void ctx_mfma_kernel(
    const unsigned short* __restrict__ attnb, const unsigned short* __restrict__ vt,
    unsigned short* __restrict__ ctx_b)
{
    __shared__ __align__(16) unsigned short As[128 * 32];
    __shared__ __align__(16) unsigned short Bs[32 * 32];

    const int t = threadIdx.x;
    const int lane = t & 63, wave = t >> 6;
    const int lr = lane & 15, lk = lane >> 4;
    const int i0 = blockIdx.x * 128;
    const int nh = blockIdx.y;
    const int n = nh >> 3, h = nh & 7;

    const unsigned short* Abase = attnb + ((size_t)nh * 1024 + i0) * 1024;
    const unsigned short* Bbase = vt + (size_t)nh * 32768;

    f32x4 acc[2][2] = {};

    for (int k0 = 0; k0 < 1024; k0 += 32) {
#pragma unroll
        for (int c = 0; c < 2; c++) {
            int bo = t * 16 + c * 4096;
            int row = bo >> 6;
            int col = (bo & 63) >> 1;
            __builtin_amdgcn_global_load_lds(
                (const __attribute__((address_space(1))) void*)(Abase + (size_t)row * 1024 + k0 + col),
                (__attribute__((address_space(3))) void*)(As + (bo >> 1)), 16, 0, 0);
        }
        if (t < 128) {
            int bo = t * 16;
            int row = bo >> 6;
            int col = (bo & 63) >> 1;
            __builtin_amdgcn_global_load_lds(
                (const __attribute__((address_space(1))) void*)(Bbase + (size_t)row * 1024 + k0 + col),
                (__attribute__((address_space(3))) void*)(Bs + (bo >> 1)), 16, 0, 0);
        }
        __syncthreads();

        bf16x8 af[2], bf_[2];
#pragma unroll
        for (int mi = 0; mi < 2; mi++)
            af[mi] = *(const bf16x8*)(As + (wave * 32 + mi * 16 + lr) * 32 + lk * 8);
#pragma unroll
        for (int nj = 0; nj < 2; nj++)
            bf_[nj] = *(const bf16x8*)(Bs + (nj * 16 + lr) * 32 + lk * 8);
#pragma unroll
        for (int mi = 0; mi < 2; mi++)
#pragma unroll
            for (int nj = 0; nj < 2; nj++)
                acc[mi][nj] = __builtin_amdgcn_mfma_f32_16x16x32_bf16(
                    af[mi], bf_[nj], acc[mi][nj], 0, 0, 0);
        __syncthreads();
    }

#pragma unroll
    for (int nj = 0; nj < 2; nj++) {
        int d = nj * 16 + lr;
#pragma unroll
        for (int mi = 0; mi < 2; mi++) {
            int ibase = i0 + wave * 32 + mi * 16 + lk * 4;
#pragma unroll
            for (int j = 0; j < 4; j++) {
                int i = ibase + j;
                ctx_b[((size_t)i * 4 + n) * 256 + h * 32 + d] = f2bf(acc[mi][nj][j]);
            }
        }
    }
}

// ---------------------------------------------------------------------------
// GLU (bf16 in -> bf16 out)
// ---------------------------------------------------------------------------
__global__ __launch_bounds__(256) void glu_kernel(
    const unsigned short* __restrict__ h1, unsigned short* __restrict__ g)
{
    int idx4 = blockIdx.x * 256 + threadIdx.x;     // over 4096*128
    int r = idx4 >> 7, c4 = idx4 & 127;
    const ushort4* row = (const ushort4*)(h1 + (size_t)r * 1024);
    ushort4 a = row[c4];
    ushort4 b = row[128 + c4];
    ushort4 o = {f2bf(bf2f(a.x) * sigmoidf_(bf2f(b.x))),
                 f2bf(bf2f(a.y) * sigmoidf_(bf2f(b.y))),
                 f2bf(bf2f(a.z) * sigmoidf_(bf2f(b.z))),
                 f2bf(bf2f(a.w) * sigmoidf_(bf2f(b.w)))};
    ((ushort4*)g)[idx4] = o;
}

// ---------------------------------------------------------------------------
// depthwise conv (K=31, pad 15) + bias + DoubleSwish; bf16 in -> bf16 out
// ---------------------------------------------------------------------------
__global__ __launch_bounds__(256) void dwconv_kernel(
    const unsigned short* __restrict__ g, const float* __restrict__ w_dw,
    const float* __restrict__ b_dw, unsigned short* __restrict__ out)
{
    int idx = blockIdx.x * 256 + threadIdx.x;
    int c = idx & 511;
    int r = idx >> 9;
    int nn = r & 3, l = r >> 2;
    float acc = b_dw[c];
#pragma unroll
    for (int kk = 0; kk < 31; kk++) {
        int l2 = l + kk - 15;
        if (l2 >= 0 && l2 < 1024)
            acc += bf2f(g[(((size_t)l2 * 4 + nn) << 9) + c]) * w_dw[c * 31 + kk];
    }
    out[idx] = f2bf(acc * sigmoidf_(acc - 1.f));
}

// ---------------------------------------------------------------------------
// BasicNorm
// ---------------------------------------------------------------------------
__global__ __launch_bounds__(256) void norm_kernel(
    const float* __restrict__ x, const float* __restrict__ eps_p,
    float* __restrict__ out)
{
    int r = blockIdx.x, t = threadIdx.x;
    float a = x[(size_t)r * 512 + t];
    float b = x[(size_t)r * 512 + 256 + t];
    float ss = a * a + b * b;
#pragma unroll
    for (int d = 1; d < 64; d <<= 1) ss += __shfl_xor(ss, d);
    __shared__ float red[4];
    if ((t & 63) == 0) red[t >> 6] = ss;
    __syncthreads();
    float tot = red[0] + red[1] + red[2] + red[3];
    float scale = rsqrtf(tot * (1.f / 512.f) + __expf(eps_p[0]));
    out[(size_t)r * 512 + t] = a * scale;
    out[(size_t)r * 512 + 256 + t] = b * scale;
}

// ---------------------------------------------------------------------------
extern "C" void kernel_launch(void* const* d_in, const int* in_sizes, int n_in,
                              void* d_out, int out_size, void* d_ws, size_t ws_size,
                              hipStream_t stream)
{
    const float* src   = (const float*)d_in[0];
    const float* pos   = (const float*)d_in[1];
    const float* as_   = (const float*)d_in[2];
    const float* w_in  = (const float*)d_in[3];
    const float* b_in  = (const float*)d_in[4];
    const float* w_pos = (const float*)d_in[5];
    const float* pbu   = (const float*)d_in[6];
    const float* pbv   = (const float*)d_in[7];
    const float* prin  = (const float*)d_in[8];
    const float* prout = (const float*)d_in[9];
    const float* w_out = (const float*)d_in[10];
    const float* b_out = (const float*)d_in[11];
    const float* w_ff1m = (const float*)d_in[12];
    const float* b_ff1m = (const float*)d_in[13];
    const float* w_ff2m = (const float*)d_in[14];
    const float* b_ff2m = (const float*)d_in[15];
    const float* w_ff1 = (const float*)d_in[16];
    const float* b_ff1 = (const float*)d_in[17];
    const float* w_ff2 = (const float*)d_in[18];
    const float* b_ff2 = (const float*)d_in[19];
    const float* w_pw1 = (const float*)d_in[20];
    const float* b_pw1 = (const float*)d_in[21];
    const float* w_dw  = (const float*)d_in[22];
    const float* b_dw  = (const float*)d_in[23];
    const float* w_pw2 = (const float*)d_in[24];
    const float* b_pw2 = (const float*)d_in[25];
    const float* neps  = (const float*)d_in[26];

    float* out_x = (float*)d_out;
    float* out_s = (float*)d_out + 2097152;

    // ---- workspace layout (float units) ----
    float* ws = (float*)d_ws;
    float* xbuf = ws;                               // 2,097,152
    float* U    = xbuf + 2097152;                   // 6,291,456
    float* sbbf = U + 6291456;                      // 1,048,576
    float* xb16f= sbbf + 1048576;                   // 1,048,576
    float* qkvb = xb16f + 1048576;                  // 3,145,728 (later p2h)
    float* qu   = qkvb + 3145728;                   // 1,048,576 (later ctxb)
    float* qv   = qu + 1048576;                     // 1,048,576
    float* kbuf = qv + 1048576;                     // 1,048,576
    float* vbuf = kbuf + 1048576;                   // 1,048,576 (vt bf16)
    float* pbuf = vbuf + 1048576;                   // 524,288
    float* posbf= pbuf + 524288;                    // 524,288
    float* totf = posbf + 524288;                   // 16,777,216
    float* Wreg = totf + 16777216;                  // weights bf16 region

    unsigned short* hb16  = (unsigned short*)U;
    unsigned short* gbuf  = (unsigned short*)(U + 4194304);
    unsigned short* sbb   = (unsigned short*)sbbf;
    unsigned short* dbufb = (unsigned short*)sbbf;
    unsigned short* xb16  = (unsigned short*)xb16f;
    unsigned short* ctxb  = (unsigned short*)qu;
    unsigned short* posb  = (unsigned short*)posbf;
    unsigned short* totb  = (unsigned short*)totf;
    unsigned short* vt    = (unsigned short*)vbuf;
    _Float16*       quh   = (_Float16*)qu;
    _Float16*       qvh   = (_Float16*)qv;
    _Float16*       kh    = (_Float16*)kbuf;
    _Float16*       p2h   = (_Float16*)qkvb;

    // per-weight bf16 buffers
    float* wp = Wreg;
    unsigned short* wff1m_b = (unsigned short*)wp; wp += 524288;
    unsigned short* wff2m_b = (unsigned short*)wp; wp += 524288;
    unsigned short* win_b   = (unsigned short*)wp; wp += 196608;
    unsigned short* wpos_b  = (unsigned short*)wp; wp += 65536;
    unsigned short* wout_b  = (unsigned short*)wp; wp += 65536;
    unsigned short* wpw1_b  = (unsigned short*)wp; wp += 262144;
    unsigned short* wpw2_b  = (unsigned short*)wp; wp += 131072;
    unsigned short* wff1_b  = (unsigned short*)wp; wp += 524288;
    unsigned short* wff2_b  = (unsigned short*)wp; wp += 524288;

    dim3 blk(256);
    const int M = 4096;

    // --- one mega-cast for src, pos, and all weights ---
    {
        CastJobs jobs;
        const float* srcs[11] = {src, pos, w_ff1m, w_ff2m, w_in, w_pos,
                                 w_out, w_pw1, w_pw2, w_ff1, w_ff2};
        unsigned short* dsts[11] = {sbb, posb, wff1m_b, wff2m_b, win_b, wpos_b,
                                    wout_b, wpw1_b, wpw2_b, wff1_b, wff2_b};
        int n4s[11] = {524288, 262016, 262144, 262144, 98304, 32768,
                       32768, 131072, 65536, 262144, 262144};
        int cum = 0;
        for (int s = 0; s < 11; s++) {
            jobs.src[s] = (const float4*)srcs[s];
            jobs.dst[s] = (ushort4*)dsts[s];
            cum += n4s[s];
            jobs.end[s] = cum;
        }
        cast_all_kernel<<<(cum + 255) / 256, blk, 0, stream>>>(jobs, cum);
    }

    // --- macaron FFN ---
    mfma_gemm<1,0,0,1><<<dim3(16, 32), blk, 0, stream>>>(
        sbb, wff1m_b, b_ff1m, nullptr, nullptr, hb16, M, 2048, 512);
    mfma_gemm<0,1,1,1><<<dim3(4, 32), blk, 0, stream>>>(
        hb16, wff2m_b, b_ff2m, src, xbuf, xb16, M, 512, 2048);

    // --- attention ---
    mfma_gemm<0,0,1,0><<<dim3(6, 32), blk, 0, stream>>>(
        xb16, win_b, b_in, nullptr, qkvb, nullptr, M, 768, 512);
    split_kernel<<<4096, blk, 0, stream>>>(qkvb, pbu, pbv, quh, qvh, kh, vt);
    mfma_gemm<0,0,1,0><<<dim3(2, 16), blk, 0, stream>>>(
        posb, wpos_b, nullptr, nullptr, pbuf, nullptr, 2047, 256, 512);
    repack_p_kernel<<<2047, blk, 0, stream>>>(pbuf, p2h);
    scores_kernel<<<dim3(16, 16, 32), blk, 0, stream>>>(quh, qvh, kh, p2h, totb);
    attn_finish_kernel<<<4096, blk, 0, stream>>>(totb, as_, prin, prout, out_s);
    ctx_mfma_kernel<<<dim3(8, 32), blk, 0, stream>>>(totb, vt, ctxb);
    mfma_gemm<0,1,1,1><<<dim3(4, 32), blk, 0, stream>>>(
        ctxb, wout_b, b_out, xbuf, xbuf, xb16, M, 512, 256);

    // --- conv module ---
    mfma_gemm<0,0,0,1><<<dim3(8, 32), blk, 0, stream>>>(
        xb16, wpw1_b, b_pw1, nullptr, nullptr, hb16, M, 1024, 512);
    glu_kernel<<<2048, blk, 0, stream>>>(hb16, gbuf);
    dwconv_kernel<<<8192, blk, 0, stream>>>(gbuf, w_dw, b_dw, dbufb);
    mfma_gemm<0,1,1,1><<<dim3(4, 32), blk, 0, stream>>>(
        dbufb, wpw2_b, b_pw2, xbuf, xbuf, xb16, M, 512, 512);

    // --- final FFN + BasicNorm ---
    mfma_gemm<1,0,0,1><<<dim3(16, 32), blk, 0, stream>>>(
        xb16, wff1_b, b_ff1, nullptr, nullptr, hb16, M, 2048, 512);
    mfma_gemm<0,1,1,0><<<dim3(4, 32), blk, 0, stream>>>(
        hb16, wff2_b, b_ff2, xbuf, xbuf, nullptr, M, 512, 2048);
    norm_kernel<<<4096, blk, 0, stream>>>(xbuf, neps, out_x);
}

// Round 14
// 522.778 us; speedup vs baseline: 1.9616x; 1.1394x over previous
//
#include <hip/hip_runtime.h>

#define DEV_INLINE __device__ __forceinline__

typedef short bf16x8 __attribute__((ext_vector_type(8)));
typedef float f32x4 __attribute__((ext_vector_type(4)));
typedef unsigned short u16x8 __attribute__((ext_vector_type(8)));
typedef _Float16 f16x8 __attribute__((ext_vector_type(8)));
typedef _Float16 f16x2 __attribute__((ext_vector_type(2)));

DEV_INLINE float sigmoidf_(float x) { return 1.f / (1.f + __expf(-x)); }
DEV_INLINE unsigned short f2bf(float x) {
    unsigned int u = __float_as_uint(x);
    unsigned int r = (u + 0x7FFFu + ((u >> 16) & 1u)) >> 16;
    return (unsigned short)r;
}
DEV_INLINE float bf2f(unsigned short u) {
    return __uint_as_float(((unsigned int)u) << 16);
}
DEV_INLINE float fdot2_(f16x2 a, f16x2 b, float c) {
#if __has_builtin(__builtin_amdgcn_fdot2)
    return __builtin_amdgcn_fdot2(a, b, c, false);
#else
    return c + (float)a[0] * (float)b[0] + (float)a[1] * (float)b[1];
#endif
}
#define SL(v, k) __builtin_shufflevector(v, v, 2 * (k), 2 * (k) + 1)

// ---------------------------------------------------------------------------
// mega-cast: all fp32->bf16 casts in one launch
// ---------------------------------------------------------------------------
struct CastJobs {
    const float4* src[11];
    ushort4* dst[11];
    int end[11];
};

__global__ __launch_bounds__(256) void cast_all_kernel(CastJobs jobs, int total4)
{
    int gi = blockIdx.x * 256 + threadIdx.x;
    if (gi >= total4) return;
    int s = 0, base = 0;
    while (gi >= jobs.end[s]) { base = jobs.end[s]; s++; }
    int li = gi - base;
    float4 v = jobs.src[s][li];
    ushort4 o = {f2bf(v.x), f2bf(v.y), f2bf(v.z), f2bf(v.w)};
    jobs.dst[s][li] = o;
}

// ---------------------------------------------------------------------------
// bf16 MFMA GEMM (m97 structure), 128x128 tile
// ---------------------------------------------------------------------------
template<int ACT, int RES, int WF32, int WBF>
__global__ __launch_bounds__(256) void mfma_gemm(
    const unsigned short* __restrict__ A, const unsigned short* __restrict__ B,
    const float* __restrict__ bias, const float* __restrict__ res,
    float* __restrict__ C, unsigned short* __restrict__ Cb, int M, int N, int K)
{
    __shared__ __align__(16) unsigned short As[128 * 32];
    __shared__ __align__(16) unsigned short Bs[128 * 32];

    const int t = threadIdx.x;
    const int lane = t & 63, wave = t >> 6;
    const int wr = wave >> 1, wc = wave & 1;
    const int lr = lane & 15, lk = lane >> 4;
    const int m0 = blockIdx.y * 128, n0 = blockIdx.x * 128;

    f32x4 acc[4][4] = {};

    for (int k0 = 0; k0 < K; k0 += 32) {
#pragma unroll
        for (int c = 0; c < 2; c++) {
            int bo = t * 16 + c * 4096;
            int row = bo >> 6;
            int col = (bo & 63) >> 1;
            __builtin_amdgcn_global_load_lds(
                (const __attribute__((address_space(1))) void*)(A + (size_t)(m0 + row) * K + k0 + col),
                (__attribute__((address_space(3))) void*)(As + (bo >> 1)), 16, 0, 0);
            __builtin_amdgcn_global_load_lds(
                (const __attribute__((address_space(1))) void*)(B + (size_t)(n0 + row) * K + k0 + col),
                (__attribute__((address_space(3))) void*)(Bs + (bo >> 1)), 16, 0, 0);
        }
        __syncthreads();

        bf16x8 af[4], bfr[4];
#pragma unroll
        for (int mi = 0; mi < 4; mi++)
            af[mi] = *(const bf16x8*)(As + (wr * 64 + mi * 16 + lr) * 32 + lk * 8);
#pragma unroll
        for (int nj = 0; nj < 4; nj++)
            bfr[nj] = *(const bf16x8*)(Bs + (wc * 64 + nj * 16 + lr) * 32 + lk * 8);
#pragma unroll
        for (int mi = 0; mi < 4; mi++)
#pragma unroll
            for (int nj = 0; nj < 4; nj++)
                acc[mi][nj] = __builtin_amdgcn_mfma_f32_16x16x32_bf16(
                    af[mi], bfr[nj], acc[mi][nj], 0, 0, 0);
        __syncthreads();
    }

#pragma unroll
    for (int nj = 0; nj < 4; nj++) {
        int col = n0 + wc * 64 + nj * 16 + lr;
        float bv = bias ? bias[col] : 0.f;
#pragma unroll
        for (int mi = 0; mi < 4; mi++) {
            int row = m0 + wr * 64 + mi * 16 + lk * 4;
#pragma unroll
            for (int j = 0; j < 4; j++) {
                int r = row + j;
                if (r >= M) continue;
                float v = acc[mi][nj][j] + bv;
                if (ACT) v = v * sigmoidf_(v - 1.f);
                size_t off = (size_t)r * N + col;
                if (RES) v += res[off];
                if (WF32) C[off] = v;
                if (WBF) Cb[off] = f2bf(v);
            }
        }
    }
}

// ---------------------------------------------------------------------------
// bf16 MFMA GEMM, 128x64 tile (for small-N GEMMs: doubles grid occupancy)
// 4 waves as 2x2; wave tile 64x32 = 4x2 fragments. LDS 12KB.
// ---------------------------------------------------------------------------
template<int ACT, int RES, int WF32, int WBF>
__global__ __launch_bounds__(256) void mfma_gemm_n64(
    const unsigned short* __restrict__ A, const unsigned short* __restrict__ B,
    const float* __restrict__ bias, const float* __restrict__ res,
    float* __restrict__ C, unsigned short* __restrict__ Cb, int M, int N, int K)
{
    __shared__ __align__(16) unsigned short As[128 * 32];
    __shared__ __align__(16) unsigned short Bs[64 * 32];

    const int t = threadIdx.x;
    const int lane = t & 63, wave = t >> 6;
    const int wr = wave >> 1, wc = wave & 1;
    const int lr = lane & 15, lk = lane >> 4;
    const int m0 = blockIdx.y * 128, n0 = blockIdx.x * 64;

    f32x4 acc[4][2] = {};

    for (int k0 = 0; k0 < K; k0 += 32) {
#pragma unroll
        for (int c = 0; c < 2; c++) {
            int bo = t * 16 + c * 4096;
            int row = bo >> 6;
            int col = (bo & 63) >> 1;
            __builtin_amdgcn_global_load_lds(
                (const __attribute__((address_space(1))) void*)(A + (size_t)(m0 + row) * K + k0 + col),
                (__attribute__((address_space(3))) void*)(As + (bo >> 1)), 16, 0, 0);
        }
        {
            int bo = t * 16;                   // 4KB B tile
            int row = bo >> 6;
            int col = (bo & 63) >> 1;
            __builtin_amdgcn_global_load_lds(
                (const __attribute__((address_space(1))) void*)(B + (size_t)(n0 + row) * K + k0 + col),
                (__attribute__((address_space(3))) void*)(Bs + (bo >> 1)), 16, 0, 0);
        }
        __syncthreads();

        bf16x8 af[4], bfr[2];
#pragma unroll
        for (int mi = 0; mi < 4; mi++)
            af[mi] = *(const bf16x8*)(As + (wr * 64 + mi * 16 + lr) * 32 + lk * 8);
#pragma unroll
        for (int nj = 0; nj < 2; nj++)
            bfr[nj] = *(const bf16x8*)(Bs + (wc * 32 + nj * 16 + lr) * 32 + lk * 8);
#pragma unroll
        for (int mi = 0; mi < 4; mi++)
#pragma unroll
            for (int nj = 0; nj < 2; nj++)
                acc[mi][nj] = __builtin_amdgcn_mfma_f32_16x16x32_bf16(
                    af[mi], bfr[nj], acc[mi][nj], 0, 0, 0);
        __syncthreads();
    }

#pragma unroll
    for (int nj = 0; nj < 2; nj++) {
        int col = n0 + wc * 32 + nj * 16 + lr;
        float bv = bias ? bias[col] : 0.f;
#pragma unroll
        for (int mi = 0; mi < 4; mi++) {
            int row = m0 + wr * 64 + mi * 16 + lk * 4;
#pragma unroll
            for (int j = 0; j < 4; j++) {
                int r = row + j;
                float v = acc[mi][nj][j] + bv;
                if (ACT) v = v * sigmoidf_(v - 1.f);
                size_t off = (size_t)r * N + col;
                if (RES) v += res[off];
                if (WF32) C[off] = v;
                if (WBF) Cb[off] = f2bf(v);
            }
        }
    }
}

// ---------------------------------------------------------------------------
// Split qkv (L,N,768): qu/qv/k -> fp16 (N,H,L,d); v -> bf16 transposed (N,H,d,L)
// ---------------------------------------------------------------------------
__global__ __launch_bounds__(256) void split_kernel(
    const float* __restrict__ qkv,
    const float* __restrict__ pbu, const float* __restrict__ pbv,
    _Float16* __restrict__ quh, _Float16* __restrict__ qvh,
    _Float16* __restrict__ kh, unsigned short* __restrict__ vt)
{
    int idx = blockIdx.x * 256 + threadIdx.x;
    int dd = idx & 31;
    int l  = (idx >> 5) & 1023;
    int nh = idx >> 15;               // n*8+h
    int h  = nh & 7;
    int n  = nh >> 3;
    size_t base = ((size_t)l * 4 + n) * 768 + h * 32 + dd;
    float q = qkv[base];
    quh[idx] = (_Float16)(q + pbu[h * 32 + dd]);
    qvh[idx] = (_Float16)(q + pbv[h * 32 + dd]);
    kh[idx]  = (_Float16)qkv[base + 256];
    vt[(size_t)nh * 32768 + dd * 1024 + l] = f2bf(qkv[base + 512]);
}

// ---------------------------------------------------------------------------
// Repack p (m,h,d) fp32 -> p2 (h,m,d) fp16
// ---------------------------------------------------------------------------
__global__ __launch_bounds__(256) void repack_p_kernel(
    const float* __restrict__ pb, _Float16* __restrict__ p2h)
{
    int idx = blockIdx.x * 256 + threadIdx.x;
    if (idx >= 2047 * 256) return;
    int dd = idx & 31;
    int h  = (idx >> 5) & 7;
    int m  = idx >> 8;
    p2h[((size_t)h * 2047 + m) * 32 + dd] = (_Float16)pb[idx];
}

// ---------------------------------------------------------------------------
// scores_kernel v3 (fp16 fdot2): totb[n,h,i,j] = bf16((ac + bd) * scale)
// ---------------------------------------------------------------------------
__global__ __launch_bounds__(256) void scores_kernel(
    const _Float16* __restrict__ quh, const _Float16* __restrict__ qvh,
    const _Float16* __restrict__ kh, const _Float16* __restrict__ p2h,
    unsigned short* __restrict__ totb)
{
    __shared__ __align__(16) float4 Qu4h[64 * 5];
    __shared__ __align__(16) float4 Qv4h[64 * 5];
    __shared__ __align__(16) float4 K4h[64 * 5];
    __shared__ __align__(16) float4 P4h[127 * 5 + 3];
    __shared__ __align__(16) unsigned short staged[64][72];

    const int t = threadIdx.x;
    const int tx = t & 15, ty = t >> 4;
    const int j0 = blockIdx.x * 64, i0 = blockIdx.y * 64;
    const int nh = blockIdx.z;
    const int h = nh & 7;
    const int m_base = 960 - i0 + j0;   // >= 0 always

    const float4* qug = (const float4*)(quh + ((size_t)nh * 1024 + i0) * 32);
    const float4* qvg = (const float4*)(qvh + ((size_t)nh * 1024 + i0) * 32);
    const float4* kg  = (const float4*)(kh + ((size_t)nh * 1024 + j0) * 32);
    const float4* pg  = (const float4*)(p2h + ((size_t)h * 2047 + m_base) * 32);

    {
        int r = t >> 2, c = t & 3;
        Qu4h[r * 5 + c] = qug[t];
        Qv4h[r * 5 + c] = qvg[t];
        K4h[r * 5 + c]  = kg[t];
    }
#pragma unroll
    for (int cc = 0; cc < 2; cc++) {
        int fi = t + 256 * cc;
        if (fi < 508) {
            int r = fi >> 2, c = fi & 3;
            P4h[r * 5 + c] = pg[fi];
        }
    }
    __syncthreads();

    float acc[4][4] = {};
    const int pbase = 63 + tx - ty;

#pragma unroll
    for (int dg = 0; dg < 4; dg++) {
        f16x8 qu_[4], qv_[4], k_[4], p_[7];
#pragma unroll
        for (int ii = 0; ii < 4; ii++) {
            qu_[ii] = __builtin_bit_cast(f16x8, Qu4h[(ty + 16 * ii) * 5 + dg]);
            qv_[ii] = __builtin_bit_cast(f16x8, Qv4h[(ty + 16 * ii) * 5 + dg]);
        }
#pragma unroll
        for (int jj = 0; jj < 4; jj++)
            k_[jj] = __builtin_bit_cast(f16x8, K4h[(tx + 16 * jj) * 5 + dg]);
#pragma unroll
        for (int s = 0; s < 7; s++)
            p_[s] = __builtin_bit_cast(f16x8, P4h[(pbase + 16 * (s - 3)) * 5 + dg]);
#pragma unroll
        for (int ii = 0; ii < 4; ii++)
#pragma unroll
            for (int jj = 0; jj < 4; jj++) {
                f16x8 a = qu_[ii], b = k_[jj];
                f16x8 av = qv_[ii], pv = p_[jj - ii + 3];
                float r = acc[ii][jj];
                r = fdot2_(SL(a, 0), SL(b, 0), r);
                r = fdot2_(SL(a, 1), SL(b, 1), r);
                r = fdot2_(SL(a, 2), SL(b, 2), r);
                r = fdot2_(SL(a, 3), SL(b, 3), r);
                r = fdot2_(SL(av, 0), SL(pv, 0), r);
                r = fdot2_(SL(av, 1), SL(pv, 1), r);
                r = fdot2_(SL(av, 2), SL(pv, 2), r);
                r = fdot2_(SL(av, 3), SL(pv, 3), r);
                acc[ii][jj] = r;
            }
    }

    const float scale = 0.17677669529663687f;
#pragma unroll
    for (int ii = 0; ii < 4; ii++)
#pragma unroll
        for (int jj = 0; jj < 4; jj++)
            staged[ty + 16 * ii][tx + 16 * jj] = f2bf(acc[ii][jj] * scale);
    __syncthreads();

    unsigned short* o = totb + ((size_t)nh * 1024 + i0) * 1024 + j0;
    int r = t >> 2, q = t & 3;
    u16x8 v0 = *(const u16x8*)&staged[r][q * 16];
    u16x8 v1 = *(const u16x8*)&staged[r][q * 16 + 8];
    *(u16x8*)(o + (size_t)r * 1024 + q * 16) = v0;
    *(u16x8*)(o + (size_t)r * 1024 + q * 16 + 8) = v1;
}

// ---------------------------------------------------------------------------
// attn_finish_kernel: 512 threads, 2 j-cols/thread (low VGPR -> high occupancy)
// ---------------------------------------------------------------------------
__global__ __launch_bounds__(512) void attn_finish_kernel(
    unsigned short* __restrict__ totb, const float* __restrict__ as_,
    const float* __restrict__ proj_in, const float* __restrict__ proj_out,
    float* __restrict__ out_s)
{
    __shared__ float pin_s[64], po_s[64];
    __shared__ float redbuf[8][8];

    const int t = threadIdx.x;
    const int n = blockIdx.x >> 10;
    const int i = blockIdx.x & 1023;
    const int j0 = t * 2;
    const int wave = t >> 6, lane = t & 63;

    if (t < 64) { pin_s[t] = proj_in[t]; po_s[t] = proj_out[t]; }
    __syncthreads();

    float th[8][2];
#pragma unroll
    for (int h = 0; h < 8; h++) {
        unsigned int u = *(const unsigned int*)(totb + ((size_t)(n * 8 + h) * 1024 + i) * 1024 + j0);
        th[h][0] = bf2f((unsigned short)(u & 0xffffu));
        th[h][1] = bf2f((unsigned short)(u >> 16));
    }

    const float4* as4 = (const float4*)(as_ + (((size_t)n * 1024 + i) * 1024 + j0) * 8);
    float4* os4 = (float4*)(out_s + (((size_t)n * 1024 + i) * 1024 + j0) * 8);

#pragma unroll
    for (int jj = 0; jj < 2; jj++) {
        float4 alo = as4[jj * 2];
        float4 ahi = as4[jj * 2 + 1];
        float ag[8] = {alo.x, alo.y, alo.z, alo.w, ahi.x, ahi.y, ahi.z, ahi.w};
#pragma unroll
        for (int h = 0; h < 8; h++) {
            float si = 0.f;
#pragma unroll
            for (int g = 0; g < 8; g++) si += ag[g] * pin_s[g * 8 + h];
            th[h][jj] += si;
        }
        float so[8];
#pragma unroll
        for (int g = 0; g < 8; g++) {
            float s = ag[g];
#pragma unroll
            for (int h = 0; h < 8; h++) s += th[h][jj] * po_s[h * 8 + g];
            so[g] = s;
        }
        float4 o0 = {so[0], so[1], so[2], so[3]};
        float4 o1 = {so[4], so[5], so[6], so[7]};
        os4[jj * 2] = o0;
        os4[jj * 2 + 1] = o1;
    }

    // softmax WITHOUT max subtraction (|th| <~ 15 << 88, fp32-safe)
    float sm[8];
#pragma unroll
    for (int h = 0; h < 8; h++) {
        th[h][0] = __expf(th[h][0]);
        th[h][1] = __expf(th[h][1]);
        sm[h] = th[h][0] + th[h][1];
    }
#pragma unroll
    for (int d = 1; d < 64; d <<= 1)
#pragma unroll
        for (int h = 0; h < 8; h++) sm[h] += __shfl_xor(sm[h], d);
    if (lane == 0)
#pragma unroll
        for (int h = 0; h < 8; h++) redbuf[wave][h] = sm[h];
    __syncthreads();

#pragma unroll
    for (int h = 0; h < 8; h++) {
        float s = 0.f;
#pragma unroll
        for (int w = 0; w < 8; w++) s += redbuf[w][h];
        float rs = 1.f / s;
        unsigned int lo = f2bf(th[h][0] * rs);
        unsigned int hi = f2bf(th[h][1] * rs);
        *(unsigned int*)(totb + ((size_t)(n * 8 + h) * 1024 + i) * 1024 + j0) =
            lo | (hi << 16);
    }
}

// ---------------------------------------------------------------------------
// ctx_mfma_kernel: ctx[i,n,h*32+d] = sum_j attn[i,j]*vT[d,j] via MFMA
// ---------------------------------------------------------------------------
__global__ __launch_bounds__(256) void ctx_mfma_kernel(
    const unsigned short* __restrict__ attnb, const unsigned short* __restrict__ vt,
    unsigned short* __restrict__ ctx_b)
{
    __shared__ __align__(16) unsigned short As[128 * 32];
    __shared__ __align__(16) unsigned short Bs[32 * 32];

    const int t = threadIdx.x;
    const int lane = t & 63, wave = t >> 6;
    const int lr = lane & 15, lk = lane >> 4;
    const int i0 = blockIdx.x * 128;
    const int nh = blockIdx.y;
    const int n = nh >> 3, h = nh & 7;

    const unsigned short* Abase = attnb + ((size_t)nh * 1024 + i0) * 1024;
    const unsigned short* Bbase = vt + (size_t)nh * 32768;

    f32x4 acc[2][2] = {};

    for (int k0 = 0; k0 < 1024; k0 += 32) {
#pragma unroll
        for (int c = 0; c < 2; c++) {
            int bo = t * 16 + c * 4096;
            int row = bo >> 6;
            int col = (bo & 63) >> 1;
            __builtin_amdgcn_global_load_lds(
                (const __attribute__((address_space(1))) void*)(Abase + (size_t)row * 1024 + k0 + col),
                (__attribute__((address_space(3))) void*)(As + (bo >> 1)), 16, 0, 0);
        }
        if (t < 128) {
            int bo = t * 16;
            int row = bo >> 6;
            int col = (bo & 63) >> 1;
            __builtin_amdgcn_global_load_lds(
                (const __attribute__((address_space(1))) void*)(Bbase + (size_t)row * 1024 + k0 + col),
                (__attribute__((address_space(3))) void*)(Bs + (bo >> 1)), 16, 0, 0);
        }
        __syncthreads();

        bf16x8 af[2], bf_[2];
#pragma unroll
        for (int mi = 0; mi < 2; mi++)
            af[mi] = *(const bf16x8*)(As + (wave * 32 + mi * 16 + lr) * 32 + lk * 8);
#pragma unroll
        for (int nj = 0; nj < 2; nj++)
            bf_[nj] = *(const bf16x8*)(Bs + (nj * 16 + lr) * 32 + lk * 8);
#pragma unroll
        for (int mi = 0; mi < 2; mi++)
#pragma unroll
            for (int nj = 0; nj < 2; nj++)
                acc[mi][nj] = __builtin_amdgcn_mfma_f32_16x16x32_bf16(
                    af[mi], bf_[nj], acc[mi][nj], 0, 0, 0);
        __syncthreads();
    }

#pragma unroll
    for (int nj = 0; nj < 2; nj++) {
        int d = nj * 16 + lr;
#pragma unroll
        for (int mi = 0; mi < 2; mi++) {
            int ibase = i0 + wave * 32 + mi * 16 + lk * 4;
#pragma unroll
            for (int j = 0; j < 4; j++) {
                int i = ibase + j;
                ctx_b[((size_t)i * 4 + n) * 256 + h * 32 + d] = f2bf(acc[mi][nj][j]);
            }
        }
    }
}

// ---------------------------------------------------------------------------
// GLU (bf16 in -> bf16 out)
// ---------------------------------------------------------------------------
__global__ __launch_bounds__(256) void glu_kernel(
    const unsigned short* __restrict__ h1, unsigned short* __restrict__ g)
{
    int idx4 = blockIdx.x * 256 + threadIdx.x;     // over 4096*128
    int r = idx4 >> 7, c4 = idx4 & 127;
    const ushort4* row = (const ushort4*)(h1 + (size_t)r * 1024);
    ushort4 a = row[c4];
    ushort4 b = row[128 + c4];
    ushort4 o = {f2bf(bf2f(a.x) * sigmoidf_(bf2f(b.x))),
                 f2bf(bf2f(a.y) * sigmoidf_(bf2f(b.y))),
                 f2bf(bf2f(a.z) * sigmoidf_(bf2f(b.z))),
                 f2bf(bf2f(a.w) * sigmoidf_(bf2f(b.w)))};
    ((ushort4*)g)[idx4] = o;
}

// ---------------------------------------------------------------------------
// depthwise conv (K=31, pad 15) + bias + DoubleSwish; bf16 in -> bf16 out
// ---------------------------------------------------------------------------
__global__ __launch_bounds__(256) void dwconv_kernel(
    const unsigned short* __restrict__ g, const float* __restrict__ w_dw,
    const float* __restrict__ b_dw, unsigned short* __restrict__ out)
{
    int idx = blockIdx.x * 256 + threadIdx.x;
    int c = idx & 511;
    int r = idx >> 9;
    int nn = r & 3, l = r >> 2;
    float acc = b_dw[c];
#pragma unroll
    for (int kk = 0; kk < 31; kk++) {
        int l2 = l + kk - 15;
        if (l2 >= 0 && l2 < 1024)
            acc += bf2f(g[(((size_t)l2 * 4 + nn) << 9) + c]) * w_dw[c * 31 + kk];
    }
    out[idx] = f2bf(acc * sigmoidf_(acc - 1.f));
}

// ---------------------------------------------------------------------------
// BasicNorm
// ---------------------------------------------------------------------------
__global__ __launch_bounds__(256) void norm_kernel(
    const float* __restrict__ x, const float* __restrict__ eps_p,
    float* __restrict__ out)
{
    int r = blockIdx.x, t = threadIdx.x;
    float a = x[(size_t)r * 512 + t];
    float b = x[(size_t)r * 512 + 256 + t];
    float ss = a * a + b * b;
#pragma unroll
    for (int d = 1; d < 64; d <<= 1) ss += __shfl_xor(ss, d);
    __shared__ float red[4];
    if ((t & 63) == 0) red[t >> 6] = ss;
    __syncthreads();
    float tot = red[0] + red[1] + red[2] + red[3];
    float scale = rsqrtf(tot * (1.f / 512.f) + __expf(eps_p[0]));
    out[(size_t)r * 512 + t] = a * scale;
    out[(size_t)r * 512 + 256 + t] = b * scale;
}

// ---------------------------------------------------------------------------
extern "C" void kernel_launch(void* const* d_in, const int* in_sizes, int n_in,
                              void* d_out, int out_size, void* d_ws, size_t ws_size,
                              hipStream_t stream)
{
    const float* src   = (const float*)d_in[0];
    const float* pos   = (const float*)d_in[1];
    const float* as_   = (const float*)d_in[2];
    const float* w_in  = (const float*)d_in[3];
    const float* b_in  = (const float*)d_in[4];
    const float* w_pos = (const float*)d_in[5];
    const float* pbu   = (const float*)d_in[6];
    const float* pbv   = (const float*)d_in[7];
    const float* prin  = (const float*)d_in[8];
    const float* prout = (const float*)d_in[9];
    const float* w_out = (const float*)d_in[10];
    const float* b_out = (const float*)d_in[11];
    const float* w_ff1m = (const float*)d_in[12];
    const float* b_ff1m = (const float*)d_in[13];
    const float* w_ff2m = (const float*)d_in[14];
    const float* b_ff2m = (const float*)d_in[15];
    const float* w_ff1 = (const float*)d_in[16];
    const float* b_ff1 = (const float*)d_in[17];
    const float* w_ff2 = (const float*)d_in[18];
    const float* b_ff2 = (const float*)d_in[19];
    const float* w_pw1 = (const float*)d_in[20];
    const float* b_pw1 = (const float*)d_in[21];
    const float* w_dw  = (const float*)d_in[22];
    const float* b_dw  = (const float*)d_in[23];
    const float* w_pw2 = (const float*)d_in[24];
    const float* b_pw2 = (const float*)d_in[25];
    const float* neps  = (const float*)d_in[26];

    float* out_x = (float*)d_out;
    float* out_s = (float*)d_out + 2097152;

    // ---- workspace layout (float units) ----
    float* ws = (float*)d_ws;
    float* xbuf = ws;                               // 2,097,152
    float* U    = xbuf + 2097152;                   // 6,291,456
    float* sbbf = U + 6291456;                      // 1,048,576
    float* xb16f= sbbf + 1048576;                   // 1,048,576
    float* qkvb = xb16f + 1048576;                  // 3,145,728 (later p2h)
    float* qu   = qkvb + 3145728;                   // 1,048,576 (later ctxb)
    float* qv   = qu + 1048576;                     // 1,048,576
    float* kbuf = qv + 1048576;                     // 1,048,576
    float* vbuf = kbuf + 1048576;                   // 1,048,576 (vt bf16)
    float* pbuf = vbuf + 1048576;                   // 524,288
    float* posbf= pbuf + 524288;                    // 524,288
    float* totf = posbf + 524288;                   // 16,777,216
    float* Wreg = totf + 16777216;                  // weights bf16 region

    unsigned short* hb16  = (unsigned short*)U;
    unsigned short* gbuf  = (unsigned short*)(U + 4194304);
    unsigned short* sbb   = (unsigned short*)sbbf;
    unsigned short* dbufb = (unsigned short*)sbbf;
    unsigned short* xb16  = (unsigned short*)xb16f;
    unsigned short* ctxb  = (unsigned short*)qu;
    unsigned short* posb  = (unsigned short*)posbf;
    unsigned short* totb  = (unsigned short*)totf;
    unsigned short* vt    = (unsigned short*)vbuf;
    _Float16*       quh   = (_Float16*)qu;
    _Float16*       qvh   = (_Float16*)qv;
    _Float16*       kh    = (_Float16*)kbuf;
    _Float16*       p2h   = (_Float16*)qkvb;

    // per-weight bf16 buffers
    float* wp = Wreg;
    unsigned short* wff1m_b = (unsigned short*)wp; wp += 524288;
    unsigned short* wff2m_b = (unsigned short*)wp; wp += 524288;
    unsigned short* win_b   = (unsigned short*)wp; wp += 196608;
    unsigned short* wpos_b  = (unsigned short*)wp; wp += 65536;
    unsigned short* wout_b  = (unsigned short*)wp; wp += 65536;
    unsigned short* wpw1_b  = (unsigned short*)wp; wp += 262144;
    unsigned short* wpw2_b  = (unsigned short*)wp; wp += 131072;
    unsigned short* wff1_b  = (unsigned short*)wp; wp += 524288;
    unsigned short* wff2_b  = (unsigned short*)wp; wp += 524288;

    dim3 blk(256);
    dim3 blk512(512);
    const int M = 4096;

    // --- one mega-cast for src, pos, and all weights ---
    {
        CastJobs jobs;
        const float* srcs[11] = {src, pos, w_ff1m, w_ff2m, w_in, w_pos,
                                 w_out, w_pw1, w_pw2, w_ff1, w_ff2};
        unsigned short* dsts[11] = {sbb, posb, wff1m_b, wff2m_b, win_b, wpos_b,
                                    wout_b, wpw1_b, wpw2_b, wff1_b, wff2_b};
        int n4s[11] = {524288, 262016, 262144, 262144, 98304, 32768,
                       32768, 131072, 65536, 262144, 262144};
        int cum = 0;
        for (int s = 0; s < 11; s++) {
            jobs.src[s] = (const float4*)srcs[s];
            jobs.dst[s] = (ushort4*)dsts[s];
            cum += n4s[s];
            jobs.end[s] = cum;
        }
        cast_all_kernel<<<(cum + 255) / 256, blk, 0, stream>>>(jobs, cum);
    }

    // --- macaron FFN ---
    mfma_gemm<1,0,0,1><<<dim3(16, 32), blk, 0, stream>>>(
        sbb, wff1m_b, b_ff1m, nullptr, nullptr, hb16, M, 2048, 512);
    mfma_gemm_n64<0,1,1,1><<<dim3(8, 32), blk, 0, stream>>>(
        hb16, wff2m_b, b_ff2m, src, xbuf, xb16, M, 512, 2048);

    // --- attention ---
    mfma_gemm_n64<0,0,1,0><<<dim3(12, 32), blk, 0, stream>>>(
        xb16, win_b, b_in, nullptr, qkvb, nullptr, M, 768, 512);
    split_kernel<<<4096, blk, 0, stream>>>(qkvb, pbu, pbv, quh, qvh, kh, vt);
    mfma_gemm<0,0,1,0><<<dim3(2, 16), blk, 0, stream>>>(
        posb, wpos_b, nullptr, nullptr, pbuf, nullptr, 2047, 256, 512);
    repack_p_kernel<<<2047, blk, 0, stream>>>(pbuf, p2h);
    scores_kernel<<<dim3(16, 16, 32), blk, 0, stream>>>(quh, qvh, kh, p2h, totb);
    attn_finish_kernel<<<4096, blk512, 0, stream>>>(totb, as_, prin, prout, out_s);
    ctx_mfma_kernel<<<dim3(8, 32), blk, 0, stream>>>(totb, vt, ctxb);
    mfma_gemm_n64<0,1,1,1><<<dim3(8, 32), blk, 0, stream>>>(
        ctxb, wout_b, b_out, xbuf, xbuf, xb16, M, 512, 256);

    // --- conv module ---
    mfma_gemm<0,0,0,1><<<dim3(8, 32), blk, 0, stream>>>(
        xb16, wpw1_b, b_pw1, nullptr, nullptr, hb16, M, 1024, 512);
    glu_kernel<<<2048, blk, 0, stream>>>(hb16, gbuf);
    dwconv_kernel<<<8192, blk, 0, stream>>>(gbuf, w_dw, b_dw, dbufb);
    mfma_gemm_n64<0,1,1,1><<<dim3(8, 32), blk, 0, stream>>>(
        dbufb, wpw2_b, b_pw2, xbuf, xbuf, xb16, M, 512, 512);

    // --- final FFN + BasicNorm ---
    mfma_gemm<1,0,0,1><<<dim3(16, 32), blk, 0, stream>>>(
        xb16, wff1_b, b_ff1, nullptr, nullptr, hb16, M, 2048, 512);
    mfma_gemm_n64<0,1,1,0><<<dim3(8, 32), blk, 0, stream>>>(
        hb16, wff2_b, b_ff2, xbuf, xbuf, nullptr, M, 512, 2048);
    norm_kernel<<<4096, blk, 0, stream>>>(xbuf, neps, out_x);
}

// Round 17
// 510.489 us; speedup vs baseline: 2.0088x; 1.0241x over previous
//
#include <hip/hip_runtime.h>

#define DEV_INLINE __device__ __forceinline__

typedef short bf16x8 __attribute__((ext_vector_type(8)));
typedef float f32x4 __attribute__((ext_vector_type(4)));
typedef unsigned short u16x8 __attribute__((ext_vector_type(8)));
typedef _Float16 f16x8 __attribute__((ext_vector_type(8)));
typedef _Float16 f16x2 __attribute__((ext_vector_type(2)));

DEV_INLINE float sigmoidf_(float x) { return 1.f / (1.f + __expf(-x)); }
DEV_INLINE unsigned short f2bf(float x) {
    unsigned int u = __float_as_uint(x);
    unsigned int r = (u + 0x7FFFu + ((u >> 16) & 1u)) >> 16;
    return (unsigned short)r;
}
DEV_INLINE float bf2f(unsigned short u) {
    return __uint_as_float(((unsigned int)u) << 16);
}
DEV_INLINE float fdot2_(f16x2 a, f16x2 b, float c) {
#if __has_builtin(__builtin_amdgcn_fdot2)
    return __builtin_amdgcn_fdot2(a, b, c, false);
#else
    return c + (float)a[0] * (float)b[0] + (float)a[1] * (float)b[1];
#endif
}
#define SL(v, k) __builtin_shufflevector(v, v, 2 * (k), 2 * (k) + 1)

// ---------------------------------------------------------------------------
// mega-cast: all fp32->bf16 casts in one launch
// ---------------------------------------------------------------------------
struct CastJobs {
    const float4* src[11];
    ushort4* dst[11];
    int end[11];
};

__global__ __launch_bounds__(256) void cast_all_kernel(CastJobs jobs, int total4)
{
    int gi = blockIdx.x * 256 + threadIdx.x;
    if (gi >= total4) return;
    int s = 0, base = 0;
    while (gi >= jobs.end[s]) { base = jobs.end[s]; s++; }
    int li = gi - base;
    float4 v = jobs.src[s][li];
    ushort4 o = {f2bf(v.x), f2bf(v.y), f2bf(v.z), f2bf(v.w)};
    jobs.dst[s][li] = o;
}

// ---------------------------------------------------------------------------
// bf16 MFMA GEMM (m97 structure), 128x128 tile
// ---------------------------------------------------------------------------
template<int ACT, int RES, int WF32, int WBF>
__global__ __launch_bounds__(256) void mfma_gemm(
    const unsigned short* __restrict__ A, const unsigned short* __restrict__ B,
    const float* __restrict__ bias, const float* __restrict__ res,
    float* __restrict__ C, unsigned short* __restrict__ Cb, int M, int N, int K)
{
    __shared__ __align__(16) unsigned short As[128 * 32];
    __shared__ __align__(16) unsigned short Bs[128 * 32];

    const int t = threadIdx.x;
    const int lane = t & 63, wave = t >> 6;
    const int wr = wave >> 1, wc = wave & 1;
    const int lr = lane & 15, lk = lane >> 4;
    const int m0 = blockIdx.y * 128, n0 = blockIdx.x * 128;

    f32x4 acc[4][4] = {};

    for (int k0 = 0; k0 < K; k0 += 32) {
#pragma unroll
        for (int c = 0; c < 2; c++) {
            int bo = t * 16 + c * 4096;
            int row = bo >> 6;
            int col = (bo & 63) >> 1;
            __builtin_amdgcn_global_load_lds(
                (const __attribute__((address_space(1))) void*)(A + (size_t)(m0 + row) * K + k0 + col),
                (__attribute__((address_space(3))) void*)(As + (bo >> 1)), 16, 0, 0);
            __builtin_amdgcn_global_load_lds(
                (const __attribute__((address_space(1))) void*)(B + (size_t)(n0 + row) * K + k0 + col),
                (__attribute__((address_space(3))) void*)(Bs + (bo >> 1)), 16, 0, 0);
        }
        __syncthreads();

        bf16x8 af[4], bfr[4];
#pragma unroll
        for (int mi = 0; mi < 4; mi++)
            af[mi] = *(const bf16x8*)(As + (wr * 64 + mi * 16 + lr) * 32 + lk * 8);
#pragma unroll
        for (int nj = 0; nj < 4; nj++)
            bfr[nj] = *(const bf16x8*)(Bs + (wc * 64 + nj * 16 + lr) * 32 + lk * 8);
#pragma unroll
        for (int mi = 0; mi < 4; mi++)
#pragma unroll
            for (int nj = 0; nj < 4; nj++)
                acc[mi][nj] = __builtin_amdgcn_mfma_f32_16x16x32_bf16(
                    af[mi], bfr[nj], acc[mi][nj], 0, 0, 0);
        __syncthreads();
    }

#pragma unroll
    for (int nj = 0; nj < 4; nj++) {
        int col = n0 + wc * 64 + nj * 16 + lr;
        float bv = bias ? bias[col] : 0.f;
#pragma unroll
        for (int mi = 0; mi < 4; mi++) {
            int row = m0 + wr * 64 + mi * 16 + lk * 4;
#pragma unroll
            for (int j = 0; j < 4; j++) {
                int r = row + j;
                if (r >= M) continue;
                float v = acc[mi][nj][j] + bv;
                if (ACT) v = v * sigmoidf_(v - 1.f);
                size_t off = (size_t)r * N + col;
                if (RES) v += res[off];
                if (WF32) C[off] = v;
                if (WBF) Cb[off] = f2bf(v);
            }
        }
    }
}

// ---------------------------------------------------------------------------
// bf16 MFMA GEMM, 128x64 tile (for small-N GEMMs: doubles grid occupancy)
// ---------------------------------------------------------------------------
template<int ACT, int RES, int WF32, int WBF>
__global__ __launch_bounds__(256) void mfma_gemm_n64(
    const unsigned short* __restrict__ A, const unsigned short* __restrict__ B,
    const float* __restrict__ bias, const float* __restrict__ res,
    float* __restrict__ C, unsigned short* __restrict__ Cb, int M, int N, int K)
{
    __shared__ __align__(16) unsigned short As[128 * 32];
    __shared__ __align__(16) unsigned short Bs[64 * 32];

    const int t = threadIdx.x;
    const int lane = t & 63, wave = t >> 6;
    const int wr = wave >> 1, wc = wave & 1;
    const int lr = lane & 15, lk = lane >> 4;
    const int m0 = blockIdx.y * 128, n0 = blockIdx.x * 64;

    f32x4 acc[4][2] = {};

    for (int k0 = 0; k0 < K; k0 += 32) {
#pragma unroll
        for (int c = 0; c < 2; c++) {
            int bo = t * 16 + c * 4096;
            int row = bo >> 6;
            int col = (bo & 63) >> 1;
            __builtin_amdgcn_global_load_lds(
                (const __attribute__((address_space(1))) void*)(A + (size_t)(m0 + row) * K + k0 + col),
                (__attribute__((address_space(3))) void*)(As + (bo >> 1)), 16, 0, 0);
        }
        {
            int bo = t * 16;                   // 4KB B tile
            int row = bo >> 6;
            int col = (bo & 63) >> 1;
            __builtin_amdgcn_global_load_lds(
                (const __attribute__((address_space(1))) void*)(B + (size_t)(n0 + row) * K + k0 + col),
                (__attribute__((address_space(3))) void*)(Bs + (bo >> 1)), 16, 0, 0);
        }
        __syncthreads();

        bf16x8 af[4], bfr[2];
#pragma unroll
        for (int mi = 0; mi < 4; mi++)
            af[mi] = *(const bf16x8*)(As + (wr * 64 + mi * 16 + lr) * 32 + lk * 8);
#pragma unroll
        for (int nj = 0; nj < 2; nj++)
            bfr[nj] = *(const bf16x8*)(Bs + (wc * 32 + nj * 16 + lr) * 32 + lk * 8);
#pragma unroll
        for (int mi = 0; mi < 4; mi++)
#pragma unroll
            for (int nj = 0; nj < 2; nj++)
                acc[mi][nj] = __builtin_amdgcn_mfma_f32_16x16x32_bf16(
                    af[mi], bfr[nj], acc[mi][nj], 0, 0, 0);
        __syncthreads();
    }

#pragma unroll
    for (int nj = 0; nj < 2; nj++) {
        int col = n0 + wc * 32 + nj * 16 + lr;
        float bv = bias ? bias[col] : 0.f;
#pragma unroll
        for (int mi = 0; mi < 4; mi++) {
            int row = m0 + wr * 64 + mi * 16 + lk * 4;
#pragma unroll
            for (int j = 0; j < 4; j++) {
                int r = row + j;
                float v = acc[mi][nj][j] + bv;
                if (ACT) v = v * sigmoidf_(v - 1.f);
                size_t off = (size_t)r * N + col;
                if (RES) v += res[off];
                if (WF32) C[off] = v;
                if (WBF) Cb[off] = f2bf(v);
            }
        }
    }
}

// ---------------------------------------------------------------------------
// Split qkv (L,N,768): qu/qv/k -> fp16 (N,H,L,d); v -> bf16 transposed (N,H,d,L)
// ---------------------------------------------------------------------------
__global__ __launch_bounds__(256) void split_kernel(
    const float* __restrict__ qkv,
    const float* __restrict__ pbu, const float* __restrict__ pbv,
    _Float16* __restrict__ quh, _Float16* __restrict__ qvh,
    _Float16* __restrict__ kh, unsigned short* __restrict__ vt)
{
    int idx = blockIdx.x * 256 + threadIdx.x;
    int dd = idx & 31;
    int l  = (idx >> 5) & 1023;
    int nh = idx >> 15;               // n*8+h
    int h  = nh & 7;
    int n  = nh >> 3;
    size_t base = ((size_t)l * 4 + n) * 768 + h * 32 + dd;
    float q = qkv[base];
    quh[idx] = (_Float16)(q + pbu[h * 32 + dd]);
    qvh[idx] = (_Float16)(q + pbv[h * 32 + dd]);
    kh[idx]  = (_Float16)qkv[base + 256];
    vt[(size_t)nh * 32768 + dd * 1024 + l] = f2bf(qkv[base + 512]);
}

// ---------------------------------------------------------------------------
// Repack p (m,h,d) fp32 -> p2 (h,m,d) fp16
// ---------------------------------------------------------------------------
__global__ __launch_bounds__(256) void repack_p_kernel(
    const float* __restrict__ pb, _Float16* __restrict__ p2h)
{
    int idx = blockIdx.x * 256 + threadIdx.x;
    if (idx >= 2047 * 256) return;
    int dd = idx & 31;
    int h  = (idx >> 5) & 7;
    int m  = idx >> 8;
    p2h[((size_t)h * 2047 + m) * 32 + dd] = (_Float16)pb[idx];
}

// ---------------------------------------------------------------------------
// scores_kernel v3 (fp16 fdot2): totb[n,i,h,j] = bf16((ac + bd) * scale)
// ---------------------------------------------------------------------------
__global__ __launch_bounds__(256) void scores_kernel(
    const _Float16* __restrict__ quh, const _Float16* __restrict__ qvh,
    const _Float16* __restrict__ kh, const _Float16* __restrict__ p2h,
    unsigned short* __restrict__ totb)
{
    __shared__ __align__(16) float4 Qu4h[64 * 5];
    __shared__ __align__(16) float4 Qv4h[64 * 5];
    __shared__ __align__(16) float4 K4h[64 * 5];
    __shared__ __align__(16) float4 P4h[127 * 5 + 3];
    __shared__ __align__(16) unsigned short staged[64][72];

    const int t = threadIdx.x;
    const int tx = t & 15, ty = t >> 4;
    const int j0 = blockIdx.x * 64, i0 = blockIdx.y * 64;
    const int nh = blockIdx.z;
    const int n = nh >> 3, h = nh & 7;
    const int m_base = 960 - i0 + j0;   // >= 0 always

    const float4* qug = (const float4*)(quh + ((size_t)nh * 1024 + i0) * 32);
    const float4* qvg = (const float4*)(qvh + ((size_t)nh * 1024 + i0) * 32);
    const float4* kg  = (const float4*)(kh + ((size_t)nh * 1024 + j0) * 32);
    const float4* pg  = (const float4*)(p2h + ((size_t)h * 2047 + m_base) * 32);

    {
        int r = t >> 2, c = t & 3;
        Qu4h[r * 5 + c] = qug[t];
        Qv4h[r * 5 + c] = qvg[t];
        K4h[r * 5 + c]  = kg[t];
    }
#pragma unroll
    for (int cc = 0; cc < 2; cc++) {
        int fi = t + 256 * cc;
        if (fi < 508) {
            int r = fi >> 2, c = fi & 3;
            P4h[r * 5 + c] = pg[fi];
        }
    }
    __syncthreads();

    float acc[4][4] = {};
    const int pbase = 63 + tx - ty;

#pragma unroll
    for (int dg = 0; dg < 4; dg++) {
        f16x8 qu_[4], qv_[4], k_[4], p_[7];
#pragma unroll
        for (int ii = 0; ii < 4; ii++) {
            qu_[ii] = __builtin_bit_cast(f16x8, Qu4h[(ty + 16 * ii) * 5 + dg]);
            qv_[ii] = __builtin_bit_cast(f16x8, Qv4h[(ty + 16 * ii) * 5 + dg]);
        }
#pragma unroll
        for (int jj = 0; jj < 4; jj++)
            k_[jj] = __builtin_bit_cast(f16x8, K4h[(tx + 16 * jj) * 5 + dg]);
#pragma unroll
        for (int s = 0; s < 7; s++)
            p_[s] = __builtin_bit_cast(f16x8, P4h[(pbase + 16 * (s - 3)) * 5 + dg]);
#pragma unroll
        for (int ii = 0; ii < 4; ii++)
#pragma unroll
            for (int jj = 0; jj < 4; jj++) {
                f16x8 a = qu_[ii], b = k_[jj];
                f16x8 av = qv_[ii], pv = p_[jj - ii + 3];
                float r = acc[ii][jj];
                r = fdot2_(SL(a, 0), SL(b, 0), r);
                r = fdot2_(SL(a, 1), SL(b, 1), r);
                r = fdot2_(SL(a, 2), SL(b, 2), r);
                r = fdot2_(SL(a, 3), SL(b, 3), r);
                r = fdot2_(SL(av, 0), SL(pv, 0), r);
                r = fdot2_(SL(av, 1), SL(pv, 1), r);
                r = fdot2_(SL(av, 2), SL(pv, 2), r);
                r = fdot2_(SL(av, 3), SL(pv, 3), r);
                acc[ii][jj] = r;
            }
    }

    const float scale = 0.17677669529663687f;
#pragma unroll
    for (int ii = 0; ii < 4; ii++)
#pragma unroll
        for (int jj = 0; jj < 4; jj++)
            staged[ty + 16 * ii][tx + 16 * jj] = f2bf(acc[ii][jj] * scale);
    __syncthreads();

    // store to (n,i,h,j): row i0+r at ((n*1024+i0+r)*8+h)*1024 + j0
    int r = t >> 2, q = t & 3;
    unsigned short* o = totb + (((size_t)(n * 1024 + i0 + r)) * 8 + h) * 1024 + j0;
    u16x8 v0 = *(const u16x8*)&staged[r][q * 16];
    u16x8 v1 = *(const u16x8*)&staged[r][q * 16 + 8];
    *(u16x8*)(o + q * 16) = v0;
    *(u16x8*)(o + q * 16 + 8) = v1;
}

// ---------------------------------------------------------------------------
// attn_finish_kernel: 256 threads, 4 j-cols/thread, (n,i,h,j) tot layout
// ---------------------------------------------------------------------------
__global__ __launch_bounds__(256) void attn_finish_kernel(
    unsigned short* __restrict__ totb, const float* __restrict__ as_,
    const float* __restrict__ proj_in, const float* __restrict__ proj_out,
    float* __restrict__ out_s)
{
    __shared__ float pin_s[64], po_s[64];
    __shared__ float redbuf[4][8];

    const int t = threadIdx.x;
    const int n = blockIdx.x >> 10;
    const int i = blockIdx.x & 1023;
    const int j0 = t * 4;
    const int wave = t >> 6, lane = t & 63;

    if (t < 64) { pin_s[t] = proj_in[t]; po_s[t] = proj_out[t]; }
    __syncthreads();

    unsigned short* tbase = totb + ((size_t)(n * 1024 + i)) * 8192;  // 8 h rows contiguous

    float th[8][4];
#pragma unroll
    for (int h = 0; h < 8; h++) {
        ushort4 u = *(const ushort4*)(tbase + h * 1024 + j0);
        th[h][0] = bf2f(u.x); th[h][1] = bf2f(u.y);
        th[h][2] = bf2f(u.z); th[h][3] = bf2f(u.w);
    }

    const float4* as4 = (const float4*)(as_ + (((size_t)n * 1024 + i) * 1024 + j0) * 8);
    float4* os4 = (float4*)(out_s + (((size_t)n * 1024 + i) * 1024 + j0) * 8);

#pragma unroll
    for (int jj = 0; jj < 4; jj++) {
        float4 alo = as4[jj * 2];
        float4 ahi = as4[jj * 2 + 1];
        float ag[8] = {alo.x, alo.y, alo.z, alo.w, ahi.x, ahi.y, ahi.z, ahi.w};
#pragma unroll
        for (int h = 0; h < 8; h++) {
            float si = 0.f;
#pragma unroll
            for (int g = 0; g < 8; g++) si += ag[g] * pin_s[g * 8 + h];
            th[h][jj] += si;
        }
        float so[8];
#pragma unroll
        for (int g = 0; g < 8; g++) {
            float s = ag[g];
#pragma unroll
            for (int h = 0; h < 8; h++) s += th[h][jj] * po_s[h * 8 + g];
            so[g] = s;
        }
        float4 o0 = {so[0], so[1], so[2], so[3]};
        float4 o1 = {so[4], so[5], so[6], so[7]};
        os4[jj * 2] = o0;
        os4[jj * 2 + 1] = o1;
    }

    // softmax WITHOUT max subtraction (|th| <~ 15 << 88, fp32-safe)
    float sm[8];
#pragma unroll
    for (int h = 0; h < 8; h++) {
        float s = 0.f;
#pragma unroll
        for (int jj = 0; jj < 4; jj++) {
            th[h][jj] = __expf(th[h][jj]);
            s += th[h][jj];
        }
        sm[h] = s;
    }
#pragma unroll
    for (int d = 1; d < 64; d <<= 1)
#pragma unroll
        for (int h = 0; h < 8; h++) sm[h] += __shfl_xor(sm[h], d);
    if (lane == 0)
#pragma unroll
        for (int h = 0; h < 8; h++) redbuf[wave][h] = sm[h];
    __syncthreads();

#pragma unroll
    for (int h = 0; h < 8; h++) {
        float rs = 1.f / (redbuf[0][h] + redbuf[1][h] + redbuf[2][h] + redbuf[3][h]);
        ushort4 o = {f2bf(th[h][0] * rs), f2bf(th[h][1] * rs),
                     f2bf(th[h][2] * rs), f2bf(th[h][3] * rs)};
        *(ushort4*)(tbase + h * 1024 + j0) = o;
    }
}

// ---------------------------------------------------------------------------
// ctx_mfma_kernel: ctx[i,n,h*32+d] = sum_j attn[i,j]*vT[d,j] via MFMA
// attn layout (n,i,h,j); 128x32 tile per block; grid (8 i-tiles, 32 nh)
// ---------------------------------------------------------------------------
__global__ __launch_bounds__(256) void ctx_mfma_kernel(
    const unsigned short* __restrict__ attnb, const unsigned short* __restrict__ vt,
    unsigned short* __restrict__ ctx_b)
{
    __shared__ __align__(16) unsigned short As[128 * 32];
    __shared__ __align__(16) unsigned short Bs[32 * 32];

    const int t = threadIdx.x;
    const int lane = t & 63, wave = t >> 6;
    const int lr = lane & 15, lk = lane >> 4;
    const int i0 = blockIdx.x * 128;
    const int nh = blockIdx.y;
    const int n = nh >> 3, h = nh & 7;

    const unsigned short* Bbase = vt + (size_t)nh * 32768;

    f32x4 acc[2][2] = {};

    for (int k0 = 0; k0 < 1024; k0 += 32) {
#pragma unroll
        for (int c = 0; c < 2; c++) {
            int bo = t * 16 + c * 4096;
            int row = bo >> 6;
            int col = (bo & 63) >> 1;
            __builtin_amdgcn_global_load_lds(
                (const __attribute__((address_space(1))) void*)(
                    attnb + (((size_t)(n * 1024 + i0 + row)) * 8 + h) * 1024 + k0 + col),
                (__attribute__((address_space(3))) void*)(As + (bo >> 1)), 16, 0, 0);
        }
        if (t < 128) {
            int bo = t * 16;
            int row = bo >> 6;
            int col = (bo & 63) >> 1;
            __builtin_amdgcn_global_load_lds(
                (const __attribute__((address_space(1))) void*)(Bbase + (size_t)row * 1024 + k0 + col),
                (__attribute__((address_space(3))) void*)(Bs + (bo >> 1)), 16, 0, 0);
        }
        __syncthreads();

        bf16x8 af[2], bf_[2];
#pragma unroll
        for (int mi = 0; mi < 2; mi++)
            af[mi] = *(const bf16x8*)(As + (wave * 32 + mi * 16 + lr) * 32 + lk * 8);
#pragma unroll
        for (int nj = 0; nj < 2; nj++)
            bf_[nj] = *(const bf16x8*)(Bs + (nj * 16 + lr) * 32 + lk * 8);
#pragma unroll
        for (int mi = 0; mi < 2; mi++)
#pragma unroll
            for (int nj = 0; nj < 2; nj++)
                acc[mi][nj] = __builtin_amdgcn_mfma_f32_16x16x32_bf16(
                    af[mi], bf_[nj], acc[mi][nj], 0, 0, 0);
        __syncthreads();
    }

#pragma unroll
    for (int nj = 0; nj < 2; nj++) {
        int d = nj * 16 + lr;
#pragma unroll
        for (int mi = 0; mi < 2; mi++) {
            int ibase = i0 + wave * 32 + mi * 16 + lk * 4;
#pragma unroll
            for (int j = 0; j < 4; j++) {
                int i = ibase + j;
                ctx_b[((size_t)i * 4 + n) * 256 + h * 32 + d] = f2bf(acc[mi][nj][j]);
            }
        }
    }
}

// ---------------------------------------------------------------------------
// GLU (bf16 in -> bf16 out)
// ---------------------------------------------------------------------------
__global__ __launch_bounds__(256) void glu_kernel(
    const unsigned short* __restrict__ h1, unsigned short* __restrict__ g)
{
    int idx4 = blockIdx.x * 256 + threadIdx.x;     // over 4096*128
    int r = idx4 >> 7, c4 = idx4 & 127;
    const ushort4* row = (const ushort4*)(h1 + (size_t)r * 1024);
    ushort4 a = row[c4];
    ushort4 b = row[128 + c4];
    ushort4 o = {f2bf(bf2f(a.x) * sigmoidf_(bf2f(b.x))),
                 f2bf(bf2f(a.y) * sigmoidf_(bf2f(b.y))),
                 f2bf(bf2f(a.z) * sigmoidf_(bf2f(b.z))),
                 f2bf(bf2f(a.w) * sigmoidf_(bf2f(b.w)))};
    ((ushort4*)g)[idx4] = o;
}

// ---------------------------------------------------------------------------
// depthwise conv (K=31, pad 15) + bias + DoubleSwish; bf16 in -> bf16 out
// ---------------------------------------------------------------------------
__global__ __launch_bounds__(256) void dwconv_kernel(
    const unsigned short* __restrict__ g, const float* __restrict__ w_dw,
    const float* __restrict__ b_dw, unsigned short* __restrict__ out)
{
    int idx = blockIdx.x * 256 + threadIdx.x;
    int c = idx & 511;
    int r = idx >> 9;
    int nn = r & 3, l = r >> 2;
    float acc = b_dw[c];
#pragma unroll
    for (int kk = 0; kk < 31; kk++) {
        int l2 = l + kk - 15;
        if (l2 >= 0 && l2 < 1024)
            acc += bf2f(g[(((size_t)l2 * 4 + nn) << 9) + c]) * w_dw[c * 31 + kk];
    }
    out[idx] = f2bf(acc * sigmoidf_(acc - 1.f));
}

// ---------------------------------------------------------------------------
// BasicNorm
// ---------------------------------------------------------------------------
__global__ __launch_bounds__(256) void norm_kernel(
    const float* __restrict__ x, const float* __restrict__ eps_p,
    float* __restrict__ out)
{
    int r = blockIdx.x, t = threadIdx.x;
    float a = x[(size_t)r * 512 + t];
    float b = x[(size_t)r * 512 + 256 + t];
    float ss = a * a + b * b;
#pragma unroll
    for (int d = 1; d < 64; d <<= 1) ss += __shfl_xor(ss, d);
    __shared__ float red[4];
    if ((t & 63) == 0) red[t >> 6] = ss;
    __syncthreads();
    float tot = red[0] + red[1] + red[2] + red[3];
    float scale = rsqrtf(tot * (1.f / 512.f) + __expf(eps_p[0]));
    out[(size_t)r * 512 + t] = a * scale;
    out[(size_t)r * 512 + 256 + t] = b * scale;
}

// ---------------------------------------------------------------------------
extern "C" void kernel_launch(void* const* d_in, const int* in_sizes, int n_in,
                              void* d_out, int out_size, void* d_ws, size_t ws_size,
                              hipStream_t stream)
{
    const float* src   = (const float*)d_in[0];
    const float* pos   = (const float*)d_in[1];
    const float* as_   = (const float*)d_in[2];
    const float* w_in  = (const float*)d_in[3];
    const float* b_in  = (const float*)d_in[4];
    const float* w_pos = (const float*)d_in[5];
    const float* pbu   = (const float*)d_in[6];
    const float* pbv   = (const float*)d_in[7];
    const float* prin  = (const float*)d_in[8];
    const float* prout = (const float*)d_in[9];
    const float* w_out = (const float*)d_in[10];
    const float* b_out = (const float*)d_in[11];
    const float* w_ff1m = (const float*)d_in[12];
    const float* b_ff1m = (const float*)d_in[13];
    const float* w_ff2m = (const float*)d_in[14];
    const float* b_ff2m = (const float*)d_in[15];
    const float* w_ff1 = (const float*)d_in[16];
    const float* b_ff1 = (const float*)d_in[17];
    const float* w_ff2 = (const float*)d_in[18];
    const float* b_ff2 = (const float*)d_in[19];
    const float* w_pw1 = (const float*)d_in[20];
    const float* b_pw1 = (const float*)d_in[21];
    const float* w_dw  = (const float*)d_in[22];
    const float* b_dw  = (const float*)d_in[23];
    const float* w_pw2 = (const float*)d_in[24];
    const float* b_pw2 = (const float*)d_in[25];
    const float* neps  = (const float*)d_in[26];

    float* out_x = (float*)d_out;
    float* out_s = (float*)d_out + 2097152;

    // ---- workspace layout (float units) ----
    float* ws = (float*)d_ws;
    float* xbuf = ws;                               // 2,097,152
    float* U    = xbuf + 2097152;                   // 6,291,456
    float* sbbf = U + 6291456;                      // 1,048,576
    float* xb16f= sbbf + 1048576;                   // 1,048,576
    float* qkvb = xb16f + 1048576;                  // 3,145,728 (later p2h)
    float* qu   = qkvb + 3145728;                   // 1,048,576 (later ctxb)
    float* qv   = qu + 1048576;                     // 1,048,576
    float* kbuf = qv + 1048576;                     // 1,048,576
    float* vbuf = kbuf + 1048576;                   // 1,048,576 (vt bf16)
    float* pbuf = vbuf + 1048576;                   // 524,288
    float* posbf= pbuf + 524288;                    // 524,288
    float* totf = posbf + 524288;                   // 16,777,216
    float* Wreg = totf + 16777216;                  // weights bf16 region

    unsigned short* hb16  = (unsigned short*)U;
    unsigned short* gbuf  = (unsigned short*)(U + 4194304);
    unsigned short* sbb   = (unsigned short*)sbbf;
    unsigned short* dbufb = (unsigned short*)sbbf;
    unsigned short* xb16  = (unsigned short*)xb16f;
    unsigned short* ctxb  = (unsigned short*)qu;
    unsigned short* posb  = (unsigned short*)posbf;
    unsigned short* totb  = (unsigned short*)totf;
    unsigned short* vt    = (unsigned short*)vbuf;
    _Float16*       quh   = (_Float16*)qu;
    _Float16*       qvh   = (_Float16*)qv;
    _Float16*       kh    = (_Float16*)kbuf;
    _Float16*       p2h   = (_Float16*)qkvb;

    // per-weight bf16 buffers
    float* wp = Wreg;
    unsigned short* wff1m_b = (unsigned short*)wp; wp += 524288;
    unsigned short* wff2m_b = (unsigned short*)wp; wp += 524288;
    unsigned short* win_b   = (unsigned short*)wp; wp += 196608;
    unsigned short* wpos_b  = (unsigned short*)wp; wp += 65536;
    unsigned short* wout_b  = (unsigned short*)wp; wp += 65536;
    unsigned short* wpw1_b  = (unsigned short*)wp; wp += 262144;
    unsigned short* wpw2_b  = (unsigned short*)wp; wp += 131072;
    unsigned short* wff1_b  = (unsigned short*)wp; wp += 524288;
    unsigned short* wff2_b  = (unsigned short*)wp; wp += 524288;

    dim3 blk(256);
    const int M = 4096;

    // --- one mega-cast for src, pos, and all weights ---
    {
        CastJobs jobs;
        const float* srcs[11] = {src, pos, w_ff1m, w_ff2m, w_in, w_pos,
                                 w_out, w_pw1, w_pw2, w_ff1, w_ff2};
        unsigned short* dsts[11] = {sbb, posb, wff1m_b, wff2m_b, win_b, wpos_b,
                                    wout_b, wpw1_b, wpw2_b, wff1_b, wff2_b};
        int n4s[11] = {524288, 262016, 262144, 262144, 98304, 32768,
                       32768, 131072, 65536, 262144, 262144};
        int cum = 0;
        for (int s = 0; s < 11; s++) {
            jobs.src[s] = (const float4*)srcs[s];
            jobs.dst[s] = (ushort4*)dsts[s];
            cum += n4s[s];
            jobs.end[s] = cum;
        }
        cast_all_kernel<<<(cum + 255) / 256, blk, 0, stream>>>(jobs, cum);
    }

    // --- macaron FFN ---
    mfma_gemm<1,0,0,1><<<dim3(16, 32), blk, 0, stream>>>(
        sbb, wff1m_b, b_ff1m, nullptr, nullptr, hb16, M, 2048, 512);
    mfma_gemm_n64<0,1,1,1><<<dim3(8, 32), blk, 0, stream>>>(
        hb16, wff2m_b, b_ff2m, src, xbuf, xb16, M, 512, 2048);

    // --- attention ---
    mfma_gemm_n64<0,0,1,0><<<dim3(12, 32), blk, 0, stream>>>(
        xb16, win_b, b_in, nullptr, qkvb, nullptr, M, 768, 512);
    split_kernel<<<4096, blk, 0, stream>>>(qkvb, pbu, pbv, quh, qvh, kh, vt);
    mfma_gemm<0,0,1,0><<<dim3(2, 16), blk, 0, stream>>>(
        posb, wpos_b, nullptr, nullptr, pbuf, nullptr, 2047, 256, 512);
    repack_p_kernel<<<2047, blk, 0, stream>>>(pbuf, p2h);
    scores_kernel<<<dim3(16, 16, 32), blk, 0, stream>>>(quh, qvh, kh, p2h, totb);
    attn_finish_kernel<<<4096, blk, 0, stream>>>(totb, as_, prin, prout, out_s);
    ctx_mfma_kernel<<<dim3(8, 32), blk, 0, stream>>>(totb, vt, ctxb);
    mfma_gemm_n64<0,1,1,1><<<dim3(8, 32), blk, 0, stream>>>(
        ctxb, wout_b, b_out, xbuf, xbuf, xb16, M, 512, 256);

    // --- conv module ---
    mfma_gemm<0,0,0,1><<<dim3(8, 32), blk, 0, stream>>>(
        xb16, wpw1_b, b_pw1, nullptr, nullptr, hb16, M, 1024, 512);
    glu_kernel<<<2048, blk, 0, stream>>>(hb16, gbuf);
    dwconv_kernel<<<8192, blk, 0, stream>>>(gbuf, w_dw, b_dw, dbufb);
    mfma_gemm_n64<0,1,1,1><<<dim3(8, 32), blk, 0, stream>>>(
        dbufb, wpw2_b, b_pw2, xbuf, xbuf, xb16, M, 512, 512);

    // --- final FFN + BasicNorm ---
    mfma_gemm<1,0,0,1><<<dim3(16, 32), blk, 0, stream>>>(
        xb16, wff1_b, b_ff1, nullptr, nullptr, hb16, M, 2048, 512);
    mfma_gemm_n64<0,1,1,0><<<dim3(8, 32), blk, 0, stream>>>(
        hb16, wff2_b, b_ff2, xbuf, xbuf, nullptr, M, 512, 2048);
    norm_kernel<<<4096, blk, 0, stream>>>(xbuf, neps, out_x);
}

// Round 18
// 499.741 us; speedup vs baseline: 2.0520x; 1.0215x over previous
//
#include <hip/hip_runtime.h>

#define DEV_INLINE __device__ __forceinline__

typedef short bf16x8 __attribute__((ext_vector_type(8)));
typedef float f32x4 __attribute__((ext_vector_type(4)));
typedef unsigned short u16x8 __attribute__((ext_vector_type(8)));
typedef _Float16 f16x8 __attribute__((ext_vector_type(8)));
typedef _Float16 f16x2 __attribute__((ext_vector_type(2)));

DEV_INLINE float sigmoidf_(float x) { return 1.f / (1.f + __expf(-x)); }
DEV_INLINE unsigned short f2bf(float x) {
    unsigned int u = __float_as_uint(x);
    unsigned int r = (u + 0x7FFFu + ((u >> 16) & 1u)) >> 16;
    return (unsigned short)r;
}
DEV_INLINE float bf2f(unsigned short u) {
    return __uint_as_float(((unsigned int)u) << 16);
}
DEV_INLINE float fdot2_(f16x2 a, f16x2 b, float c) {
#if __has_builtin(__builtin_amdgcn_fdot2)
    return __builtin_amdgcn_fdot2(a, b, c, false);
#else
    return c + (float)a[0] * (float)b[0] + (float)a[1] * (float)b[1];
#endif
}
#define SL(v, k) __builtin_shufflevector(v, v, 2 * (k), 2 * (k) + 1)

// ---------------------------------------------------------------------------
// mega-cast: all fp32->bf16 casts in one launch
// ---------------------------------------------------------------------------
struct CastJobs {
    const float4* src[11];
    ushort4* dst[11];
    int end[11];
};

__global__ __launch_bounds__(256) void cast_all_kernel(CastJobs jobs, int total4)
{
    int gi = blockIdx.x * 256 + threadIdx.x;
    if (gi >= total4) return;
    int s = 0, base = 0;
    while (gi >= jobs.end[s]) { base = jobs.end[s]; s++; }
    int li = gi - base;
    float4 v = jobs.src[s][li];
    ushort4 o = {f2bf(v.x), f2bf(v.y), f2bf(v.z), f2bf(v.w)};
    jobs.dst[s][li] = o;
}

// ---------------------------------------------------------------------------
// bf16 MFMA GEMM (m97 structure), 128x128 tile
// ---------------------------------------------------------------------------
template<int ACT, int RES, int WF32, int WBF>
__global__ __launch_bounds__(256) void mfma_gemm(
    const unsigned short* __restrict__ A, const unsigned short* __restrict__ B,
    const float* __restrict__ bias, const float* __restrict__ res,
    float* __restrict__ C, unsigned short* __restrict__ Cb, int M, int N, int K)
{
    __shared__ __align__(16) unsigned short As[128 * 32];
    __shared__ __align__(16) unsigned short Bs[128 * 32];

    const int t = threadIdx.x;
    const int lane = t & 63, wave = t >> 6;
    const int wr = wave >> 1, wc = wave & 1;
    const int lr = lane & 15, lk = lane >> 4;
    const int m0 = blockIdx.y * 128, n0 = blockIdx.x * 128;

    f32x4 acc[4][4] = {};

    for (int k0 = 0; k0 < K; k0 += 32) {
#pragma unroll
        for (int c = 0; c < 2; c++) {
            int bo = t * 16 + c * 4096;
            int row = bo >> 6;
            int col = (bo & 63) >> 1;
            __builtin_amdgcn_global_load_lds(
                (const __attribute__((address_space(1))) void*)(A + (size_t)(m0 + row) * K + k0 + col),
                (__attribute__((address_space(3))) void*)(As + (bo >> 1)), 16, 0, 0);
            __builtin_amdgcn_global_load_lds(
                (const __attribute__((address_space(1))) void*)(B + (size_t)(n0 + row) * K + k0 + col),
                (__attribute__((address_space(3))) void*)(Bs + (bo >> 1)), 16, 0, 0);
        }
        __syncthreads();

        bf16x8 af[4], bfr[4];
#pragma unroll
        for (int mi = 0; mi < 4; mi++)
            af[mi] = *(const bf16x8*)(As + (wr * 64 + mi * 16 + lr) * 32 + lk * 8);
#pragma unroll
        for (int nj = 0; nj < 4; nj++)
            bfr[nj] = *(const bf16x8*)(Bs + (wc * 64 + nj * 16 + lr) * 32 + lk * 8);
#pragma unroll
        for (int mi = 0; mi < 4; mi++)
#pragma unroll
            for (int nj = 0; nj < 4; nj++)
                acc[mi][nj] = __builtin_amdgcn_mfma_f32_16x16x32_bf16(
                    af[mi], bfr[nj], acc[mi][nj], 0, 0, 0);
        __syncthreads();
    }

#pragma unroll
    for (int nj = 0; nj < 4; nj++) {
        int col = n0 + wc * 64 + nj * 16 + lr;
        float bv = bias ? bias[col] : 0.f;
#pragma unroll
        for (int mi = 0; mi < 4; mi++) {
            int row = m0 + wr * 64 + mi * 16 + lk * 4;
#pragma unroll
            for (int j = 0; j < 4; j++) {
                int r = row + j;
                if (r >= M) continue;
                float v = acc[mi][nj][j] + bv;
                if (ACT) v = v * sigmoidf_(v - 1.f);
                size_t off = (size_t)r * N + col;
                if (RES) v += res[off];
                if (WF32) C[off] = v;
                if (WBF) Cb[off] = f2bf(v);
            }
        }
    }
}

// ---------------------------------------------------------------------------
// bf16 MFMA GEMM, 128x64 tile (for small-N GEMMs: doubles grid occupancy)
// ---------------------------------------------------------------------------
template<int ACT, int RES, int WF32, int WBF>
__global__ __launch_bounds__(256) void mfma_gemm_n64(
    const unsigned short* __restrict__ A, const unsigned short* __restrict__ B,
    const float* __restrict__ bias, const float* __restrict__ res,
    float* __restrict__ C, unsigned short* __restrict__ Cb, int M, int N, int K)
{
    __shared__ __align__(16) unsigned short As[128 * 32];
    __shared__ __align__(16) unsigned short Bs[64 * 32];

    const int t = threadIdx.x;
    const int lane = t & 63, wave = t >> 6;
    const int wr = wave >> 1, wc = wave & 1;
    const int lr = lane & 15, lk = lane >> 4;
    const int m0 = blockIdx.y * 128, n0 = blockIdx.x * 64;

    f32x4 acc[4][2] = {};

    for (int k0 = 0; k0 < K; k0 += 32) {
#pragma unroll
        for (int c = 0; c < 2; c++) {
            int bo = t * 16 + c * 4096;
            int row = bo >> 6;
            int col = (bo & 63) >> 1;
            __builtin_amdgcn_global_load_lds(
                (const __attribute__((address_space(1))) void*)(A + (size_t)(m0 + row) * K + k0 + col),
                (__attribute__((address_space(3))) void*)(As + (bo >> 1)), 16, 0, 0);
        }
        {
            int bo = t * 16;                   // 4KB B tile
            int row = bo >> 6;
            int col = (bo & 63) >> 1;
            __builtin_amdgcn_global_load_lds(
                (const __attribute__((address_space(1))) void*)(B + (size_t)(n0 + row) * K + k0 + col),
                (__attribute__((address_space(3))) void*)(Bs + (bo >> 1)), 16, 0, 0);
        }
        __syncthreads();

        bf16x8 af[4], bfr[2];
#pragma unroll
        for (int mi = 0; mi < 4; mi++)
            af[mi] = *(const bf16x8*)(As + (wr * 64 + mi * 16 + lr) * 32 + lk * 8);
#pragma unroll
        for (int nj = 0; nj < 2; nj++)
            bfr[nj] = *(const bf16x8*)(Bs + (wc * 32 + nj * 16 + lr) * 32 + lk * 8);
#pragma unroll
        for (int mi = 0; mi < 4; mi++)
#pragma unroll
            for (int nj = 0; nj < 2; nj++)
                acc[mi][nj] = __builtin_amdgcn_mfma_f32_16x16x32_bf16(
                    af[mi], bfr[nj], acc[mi][nj], 0, 0, 0);
        __syncthreads();
    }

#pragma unroll
    for (int nj = 0; nj < 2; nj++) {
        int col = n0 + wc * 32 + nj * 16 + lr;
        float bv = bias ? bias[col] : 0.f;
#pragma unroll
        for (int mi = 0; mi < 4; mi++) {
            int row = m0 + wr * 64 + mi * 16 + lk * 4;
#pragma unroll
            for (int j = 0; j < 4; j++) {
                int r = row + j;
                float v = acc[mi][nj][j] + bv;
                if (ACT) v = v * sigmoidf_(v - 1.f);
                size_t off = (size_t)r * N + col;
                if (RES) v += res[off];
                if (WF32) C[off] = v;
                if (WBF) Cb[off] = f2bf(v);
            }
        }
    }
}

// ---------------------------------------------------------------------------
// Split qkv (L,N,768): qu/qv/k -> fp16 (N,H,L,d); v -> bf16 transposed (N,H,d,L)
// ---------------------------------------------------------------------------
__global__ __launch_bounds__(256) void split_kernel(
    const float* __restrict__ qkv,
    const float* __restrict__ pbu, const float* __restrict__ pbv,
    _Float16* __restrict__ quh, _Float16* __restrict__ qvh,
    _Float16* __restrict__ kh, unsigned short* __restrict__ vt)
{
    int idx = blockIdx.x * 256 + threadIdx.x;
    int dd = idx & 31;
    int l  = (idx >> 5) & 1023;
    int nh = idx >> 15;               // n*8+h
    int h  = nh & 7;
    int n  = nh >> 3;
    size_t base = ((size_t)l * 4 + n) * 768 + h * 32 + dd;
    float q = qkv[base];
    quh[idx] = (_Float16)(q + pbu[h * 32 + dd]);
    qvh[idx] = (_Float16)(q + pbv[h * 32 + dd]);
    kh[idx]  = (_Float16)qkv[base + 256];
    vt[(size_t)nh * 32768 + dd * 1024 + l] = f2bf(qkv[base + 512]);
}

// ---------------------------------------------------------------------------
// Repack p (m,h,d) fp32 -> p2 (h,m,d) fp16
// ---------------------------------------------------------------------------
__global__ __launch_bounds__(256) void repack_p_kernel(
    const float* __restrict__ pb, _Float16* __restrict__ p2h)
{
    int idx = blockIdx.x * 256 + threadIdx.x;
    if (idx >= 2047 * 256) return;
    int dd = idx & 31;
    int h  = (idx >> 5) & 7;
    int m  = idx >> 8;
    p2h[((size_t)h * 2047 + m) * 32 + dd] = (_Float16)pb[idx];
}

// ---------------------------------------------------------------------------
// scores_kernel v3 (fp16 fdot2): totb[n,i,h,j] = bf16((ac + bd) * scale)
// ---------------------------------------------------------------------------
__global__ __launch_bounds__(256) void scores_kernel(
    const _Float16* __restrict__ quh, const _Float16* __restrict__ qvh,
    const _Float16* __restrict__ kh, const _Float16* __restrict__ p2h,
    unsigned short* __restrict__ totb)
{
    __shared__ __align__(16) float4 Qu4h[64 * 5];
    __shared__ __align__(16) float4 Qv4h[64 * 5];
    __shared__ __align__(16) float4 K4h[64 * 5];
    __shared__ __align__(16) float4 P4h[127 * 5 + 3];
    __shared__ __align__(16) unsigned short staged[64][72];

    const int t = threadIdx.x;
    const int tx = t & 15, ty = t >> 4;
    const int j0 = blockIdx.x * 64, i0 = blockIdx.y * 64;
    const int nh = blockIdx.z;
    const int n = nh >> 3, h = nh & 7;
    const int m_base = 960 - i0 + j0;   // >= 0 always

    const float4* qug = (const float4*)(quh + ((size_t)nh * 1024 + i0) * 32);
    const float4* qvg = (const float4*)(qvh + ((size_t)nh * 1024 + i0) * 32);
    const float4* kg  = (const float4*)(kh + ((size_t)nh * 1024 + j0) * 32);
    const float4* pg  = (const float4*)(p2h + ((size_t)h * 2047 + m_base) * 32);

    {
        int r = t >> 2, c = t & 3;
        Qu4h[r * 5 + c] = qug[t];
        Qv4h[r * 5 + c] = qvg[t];
        K4h[r * 5 + c]  = kg[t];
    }
#pragma unroll
    for (int cc = 0; cc < 2; cc++) {
        int fi = t + 256 * cc;
        if (fi < 508) {
            int r = fi >> 2, c = fi & 3;
            P4h[r * 5 + c] = pg[fi];
        }
    }
    __syncthreads();

    float acc[4][4] = {};
    const int pbase = 63 + tx - ty;

#pragma unroll
    for (int dg = 0; dg < 4; dg++) {
        f16x8 qu_[4], qv_[4], k_[4], p_[7];
#pragma unroll
        for (int ii = 0; ii < 4; ii++) {
            qu_[ii] = __builtin_bit_cast(f16x8, Qu4h[(ty + 16 * ii) * 5 + dg]);
            qv_[ii] = __builtin_bit_cast(f16x8, Qv4h[(ty + 16 * ii) * 5 + dg]);
        }
#pragma unroll
        for (int jj = 0; jj < 4; jj++)
            k_[jj] = __builtin_bit_cast(f16x8, K4h[(tx + 16 * jj) * 5 + dg]);
#pragma unroll
        for (int s = 0; s < 7; s++)
            p_[s] = __builtin_bit_cast(f16x8, P4h[(pbase + 16 * (s - 3)) * 5 + dg]);
#pragma unroll
        for (int ii = 0; ii < 4; ii++)
#pragma unroll
            for (int jj = 0; jj < 4; jj++) {
                f16x8 a = qu_[ii], b = k_[jj];
                f16x8 av = qv_[ii], pv = p_[jj - ii + 3];
                float r = acc[ii][jj];
                r = fdot2_(SL(a, 0), SL(b, 0), r);
                r = fdot2_(SL(a, 1), SL(b, 1), r);
                r = fdot2_(SL(a, 2), SL(b, 2), r);
                r = fdot2_(SL(a, 3), SL(b, 3), r);
                r = fdot2_(SL(av, 0), SL(pv, 0), r);
                r = fdot2_(SL(av, 1), SL(pv, 1), r);
                r = fdot2_(SL(av, 2), SL(pv, 2), r);
                r = fdot2_(SL(av, 3), SL(pv, 3), r);
                acc[ii][jj] = r;
            }
    }

    const float scale = 0.17677669529663687f;
#pragma unroll
    for (int ii = 0; ii < 4; ii++)
#pragma unroll
        for (int jj = 0; jj < 4; jj++)
            staged[ty + 16 * ii][tx + 16 * jj] = f2bf(acc[ii][jj] * scale);
    __syncthreads();

    // store to (n,i,h,j): row i0+r at ((n*1024+i0+r)*8+h)*1024 + j0
    int r = t >> 2, q = t & 3;
    unsigned short* o = totb + (((size_t)(n * 1024 + i0 + r)) * 8 + h) * 1024 + j0;
    u16x8 v0 = *(const u16x8*)&staged[r][q * 16];
    u16x8 v1 = *(const u16x8*)&staged[r][q * 16 + 8];
    *(u16x8*)(o + q * 16) = v0;
    *(u16x8*)(o + q * 16 + 8) = v1;
}

// ---------------------------------------------------------------------------
// attn_finish_kernel: 256 threads, 4 j-cols/thread, (n,i,h,j) layout,
// ALL global loads hoisted up front for max memory-level parallelism.
// ---------------------------------------------------------------------------
__global__ __launch_bounds__(256) void attn_finish_kernel(
    unsigned short* __restrict__ totb, const float* __restrict__ as_,
    const float* __restrict__ proj_in, const float* __restrict__ proj_out,
    float* __restrict__ out_s)
{
    __shared__ float pin_s[64], po_s[64];
    __shared__ float redbuf[4][8];

    const int t = threadIdx.x;
    const int n = blockIdx.x >> 10;
    const int i = blockIdx.x & 1023;
    const int j0 = t * 4;
    const int wave = t >> 6, lane = t & 63;

    if (t < 64) { pin_s[t] = proj_in[t]; po_s[t] = proj_out[t]; }

    unsigned short* tbase = totb + ((size_t)(n * 1024 + i)) * 8192;
    const float4* as4 = (const float4*)(as_ + (((size_t)n * 1024 + i) * 1024 + j0) * 8);
    float4* os4 = (float4*)(out_s + (((size_t)n * 1024 + i) * 1024 + j0) * 8);

    // ---- issue ALL loads up front (8 tot + 8 as_ per thread) ----
    ushort4 tu[8];
#pragma unroll
    for (int h = 0; h < 8; h++)
        tu[h] = *(const ushort4*)(tbase + h * 1024 + j0);
    float4 av4[8];
#pragma unroll
    for (int c = 0; c < 8; c++) av4[c] = as4[c];
    __syncthreads();   // pin_s/po_s ready

    float th[8][4];
#pragma unroll
    for (int h = 0; h < 8; h++) {
        th[h][0] = bf2f(tu[h].x); th[h][1] = bf2f(tu[h].y);
        th[h][2] = bf2f(tu[h].z); th[h][3] = bf2f(tu[h].w);
    }

#pragma unroll
    for (int jj = 0; jj < 4; jj++) {
        float4 alo = av4[jj * 2], ahi = av4[jj * 2 + 1];
        float ag[8] = {alo.x, alo.y, alo.z, alo.w, ahi.x, ahi.y, ahi.z, ahi.w};
#pragma unroll
        for (int h = 0; h < 8; h++) {
            float si = 0.f;
#pragma unroll
            for (int g = 0; g < 8; g++) si += ag[g] * pin_s[g * 8 + h];
            th[h][jj] += si;
        }
        float so[8];
#pragma unroll
        for (int g = 0; g < 8; g++) {
            float s = ag[g];
#pragma unroll
            for (int h = 0; h < 8; h++) s += th[h][jj] * po_s[h * 8 + g];
            so[g] = s;
        }
        float4 o0 = {so[0], so[1], so[2], so[3]};
        float4 o1 = {so[4], so[5], so[6], so[7]};
        os4[jj * 2] = o0;
        os4[jj * 2 + 1] = o1;
    }

    // softmax WITHOUT max subtraction (|th| <~ 15 << 88, fp32-safe)
    float sm[8];
#pragma unroll
    for (int h = 0; h < 8; h++) {
        float s = 0.f;
#pragma unroll
        for (int jj = 0; jj < 4; jj++) {
            th[h][jj] = __expf(th[h][jj]);
            s += th[h][jj];
        }
        sm[h] = s;
    }
#pragma unroll
    for (int d = 1; d < 64; d <<= 1)
#pragma unroll
        for (int h = 0; h < 8; h++) sm[h] += __shfl_xor(sm[h], d);
    if (lane == 0)
#pragma unroll
        for (int h = 0; h < 8; h++) redbuf[wave][h] = sm[h];
    __syncthreads();

#pragma unroll
    for (int h = 0; h < 8; h++) {
        float rs = 1.f / (redbuf[0][h] + redbuf[1][h] + redbuf[2][h] + redbuf[3][h]);
        ushort4 o = {f2bf(th[h][0] * rs), f2bf(th[h][1] * rs),
                     f2bf(th[h][2] * rs), f2bf(th[h][3] * rs)};
        *(ushort4*)(tbase + h * 1024 + j0) = o;
    }
}

// ---------------------------------------------------------------------------
// ctx_mfma_kernel: ctx[i,n,h*32+d] = sum_j attn[i,j]*vT[d,j] via MFMA
// attn layout (n,i,h,j); 128x32 tile per block; grid (8 i-tiles, 32 nh)
// ---------------------------------------------------------------------------
__global__ __launch_bounds__(256) void ctx_mfma_kernel(
    const unsigned short* __restrict__ attnb, const unsigned short* __restrict__ vt,
    unsigned short* __restrict__ ctx_b)
{
    __shared__ __align__(16) unsigned short As[128 * 32];
    __shared__ __align__(16) unsigned short Bs[32 * 32];

    const int t = threadIdx.x;
    const int lane = t & 63, wave = t >> 6;
    const int lr = lane & 15, lk = lane >> 4;
    const int i0 = blockIdx.x * 128;
    const int nh = blockIdx.y;
    const int n = nh >> 3, h = nh & 7;

    const unsigned short* Bbase = vt + (size_t)nh * 32768;

    f32x4 acc[2][2] = {};

    for (int k0 = 0; k0 < 1024; k0 += 32) {
#pragma unroll
        for (int c = 0; c < 2; c++) {
            int bo = t * 16 + c * 4096;
            int row = bo >> 6;
            int col = (bo & 63) >> 1;
            __builtin_amdgcn_global_load_lds(
                (const __attribute__((address_space(1))) void*)(
                    attnb + (((size_t)(n * 1024 + i0 + row)) * 8 + h) * 1024 + k0 + col),
                (__attribute__((address_space(3))) void*)(As + (bo >> 1)), 16, 0, 0);
        }
        if (t < 128) {
            int bo = t * 16;
            int row = bo >> 6;
            int col = (bo & 63) >> 1;
            __builtin_amdgcn_global_load_lds(
                (const __attribute__((address_space(1))) void*)(Bbase + (size_t)row * 1024 + k0 + col),
                (__attribute__((address_space(3))) void*)(Bs + (bo >> 1)), 16, 0, 0);
        }
        __syncthreads();

        bf16x8 af[2], bf_[2];
#pragma unroll
        for (int mi = 0; mi < 2; mi++)
            af[mi] = *(const bf16x8*)(As + (wave * 32 + mi * 16 + lr) * 32 + lk * 8);
#pragma unroll
        for (int nj = 0; nj < 2; nj++)
            bf_[nj] = *(const bf16x8*)(Bs + (nj * 16 + lr) * 32 + lk * 8);
#pragma unroll
        for (int mi = 0; mi < 2; mi++)
#pragma unroll
            for (int nj = 0; nj < 2; nj++)
                acc[mi][nj] = __builtin_amdgcn_mfma_f32_16x16x32_bf16(
                    af[mi], bf_[nj], acc[mi][nj], 0, 0, 0);
        __syncthreads();
    }

#pragma unroll
    for (int nj = 0; nj < 2; nj++) {
        int d = nj * 16 + lr;
#pragma unroll
        for (int mi = 0; mi < 2; mi++) {
            int ibase = i0 + wave * 32 + mi * 16 + lk * 4;
#pragma unroll
            for (int j = 0; j < 4; j++) {
                int i = ibase + j;
                ctx_b[((size_t)i * 4 + n) * 256 + h * 32 + d] = f2bf(acc[mi][nj][j]);
            }
        }
    }
}

// ---------------------------------------------------------------------------
// GLU (bf16 in -> bf16 out)
// ---------------------------------------------------------------------------
__global__ __launch_bounds__(256) void glu_kernel(
    const unsigned short* __restrict__ h1, unsigned short* __restrict__ g)
{
    int idx4 = blockIdx.x * 256 + threadIdx.x;     // over 4096*128
    int r = idx4 >> 7, c4 = idx4 & 127;
    const ushort4* row = (const ushort4*)(h1 + (size_t)r * 1024);
    ushort4 a = row[c4];
    ushort4 b = row[128 + c4];
    ushort4 o = {f2bf(bf2f(a.x) * sigmoidf_(bf2f(b.x))),
                 f2bf(bf2f(a.y) * sigmoidf_(bf2f(b.y))),
                 f2bf(bf2f(a.z) * sigmoidf_(bf2f(b.z))),
                 f2bf(bf2f(a.w) * sigmoidf_(bf2f(b.w)))};
    ((ushort4*)g)[idx4] = o;
}

// ---------------------------------------------------------------------------
// depthwise conv (K=31, pad 15) + bias + DoubleSwish; bf16 in -> bf16 out
// ---------------------------------------------------------------------------
__global__ __launch_bounds__(256) void dwconv_kernel(
    const unsigned short* __restrict__ g, const float* __restrict__ w_dw,
    const float* __restrict__ b_dw, unsigned short* __restrict__ out)
{
    int idx = blockIdx.x * 256 + threadIdx.x;
    int c = idx & 511;
    int r = idx >> 9;
    int nn = r & 3, l = r >> 2;
    float acc = b_dw[c];
#pragma unroll
    for (int kk = 0; kk < 31; kk++) {
        int l2 = l + kk - 15;
        if (l2 >= 0 && l2 < 1024)
            acc += bf2f(g[(((size_t)l2 * 4 + nn) << 9) + c]) * w_dw[c * 31 + kk];
    }
    out[idx] = f2bf(acc * sigmoidf_(acc - 1.f));
}

// ---------------------------------------------------------------------------
// BasicNorm
// ---------------------------------------------------------------------------
__global__ __launch_bounds__(256) void norm_kernel(
    const float* __restrict__ x, const float* __restrict__ eps_p,
    float* __restrict__ out)
{
    int r = blockIdx.x, t = threadIdx.x;
    float a = x[(size_t)r * 512 + t];
    float b = x[(size_t)r * 512 + 256 + t];
    float ss = a * a + b * b;
#pragma unroll
    for (int d = 1; d < 64; d <<= 1) ss += __shfl_xor(ss, d);
    __shared__ float red[4];
    if ((t & 63) == 0) red[t >> 6] = ss;
    __syncthreads();
    float tot = red[0] + red[1] + red[2] + red[3];
    float scale = rsqrtf(tot * (1.f / 512.f) + __expf(eps_p[0]));
    out[(size_t)r * 512 + t] = a * scale;
    out[(size_t)r * 512 + 256 + t] = b * scale;
}

// ---------------------------------------------------------------------------
extern "C" void kernel_launch(void* const* d_in, const int* in_sizes, int n_in,
                              void* d_out, int out_size, void* d_ws, size_t ws_size,
                              hipStream_t stream)
{
    const float* src   = (const float*)d_in[0];
    const float* pos   = (const float*)d_in[1];
    const float* as_   = (const float*)d_in[2];
    const float* w_in  = (const float*)d_in[3];
    const float* b_in  = (const float*)d_in[4];
    const float* w_pos = (const float*)d_in[5];
    const float* pbu   = (const float*)d_in[6];
    const float* pbv   = (const float*)d_in[7];
    const float* prin  = (const float*)d_in[8];
    const float* prout = (const float*)d_in[9];
    const float* w_out = (const float*)d_in[10];
    const float* b_out = (const float*)d_in[11];
    const float* w_ff1m = (const float*)d_in[12];
    const float* b_ff1m = (const float*)d_in[13];
    const float* w_ff2m = (const float*)d_in[14];
    const float* b_ff2m = (const float*)d_in[15];
    const float* w_ff1 = (const float*)d_in[16];
    const float* b_ff1 = (const float*)d_in[17];
    const float* w_ff2 = (const float*)d_in[18];
    const float* b_ff2 = (const float*)d_in[19];
    const float* w_pw1 = (const float*)d_in[20];
    const float* b_pw1 = (const float*)d_in[21];
    const float* w_dw  = (const float*)d_in[22];
    const float* b_dw  = (const float*)d_in[23];
    const float* w_pw2 = (const float*)d_in[24];
    const float* b_pw2 = (const float*)d_in[25];
    const float* neps  = (const float*)d_in[26];

    float* out_x = (float*)d_out;
    float* out_s = (float*)d_out + 2097152;

    // ---- workspace layout (float units) ----
    float* ws = (float*)d_ws;
    float* xbuf = ws;                               // 2,097,152
    float* U    = xbuf + 2097152;                   // 6,291,456
    float* sbbf = U + 6291456;                      // 1,048,576
    float* xb16f= sbbf + 1048576;                   // 1,048,576
    float* qkvb = xb16f + 1048576;                  // 3,145,728 (later p2h)
    float* qu   = qkvb + 3145728;                   // 1,048,576 (later ctxb)
    float* qv   = qu + 1048576;                     // 1,048,576
    float* kbuf = qv + 1048576;                     // 1,048,576
    float* vbuf = kbuf + 1048576;                   // 1,048,576 (vt bf16)
    float* pbuf = vbuf + 1048576;                   // 524,288
    float* posbf= pbuf + 524288;                    // 524,288
    float* totf = posbf + 524288;                   // 16,777,216
    float* Wreg = totf + 16777216;                  // weights bf16 region

    unsigned short* hb16  = (unsigned short*)U;
    unsigned short* gbuf  = (unsigned short*)(U + 4194304);
    unsigned short* sbb   = (unsigned short*)sbbf;
    unsigned short* dbufb = (unsigned short*)sbbf;
    unsigned short* xb16  = (unsigned short*)xb16f;
    unsigned short* ctxb  = (unsigned short*)qu;
    unsigned short* posb  = (unsigned short*)posbf;
    unsigned short* totb  = (unsigned short*)totf;
    unsigned short* vt    = (unsigned short*)vbuf;
    _Float16*       quh   = (_Float16*)qu;
    _Float16*       qvh   = (_Float16*)qv;
    _Float16*       kh    = (_Float16*)kbuf;
    _Float16*       p2h   = (_Float16*)qkvb;

    // per-weight bf16 buffers
    float* wp = Wreg;
    unsigned short* wff1m_b = (unsigned short*)wp; wp += 524288;
    unsigned short* wff2m_b = (unsigned short*)wp; wp += 524288;
    unsigned short* win_b   = (unsigned short*)wp; wp += 196608;
    unsigned short* wpos_b  = (unsigned short*)wp; wp += 65536;
    unsigned short* wout_b  = (unsigned short*)wp; wp += 65536;
    unsigned short* wpw1_b  = (unsigned short*)wp; wp += 262144;
    unsigned short* wpw2_b  = (unsigned short*)wp; wp += 131072;
    unsigned short* wff1_b  = (unsigned short*)wp; wp += 524288;
    unsigned short* wff2_b  = (unsigned short*)wp; wp += 524288;

    dim3 blk(256);
    const int M = 4096;

    // --- one mega-cast for src, pos, and all weights ---
    {
        CastJobs jobs;
        const float* srcs[11] = {src, pos, w_ff1m, w_ff2m, w_in, w_pos,
                                 w_out, w_pw1, w_pw2, w_ff1, w_ff2};
        unsigned short* dsts[11] = {sbb, posb, wff1m_b, wff2m_b, win_b, wpos_b,
                                    wout_b, wpw1_b, wpw2_b, wff1_b, wff2_b};
        int n4s[11] = {524288, 262016, 262144, 262144, 98304, 32768,
                       32768, 131072, 65536, 262144, 262144};
        int cum = 0;
        for (int s = 0; s < 11; s++) {
            jobs.src[s] = (const float4*)srcs[s];
            jobs.dst[s] = (ushort4*)dsts[s];
            cum += n4s[s];
            jobs.end[s] = cum;
        }
        cast_all_kernel<<<(cum + 255) / 256, blk, 0, stream>>>(jobs, cum);
    }

    // --- macaron FFN ---
    mfma_gemm<1,0,0,1><<<dim3(16, 32), blk, 0, stream>>>(
        sbb, wff1m_b, b_ff1m, nullptr, nullptr, hb16, M, 2048, 512);
    mfma_gemm_n64<0,1,1,1><<<dim3(8, 32), blk, 0, stream>>>(
        hb16, wff2m_b, b_ff2m, src, xbuf, xb16, M, 512, 2048);

    // --- attention ---
    mfma_gemm_n64<0,0,1,0><<<dim3(12, 32), blk, 0, stream>>>(
        xb16, win_b, b_in, nullptr, qkvb, nullptr, M, 768, 512);
    split_kernel<<<4096, blk, 0, stream>>>(qkvb, pbu, pbv, quh, qvh, kh, vt);
    mfma_gemm<0,0,1,0><<<dim3(2, 16), blk, 0, stream>>>(
        posb, wpos_b, nullptr, nullptr, pbuf, nullptr, 2047, 256, 512);
    repack_p_kernel<<<2047, blk, 0, stream>>>(pbuf, p2h);
    scores_kernel<<<dim3(16, 16, 32), blk, 0, stream>>>(quh, qvh, kh, p2h, totb);
    attn_finish_kernel<<<4096, blk, 0, stream>>>(totb, as_, prin, prout, out_s);
    ctx_mfma_kernel<<<dim3(8, 32), blk, 0, stream>>>(totb, vt, ctxb);
    mfma_gemm_n64<0,1,1,1><<<dim3(8, 32), blk, 0, stream>>>(
        ctxb, wout_b, b_out, xbuf, xbuf, xb16, M, 512, 256);

    // --- conv module ---
    mfma_gemm<0,0,0,1><<<dim3(8, 32), blk, 0, stream>>>(
        xb16, wpw1_b, b_pw1, nullptr, nullptr, hb16, M, 1024, 512);
    glu_kernel<<<2048, blk, 0, stream>>>(hb16, gbuf);
    dwconv_kernel<<<8192, blk, 0, stream>>>(gbuf, w_dw, b_dw, dbufb);
    mfma_gemm_n64<0,1,1,1><<<dim3(8, 32), blk, 0, stream>>>(
        dbufb, wpw2_b, b_pw2, xbuf, xbuf, xb16, M, 512, 512);

    // --- final FFN + BasicNorm ---
    mfma_gemm<1,0,0,1><<<dim3(16, 32), blk, 0, stream>>>(
        xb16, wff1_b, b_ff1, nullptr, nullptr, hb16, M, 2048, 512);
    mfma_gemm_n64<0,1,1,0><<<dim3(8, 32), blk, 0, stream>>>(
        hb16, wff2_b, b_ff2, xbuf, xbuf, nullptr, M, 512, 2048);
    norm_kernel<<<4096, blk, 0, stream>>>(xbuf, neps, out_x);
}

// Round 19
// 492.629 us; speedup vs baseline: 2.0817x; 1.0144x over previous
//
#include <hip/hip_runtime.h>

#define DEV_INLINE __device__ __forceinline__
#define AS1 __attribute__((address_space(1)))
#define AS3 __attribute__((address_space(3)))

typedef short bf16x8 __attribute__((ext_vector_type(8)));
typedef float f32x4 __attribute__((ext_vector_type(4)));
typedef unsigned short u16x8 __attribute__((ext_vector_type(8)));

DEV_INLINE float sigmoidf_(float x) { return 1.f / (1.f + __expf(-x)); }
DEV_INLINE unsigned short f2bf(float x) {
    unsigned int u = __float_as_uint(x);
    unsigned int r = (u + 0x7FFFu + ((u >> 16) & 1u)) >> 16;
    return (unsigned short)r;
}
DEV_INLINE float bf2f(unsigned short u) {
    return __uint_as_float(((unsigned int)u) << 16);
}

// ---------------------------------------------------------------------------
// mega-cast: all fp32->bf16 casts in one launch
// ---------------------------------------------------------------------------
struct CastJobs {
    const float4* src[11];
    ushort4* dst[11];
    int end[11];
};

__global__ __launch_bounds__(256) void cast_all_kernel(CastJobs jobs, int total4)
{
    int gi = blockIdx.x * 256 + threadIdx.x;
    if (gi >= total4) return;
    int s = 0, base = 0;
    while (gi >= jobs.end[s]) { base = jobs.end[s]; s++; }
    int li = gi - base;
    float4 v = jobs.src[s][li];
    ushort4 o = {f2bf(v.x), f2bf(v.y), f2bf(v.z), f2bf(v.w)};
    jobs.dst[s][li] = o;
}

// ---------------------------------------------------------------------------
// bf16 MFMA GEMM (m97 structure), 128x128 tile
// ---------------------------------------------------------------------------
template<int ACT, int RES, int WF32, int WBF>
__global__ __launch_bounds__(256) void mfma_gemm(
    const unsigned short* __restrict__ A, const unsigned short* __restrict__ B,
    const float* __restrict__ bias, const float* __restrict__ res,
    float* __restrict__ C, unsigned short* __restrict__ Cb, int M, int N, int K)
{
    __shared__ __align__(16) unsigned short As[128 * 32];
    __shared__ __align__(16) unsigned short Bs[128 * 32];

    const int t = threadIdx.x;
    const int lane = t & 63, wave = t >> 6;
    const int wr = wave >> 1, wc = wave & 1;
    const int lr = lane & 15, lk = lane >> 4;
    const int m0 = blockIdx.y * 128, n0 = blockIdx.x * 128;

    f32x4 acc[4][4] = {};

    for (int k0 = 0; k0 < K; k0 += 32) {
#pragma unroll
        for (int c = 0; c < 2; c++) {
            int bo = t * 16 + c * 4096;
            int row = bo >> 6;
            int col = (bo & 63) >> 1;
            __builtin_amdgcn_global_load_lds(
                (const AS1 void*)(A + (size_t)(m0 + row) * K + k0 + col),
                (AS3 void*)(As + (bo >> 1)), 16, 0, 0);
            __builtin_amdgcn_global_load_lds(
                (const AS1 void*)(B + (size_t)(n0 + row) * K + k0 + col),
                (AS3 void*)(Bs + (bo >> 1)), 16, 0, 0);
        }
        __syncthreads();

        bf16x8 af[4], bfr[4];
#pragma unroll
        for (int mi = 0; mi < 4; mi++)
            af[mi] = *(const bf16x8*)(As + (wr * 64 + mi * 16 + lr) * 32 + lk * 8);
#pragma unroll
        for (int nj = 0; nj < 4; nj++)
            bfr[nj] = *(const bf16x8*)(Bs + (wc * 64 + nj * 16 + lr) * 32 + lk * 8);
#pragma unroll
        for (int mi = 0; mi < 4; mi++)
#pragma unroll
            for (int nj = 0; nj < 4; nj++)
                acc[mi][nj] = __builtin_amdgcn_mfma_f32_16x16x32_bf16(
                    af[mi], bfr[nj], acc[mi][nj], 0, 0, 0);
        __syncthreads();
    }

#pragma unroll
    for (int nj = 0; nj < 4; nj++) {
        int col = n0 + wc * 64 + nj * 16 + lr;
        float bv = bias ? bias[col] : 0.f;
#pragma unroll
        for (int mi = 0; mi < 4; mi++) {
            int row = m0 + wr * 64 + mi * 16 + lk * 4;
#pragma unroll
            for (int j = 0; j < 4; j++) {
                int r = row + j;
                if (r >= M) continue;
                float v = acc[mi][nj][j] + bv;
                if (ACT) v = v * sigmoidf_(v - 1.f);
                size_t off = (size_t)r * N + col;
                if (RES) v += res[off];
                if (WF32) C[off] = v;
                if (WBF) Cb[off] = f2bf(v);
            }
        }
    }
}

// ---------------------------------------------------------------------------
// bf16 MFMA GEMM, 128x64 tile (for small-N GEMMs: doubles grid occupancy)
// ---------------------------------------------------------------------------
template<int ACT, int RES, int WF32, int WBF>
__global__ __launch_bounds__(256) void mfma_gemm_n64(
    const unsigned short* __restrict__ A, const unsigned short* __restrict__ B,
    const float* __restrict__ bias, const float* __restrict__ res,
    float* __restrict__ C, unsigned short* __restrict__ Cb, int M, int N, int K)
{
    __shared__ __align__(16) unsigned short As[128 * 32];
    __shared__ __align__(16) unsigned short Bs[64 * 32];

    const int t = threadIdx.x;
    const int lane = t & 63, wave = t >> 6;
    const int wr = wave >> 1, wc = wave & 1;
    const int lr = lane & 15, lk = lane >> 4;
    const int m0 = blockIdx.y * 128, n0 = blockIdx.x * 64;

    f32x4 acc[4][2] = {};

    for (int k0 = 0; k0 < K; k0 += 32) {
#pragma unroll
        for (int c = 0; c < 2; c++) {
            int bo = t * 16 + c * 4096;
            int row = bo >> 6;
            int col = (bo & 63) >> 1;
            __builtin_amdgcn_global_load_lds(
                (const AS1 void*)(A + (size_t)(m0 + row) * K + k0 + col),
                (AS3 void*)(As + (bo >> 1)), 16, 0, 0);
        }
        {
            int bo = t * 16;                   // 4KB B tile
            int row = bo >> 6;
            int col = (bo & 63) >> 1;
            __builtin_amdgcn_global_load_lds(
                (const AS1 void*)(B + (size_t)(n0 + row) * K + k0 + col),
                (AS3 void*)(Bs + (bo >> 1)), 16, 0, 0);
        }
        __syncthreads();

        bf16x8 af[4], bfr[2];
#pragma unroll
        for (int mi = 0; mi < 4; mi++)
            af[mi] = *(const bf16x8*)(As + (wr * 64 + mi * 16 + lr) * 32 + lk * 8);
#pragma unroll
        for (int nj = 0; nj < 2; nj++)
            bfr[nj] = *(const bf16x8*)(Bs + (wc * 32 + nj * 16 + lr) * 32 + lk * 8);
#pragma unroll
        for (int mi = 0; mi < 4; mi++)
#pragma unroll
            for (int nj = 0; nj < 2; nj++)
                acc[mi][nj] = __builtin_amdgcn_mfma_f32_16x16x32_bf16(
                    af[mi], bfr[nj], acc[mi][nj], 0, 0, 0);
        __syncthreads();
    }

#pragma unroll
    for (int nj = 0; nj < 2; nj++) {
        int col = n0 + wc * 32 + nj * 16 + lr;
        float bv = bias ? bias[col] : 0.f;
#pragma unroll
        for (int mi = 0; mi < 4; mi++) {
            int row = m0 + wr * 64 + mi * 16 + lk * 4;
#pragma unroll
            for (int j = 0; j < 4; j++) {
                int r = row + j;
                float v = acc[mi][nj][j] + bv;
                if (ACT) v = v * sigmoidf_(v - 1.f);
                size_t off = (size_t)r * N + col;
                if (RES) v += res[off];
                if (WF32) C[off] = v;
                if (WBF) Cb[off] = f2bf(v);
            }
        }
    }
}

// ---------------------------------------------------------------------------
// Split qkv (L,N,768): qu/qv/k -> bf16 (N,H,L,d); v -> bf16 transposed (N,H,d,L)
// ---------------------------------------------------------------------------
__global__ __launch_bounds__(256) void split_kernel(
    const float* __restrict__ qkv,
    const float* __restrict__ pbu, const float* __restrict__ pbv,
    unsigned short* __restrict__ qub, unsigned short* __restrict__ qvb,
    unsigned short* __restrict__ kb, unsigned short* __restrict__ vt)
{
    int idx = blockIdx.x * 256 + threadIdx.x;
    int dd = idx & 31;
    int l  = (idx >> 5) & 1023;
    int nh = idx >> 15;               // n*8+h
    int h  = nh & 7;
    int n  = nh >> 3;
    size_t base = ((size_t)l * 4 + n) * 768 + h * 32 + dd;
    float q = qkv[base];
    qub[idx] = f2bf(q + pbu[h * 32 + dd]);
    qvb[idx] = f2bf(q + pbv[h * 32 + dd]);
    kb[idx]  = f2bf(qkv[base + 256]);
    vt[(size_t)nh * 32768 + dd * 1024 + l] = f2bf(qkv[base + 512]);
}

// ---------------------------------------------------------------------------
// Repack p (m,h,d) fp32 -> p2 (h,m,d) bf16
// ---------------------------------------------------------------------------
__global__ __launch_bounds__(256) void repack_p_kernel(
    const float* __restrict__ pb, unsigned short* __restrict__ p2b)
{
    int idx = blockIdx.x * 256 + threadIdx.x;
    if (idx >= 2047 * 256) return;
    int dd = idx & 31;
    int h  = (idx >> 5) & 7;
    int m  = idx >> 8;
    p2b[((size_t)h * 2047 + m) * 32 + dd] = f2bf(pb[idx]);
}

// ---------------------------------------------------------------------------
// scores_kernel v4 (MFMA): totb[n,i,h,j] = bf16((ac + bd) * scale)
//   ac = Qu (64x32) @ K^T (32x64) via 16x16x32 MFMA (2x2 frags/wave)
//   bd de-shifted: C2[i,mm] = Qv[i].P[m_base+mm] (64x128), gather diag band.
// LDS: inputs 20KB union'd with AC(64x65 f32)+C2(64x130 f32) = 49.9KB.
// ---------------------------------------------------------------------------
__global__ __launch_bounds__(256) void scores_kernel(
    const unsigned short* __restrict__ qub_, const unsigned short* __restrict__ qvb_,
    const unsigned short* __restrict__ kb_, const unsigned short* __restrict__ p2b_,
    unsigned short* __restrict__ totb)
{
    __shared__ __align__(16) char smem[49920];
    unsigned short* Qu = (unsigned short*)smem;            // 4096 B
    unsigned short* Qv = (unsigned short*)(smem + 4096);   // 4096 B
    unsigned short* Kt = (unsigned short*)(smem + 8192);   // 4096 B
    unsigned short* Pt = (unsigned short*)(smem + 12288);  // 8192 B
    float* AC = (float*)smem;                              // 64*65*4 = 16640 B
    float* C2 = (float*)(smem + 16640);                    // 64*130*4 = 33280 B

    const int t = threadIdx.x;
    const int lane = t & 63, wave = t >> 6;
    const int wr = wave >> 1, wc = wave & 1;
    const int lr = lane & 15, lk = lane >> 4;
    const int j0 = blockIdx.x * 64, i0 = blockIdx.y * 64;
    const int nh = blockIdx.z;
    const int n = nh >> 3, h = nh & 7;
    const int m_base = 960 - i0 + j0;   // >= 0; rows m_base..m_base+126 used

    const unsigned short* qug = qub_ + ((size_t)nh * 1024 + i0) * 32;
    const unsigned short* qvg = qvb_ + ((size_t)nh * 1024 + i0) * 32;
    const unsigned short* kg  = kb_ + ((size_t)nh * 1024 + j0) * 32;
    const unsigned short* pg  = p2b_ + ((size_t)h * 2047 + m_base) * 32;

    __builtin_amdgcn_global_load_lds((const AS1 void*)(qug + t * 8),
                                     (AS3 void*)(Qu + t * 8), 16, 0, 0);
    __builtin_amdgcn_global_load_lds((const AS1 void*)(qvg + t * 8),
                                     (AS3 void*)(Qv + t * 8), 16, 0, 0);
    __builtin_amdgcn_global_load_lds((const AS1 void*)(kg + t * 8),
                                     (AS3 void*)(Kt + t * 8), 16, 0, 0);
#pragma unroll
    for (int c = 0; c < 2; c++)
        __builtin_amdgcn_global_load_lds((const AS1 void*)(pg + (t + 256 * c) * 8),
                                         (AS3 void*)(Pt + (t + 256 * c) * 8), 16, 0, 0);
    __syncthreads();

    // fragments (same lane mapping as validated mfma_gemm)
    bf16x8 aq[2], av[2], bk[2], bp[4];
#pragma unroll
    for (int f = 0; f < 2; f++) {
        aq[f] = *(const bf16x8*)(Qu + (wr * 32 + f * 16 + lr) * 32 + lk * 8);
        av[f] = *(const bf16x8*)(Qv + (wr * 32 + f * 16 + lr) * 32 + lk * 8);
        bk[f] = *(const bf16x8*)(Kt + (wc * 32 + f * 16 + lr) * 32 + lk * 8);
    }
#pragma unroll
    for (int f = 0; f < 4; f++)
        bp[f] = *(const bf16x8*)(Pt + (wc * 64 + f * 16 + lr) * 32 + lk * 8);

    f32x4 aacc[2][2] = {};
    f32x4 bacc[2][4] = {};
#pragma unroll
    for (int fi = 0; fi < 2; fi++) {
#pragma unroll
        for (int fj = 0; fj < 2; fj++)
            aacc[fi][fj] = __builtin_amdgcn_mfma_f32_16x16x32_bf16(
                aq[fi], bk[fj], aacc[fi][fj], 0, 0, 0);
#pragma unroll
        for (int fj = 0; fj < 4; fj++)
            bacc[fi][fj] = __builtin_amdgcn_mfma_f32_16x16x32_bf16(
                av[fi], bp[fj], bacc[fi][fj], 0, 0, 0);
    }
    __syncthreads();   // all input LDS reads complete before overwrite

    // C/D layout: col = lane&15, row = (lane>>4)*4 + jj
#pragma unroll
    for (int fi = 0; fi < 2; fi++)
#pragma unroll
        for (int fj = 0; fj < 2; fj++)
#pragma unroll
            for (int jj = 0; jj < 4; jj++)
                AC[(wr * 32 + fi * 16 + lk * 4 + jj) * 65 + wc * 32 + fj * 16 + lr]
                    = aacc[fi][fj][jj];
#pragma unroll
    for (int fi = 0; fi < 2; fi++)
#pragma unroll
        for (int fj = 0; fj < 4; fj++)
#pragma unroll
            for (int jj = 0; jj < 4; jj++)
                C2[(wr * 32 + fi * 16 + lk * 4 + jj) * 130 + wc * 64 + fj * 16 + lr]
                    = bacc[fi][fj][jj];
    __syncthreads();

    // gather band + write: thread -> row r = t>>2, cols q*16..q*16+15
    const float scale = 0.17677669529663687f;
    int r = t >> 2, q = t & 3;
    unsigned short ov[16];
#pragma unroll
    for (int c16 = 0; c16 < 16; c16++) {
        int c = q * 16 + c16;
        float v = AC[r * 65 + c] + C2[r * 130 + 63 + c - r];
        ov[c16] = f2bf(v * scale);
    }
    unsigned short* o = totb + (((size_t)(n * 1024 + i0 + r)) * 8 + h) * 1024 + j0 + q * 16;
    *(u16x8*)o = *(const u16x8*)&ov[0];
    *(u16x8*)(o + 8) = *(const u16x8*)&ov[8];
}

// ---------------------------------------------------------------------------
// attn_finish_kernel: 256 threads, 4 j-cols/thread, (n,i,h,j) layout,
// ALL global loads hoisted up front for max memory-level parallelism.
// ---------------------------------------------------------------------------
__global__ __launch_bounds__(256) void attn_finish_kernel(
    unsigned short* __restrict__ totb, const float* __restrict__ as_,
    const float* __restrict__ proj_in, const float* __restrict__ proj_out,
    float* __restrict__ out_s)
{
    __shared__ float pin_s[64], po_s[64];
    __shared__ float redbuf[4][8];

    const int t = threadIdx.x;
    const int n = blockIdx.x >> 10;
    const int i = blockIdx.x & 1023;
    const int j0 = t * 4;
    const int wave = t >> 6, lane = t & 63;

    if (t < 64) { pin_s[t] = proj_in[t]; po_s[t] = proj_out[t]; }

    unsigned short* tbase = totb + ((size_t)(n * 1024 + i)) * 8192;
    const float4* as4 = (const float4*)(as_ + (((size_t)n * 1024 + i) * 1024 + j0) * 8);
    float4* os4 = (float4*)(out_s + (((size_t)n * 1024 + i) * 1024 + j0) * 8);

    // ---- issue ALL loads up front (8 tot + 8 as_ per thread) ----
    ushort4 tu[8];
#pragma unroll
    for (int h = 0; h < 8; h++)
        tu[h] = *(const ushort4*)(tbase + h * 1024 + j0);
    float4 av4[8];
#pragma unroll
    for (int c = 0; c < 8; c++) av4[c] = as4[c];
    __syncthreads();   // pin_s/po_s ready

    float th[8][4];
#pragma unroll
    for (int h = 0; h < 8; h++) {
        th[h][0] = bf2f(tu[h].x); th[h][1] = bf2f(tu[h].y);
        th[h][2] = bf2f(tu[h].z); th[h][3] = bf2f(tu[h].w);
    }

#pragma unroll
    for (int jj = 0; jj < 4; jj++) {
        float4 alo = av4[jj * 2], ahi = av4[jj * 2 + 1];
        float ag[8] = {alo.x, alo.y, alo.z, alo.w, ahi.x, ahi.y, ahi.z, ahi.w};
#pragma unroll
        for (int h = 0; h < 8; h++) {
            float si = 0.f;
#pragma unroll
            for (int g = 0; g < 8; g++) si += ag[g] * pin_s[g * 8 + h];
            th[h][jj] += si;
        }
        float so[8];
#pragma unroll
        for (int g = 0; g < 8; g++) {
            float s = ag[g];
#pragma unroll
            for (int h = 0; h < 8; h++) s += th[h][jj] * po_s[h * 8 + g];
            so[g] = s;
        }
        float4 o0 = {so[0], so[1], so[2], so[3]};
        float4 o1 = {so[4], so[5], so[6], so[7]};
        os4[jj * 2] = o0;
        os4[jj * 2 + 1] = o1;
    }

    // softmax WITHOUT max subtraction (|th| <~ 15 << 88, fp32-safe)
    float sm[8];
#pragma unroll
    for (int h = 0; h < 8; h++) {
        float s = 0.f;
#pragma unroll
        for (int jj = 0; jj < 4; jj++) {
            th[h][jj] = __expf(th[h][jj]);
            s += th[h][jj];
        }
        sm[h] = s;
    }
#pragma unroll
    for (int d = 1; d < 64; d <<= 1)
#pragma unroll
        for (int h = 0; h < 8; h++) sm[h] += __shfl_xor(sm[h], d);
    if (lane == 0)
#pragma unroll
        for (int h = 0; h < 8; h++) redbuf[wave][h] = sm[h];
    __syncthreads();

#pragma unroll
    for (int h = 0; h < 8; h++) {
        float rs = 1.f / (redbuf[0][h] + redbuf[1][h] + redbuf[2][h] + redbuf[3][h]);
        ushort4 o = {f2bf(th[h][0] * rs), f2bf(th[h][1] * rs),
                     f2bf(th[h][2] * rs), f2bf(th[h][3] * rs)};
        *(ushort4*)(tbase + h * 1024 + j0) = o;
    }
}

// ---------------------------------------------------------------------------
// ctx_mfma_kernel: ctx[i,n,h*32+d] = sum_j attn[i,j]*vT[d,j] via MFMA
// attn layout (n,i,h,j); 128x32 tile per block; grid (8 i-tiles, 32 nh)
// ---------------------------------------------------------------------------
__global__ __launch_bounds__(256) void ctx_mfma_kernel(
    const unsigned short* __restrict__ attnb, const unsigned short* __restrict__ vt,
    unsigned short* __restrict__ ctx_b)
{
    __shared__ __align__(16) unsigned short As[128 * 32];
    __shared__ __align__(16) unsigned short Bs[32 * 32];

    const int t = threadIdx.x;
    const int lane = t & 63, wave = t >> 6;
    const int lr = lane & 15, lk = lane >> 4;
    const int i0 = blockIdx.x * 128;
    const int nh = blockIdx.y;
    const int n = nh >> 3, h = nh & 7;

    const unsigned short* Bbase = vt + (size_t)nh * 32768;

    f32x4 acc[2][2] = {};

    for (int k0 = 0; k0 < 1024; k0 += 32) {
#pragma unroll
        for (int c = 0; c < 2; c++) {
            int bo = t * 16 + c * 4096;
            int row = bo >> 6;
            int col = (bo & 63) >> 1;
            __builtin_amdgcn_global_load_lds(
                (const AS1 void*)(
                    attnb + (((size_t)(n * 1024 + i0 + row)) * 8 + h) * 1024 + k0 + col),
                (AS3 void*)(As + (bo >> 1)), 16, 0, 0);
        }
        if (t < 128) {
            int bo = t * 16;
            int row = bo >> 6;
            int col = (bo & 63) >> 1;
            __builtin_amdgcn_global_load_lds(
                (const AS1 void*)(Bbase + (size_t)row * 1024 + k0 + col),
                (AS3 void*)(Bs + (bo >> 1)), 16, 0, 0);
        }
        __syncthreads();

        bf16x8 af[2], bf_[2];
#pragma unroll
        for (int mi = 0; mi < 2; mi++)
            af[mi] = *(const bf16x8*)(As + (wave * 32 + mi * 16 + lr) * 32 + lk * 8);
#pragma unroll
        for (int nj = 0; nj < 2; nj++)
            bf_[nj] = *(const bf16x8*)(Bs + (nj * 16 + lr) * 32 + lk * 8);
#pragma unroll
        for (int mi = 0; mi < 2; mi++)
#pragma unroll
            for (int nj = 0; nj < 2; nj++)
                acc[mi][nj] = __builtin_amdgcn_mfma_f32_16x16x32_bf16(
                    af[mi], bf_[nj], acc[mi][nj], 0, 0, 0);
        __syncthreads();
    }

#pragma unroll
    for (int nj = 0; nj < 2; nj++) {
        int d = nj * 16 + lr;
#pragma unroll
        for (int mi = 0; mi < 2; mi++) {
            int ibase = i0 + wave * 32 + mi * 16 + lk * 4;
#pragma unroll
            for (int j = 0; j < 4; j++) {
                int i = ibase + j;
                ctx_b[((size_t)i * 4 + n) * 256 + h * 32 + d] = f2bf(acc[mi][nj][j]);
            }
        }
    }
}

// ---------------------------------------------------------------------------
// GLU (bf16 in -> bf16 out)
// ---------------------------------------------------------------------------
__global__ __launch_bounds__(256) void glu_kernel(
    const unsigned short* __restrict__ h1, unsigned short* __restrict__ g)
{
    int idx4 = blockIdx.x * 256 + threadIdx.x;     // over 4096*128
    int r = idx4 >> 7, c4 = idx4 & 127;
    const ushort4* row = (const ushort4*)(h1 + (size_t)r * 1024);
    ushort4 a = row[c4];
    ushort4 b = row[128 + c4];
    ushort4 o = {f2bf(bf2f(a.x) * sigmoidf_(bf2f(b.x))),
                 f2bf(bf2f(a.y) * sigmoidf_(bf2f(b.y))),
                 f2bf(bf2f(a.z) * sigmoidf_(bf2f(b.z))),
                 f2bf(bf2f(a.w) * sigmoidf_(bf2f(b.w)))};
    ((ushort4*)g)[idx4] = o;
}

// ---------------------------------------------------------------------------
// depthwise conv (K=31, pad 15) + bias + DoubleSwish; bf16 in -> bf16 out
// ---------------------------------------------------------------------------
__global__ __launch_bounds__(256) void dwconv_kernel(
    const unsigned short* __restrict__ g, const float* __restrict__ w_dw,
    const float* __restrict__ b_dw, unsigned short* __restrict__ out)
{
    int idx = blockIdx.x * 256 + threadIdx.x;
    int c = idx & 511;
    int r = idx >> 9;
    int nn = r & 3, l = r >> 2;
    float acc = b_dw[c];
#pragma unroll
    for (int kk = 0; kk < 31; kk++) {
        int l2 = l + kk - 15;
        if (l2 >= 0 && l2 < 1024)
            acc += bf2f(g[(((size_t)l2 * 4 + nn) << 9) + c]) * w_dw[c * 31 + kk];
    }
    out[idx] = f2bf(acc * sigmoidf_(acc - 1.f));
}

// ---------------------------------------------------------------------------
// BasicNorm
// ---------------------------------------------------------------------------
__global__ __launch_bounds__(256) void norm_kernel(
    const float* __restrict__ x, const float* __restrict__ eps_p,
    float* __restrict__ out)
{
    int r = blockIdx.x, t = threadIdx.x;
    float a = x[(size_t)r * 512 + t];
    float b = x[(size_t)r * 512 + 256 + t];
    float ss = a * a + b * b;
#pragma unroll
    for (int d = 1; d < 64; d <<= 1) ss += __shfl_xor(ss, d);
    __shared__ float red[4];
    if ((t & 63) == 0) red[t >> 6] = ss;
    __syncthreads();
    float tot = red[0] + red[1] + red[2] + red[3];
    float scale = rsqrtf(tot * (1.f / 512.f) + __expf(eps_p[0]));
    out[(size_t)r * 512 + t] = a * scale;
    out[(size_t)r * 512 + 256 + t] = b * scale;
}

// ---------------------------------------------------------------------------
extern "C" void kernel_launch(void* const* d_in, const int* in_sizes, int n_in,
                              void* d_out, int out_size, void* d_ws, size_t ws_size,
                              hipStream_t stream)
{
    const float* src   = (const float*)d_in[0];
    const float* pos   = (const float*)d_in[1];
    const float* as_   = (const float*)d_in[2];
    const float* w_in  = (const float*)d_in[3];
    const float* b_in  = (const float*)d_in[4];
    const float* w_pos = (const float*)d_in[5];
    const float* pbu   = (const float*)d_in[6];
    const float* pbv   = (const float*)d_in[7];
    const float* prin  = (const float*)d_in[8];
    const float* prout = (const float*)d_in[9];
    const float* w_out = (const float*)d_in[10];
    const float* b_out = (const float*)d_in[11];
    const float* w_ff1m = (const float*)d_in[12];
    const float* b_ff1m = (const float*)d_in[13];
    const float* w_ff2m = (const float*)d_in[14];
    const float* b_ff2m = (const float*)d_in[15];
    const float* w_ff1 = (const float*)d_in[16];
    const float* b_ff1 = (const float*)d_in[17];
    const float* w_ff2 = (const float*)d_in[18];
    const float* b_ff2 = (const float*)d_in[19];
    const float* w_pw1 = (const float*)d_in[20];
    const float* b_pw1 = (const float*)d_in[21];
    const float* w_dw  = (const float*)d_in[22];
    const float* b_dw  = (const float*)d_in[23];
    const float* w_pw2 = (const float*)d_in[24];
    const float* b_pw2 = (const float*)d_in[25];
    const float* neps  = (const float*)d_in[26];

    float* out_x = (float*)d_out;
    float* out_s = (float*)d_out + 2097152;

    // ---- workspace layout (float units) ----
    float* ws = (float*)d_ws;
    float* xbuf = ws;                               // 2,097,152
    float* U    = xbuf + 2097152;                   // 6,291,456
    float* sbbf = U + 6291456;                      // 1,048,576
    float* xb16f= sbbf + 1048576;                   // 1,048,576
    float* qkvb = xb16f + 1048576;                  // 3,145,728 (later p2b)
    float* qu   = qkvb + 3145728;                   // 1,048,576 (later ctxb)
    float* qv   = qu + 1048576;                     // 1,048,576
    float* kbuf = qv + 1048576;                     // 1,048,576
    float* vbuf = kbuf + 1048576;                   // 1,048,576 (vt bf16)
    float* pbuf = vbuf + 1048576;                   // 524,288
    float* posbf= pbuf + 524288;                    // 524,288
    float* totf = posbf + 524288;                   // 16,777,216
    float* Wreg = totf + 16777216;                  // weights bf16 region

    unsigned short* hb16  = (unsigned short*)U;
    unsigned short* gbuf  = (unsigned short*)(U + 4194304);
    unsigned short* sbb   = (unsigned short*)sbbf;
    unsigned short* dbufb = (unsigned short*)sbbf;
    unsigned short* xb16  = (unsigned short*)xb16f;
    unsigned short* ctxb  = (unsigned short*)qu;
    unsigned short* posb  = (unsigned short*)posbf;
    unsigned short* totb  = (unsigned short*)totf;
    unsigned short* vt    = (unsigned short*)vbuf;
    unsigned short* qub   = (unsigned short*)qu;
    unsigned short* qvb   = (unsigned short*)qv;
    unsigned short* kb    = (unsigned short*)kbuf;
    unsigned short* p2b   = (unsigned short*)qkvb;

    // per-weight bf16 buffers
    float* wp = Wreg;
    unsigned short* wff1m_b = (unsigned short*)wp; wp += 524288;
    unsigned short* wff2m_b = (unsigned short*)wp; wp += 524288;
    unsigned short* win_b   = (unsigned short*)wp; wp += 196608;
    unsigned short* wpos_b  = (unsigned short*)wp; wp += 65536;
    unsigned short* wout_b  = (unsigned short*)wp; wp += 65536;
    unsigned short* wpw1_b  = (unsigned short*)wp; wp += 262144;
    unsigned short* wpw2_b  = (unsigned short*)wp; wp += 131072;
    unsigned short* wff1_b  = (unsigned short*)wp; wp += 524288;
    unsigned short* wff2_b  = (unsigned short*)wp; wp += 524288;

    dim3 blk(256);
    const int M = 4096;

    // --- one mega-cast for src, pos, and all weights ---
    {
        CastJobs jobs;
        const float* srcs[11] = {src, pos, w_ff1m, w_ff2m, w_in, w_pos,
                                 w_out, w_pw1, w_pw2, w_ff1, w_ff2};
        unsigned short* dsts[11] = {sbb, posb, wff1m_b, wff2m_b, win_b, wpos_b,
                                    wout_b, wpw1_b, wpw2_b, wff1_b, wff2_b};
        int n4s[11] = {524288, 262016, 262144, 262144, 98304, 32768,
                       32768, 131072, 65536, 262144, 262144};
        int cum = 0;
        for (int s = 0; s < 11; s++) {
            jobs.src[s] = (const float4*)srcs[s];
            jobs.dst[s] = (ushort4*)dsts[s];
            cum += n4s[s];
            jobs.end[s] = cum;
        }
        cast_all_kernel<<<(cum + 255) / 256, blk, 0, stream>>>(jobs, cum);
    }

    // --- macaron FFN ---
    mfma_gemm<1,0,0,1><<<dim3(16, 32), blk, 0, stream>>>(
        sbb, wff1m_b, b_ff1m, nullptr, nullptr, hb16, M, 2048, 512);
    mfma_gemm_n64<0,1,1,1><<<dim3(8, 32), blk, 0, stream>>>(
        hb16, wff2m_b, b_ff2m, src, xbuf, xb16, M, 512, 2048);

    // --- attention ---
    mfma_gemm_n64<0,0,1,0><<<dim3(12, 32), blk, 0, stream>>>(
        xb16, win_b, b_in, nullptr, qkvb, nullptr, M, 768, 512);
    split_kernel<<<4096, blk, 0, stream>>>(qkvb, pbu, pbv, qub, qvb, kb, vt);
    mfma_gemm<0,0,1,0><<<dim3(2, 16), blk, 0, stream>>>(
        posb, wpos_b, nullptr, nullptr, pbuf, nullptr, 2047, 256, 512);
    repack_p_kernel<<<2047, blk, 0, stream>>>(pbuf, p2b);
    scores_kernel<<<dim3(16, 16, 32), blk, 0, stream>>>(qub, qvb, kb, p2b, totb);
    attn_finish_kernel<<<4096, blk, 0, stream>>>(totb, as_, prin, prout, out_s);
    ctx_mfma_kernel<<<dim3(8, 32), blk, 0, stream>>>(totb, vt, ctxb);
    mfma_gemm_n64<0,1,1,1><<<dim3(8, 32), blk, 0, stream>>>(
        ctxb, wout_b, b_out, xbuf, xbuf, xb16, M, 512, 256);

    // --- conv module ---
    mfma_gemm<0,0,0,1><<<dim3(8, 32), blk, 0, stream>>>(
        xb16, wpw1_b, b_pw1, nullptr, nullptr, hb16, M, 1024, 512);
    glu_kernel<<<2048, blk, 0, stream>>>(hb16, gbuf);
    dwconv_kernel<<<8192, blk, 0, stream>>>(gbuf, w_dw, b_dw, dbufb);
    mfma_gemm_n64<0,1,1,1><<<dim3(8, 32), blk, 0, stream>>>(
        dbufb, wpw2_b, b_pw2, xbuf, xbuf, xb16, M, 512, 512);

    // --- final FFN + BasicNorm ---
    mfma_gemm<1,0,0,1><<<dim3(16, 32), blk, 0, stream>>>(
        xb16, wff1_b, b_ff1, nullptr, nullptr, hb16, M, 2048, 512);
    mfma_gemm_n64<0,1,1,0><<<dim3(8, 32), blk, 0, stream>>>(
        hb16, wff2_b, b_ff2, xbuf, xbuf, nullptr, M, 512, 2048);
    norm_kernel<<<4096, blk, 0, stream>>>(xbuf, neps, out_x);
}

// Round 20
// 485.770 us; speedup vs baseline: 2.1110x; 1.0141x over previous
//
#include <hip/hip_runtime.h>

#define DEV_INLINE __device__ __forceinline__
#define AS1 __attribute__((address_space(1)))
#define AS3 __attribute__((address_space(3)))

typedef short bf16x8 __attribute__((ext_vector_type(8)));
typedef float f32x4 __attribute__((ext_vector_type(4)));
typedef unsigned short u16x8 __attribute__((ext_vector_type(8)));

DEV_INLINE float sigmoidf_(float x) { return 1.f / (1.f + __expf(-x)); }
DEV_INLINE unsigned short f2bf(float x) {
    unsigned int u = __float_as_uint(x);
    unsigned int r = (u + 0x7FFFu + ((u >> 16) & 1u)) >> 16;
    return (unsigned short)r;
}
DEV_INLINE float bf2f(unsigned short u) {
    return __uint_as_float(((unsigned int)u) << 16);
}

// ---------------------------------------------------------------------------
// mega-cast: all fp32->bf16 casts in one launch
// ---------------------------------------------------------------------------
struct CastJobs {
    const float4* src[11];
    ushort4* dst[11];
    int end[11];
};

__global__ __launch_bounds__(256) void cast_all_kernel(CastJobs jobs, int total4)
{
    int gi = blockIdx.x * 256 + threadIdx.x;
    if (gi >= total4) return;
    int s = 0, base = 0;
    while (gi >= jobs.end[s]) { base = jobs.end[s]; s++; }
    int li = gi - base;
    float4 v = jobs.src[s][li];
    ushort4 o = {f2bf(v.x), f2bf(v.y), f2bf(v.z), f2bf(v.w)};
    jobs.dst[s][li] = o;
}

// ---------------------------------------------------------------------------
// bf16 MFMA GEMM (m97 structure), 128x128 tile
// ---------------------------------------------------------------------------
template<int ACT, int RES, int WF32, int WBF>
__global__ __launch_bounds__(256) void mfma_gemm(
    const unsigned short* __restrict__ A, const unsigned short* __restrict__ B,
    const float* __restrict__ bias, const float* __restrict__ res,
    float* __restrict__ C, unsigned short* __restrict__ Cb, int M, int N, int K)
{
    __shared__ __align__(16) unsigned short As[128 * 32];
    __shared__ __align__(16) unsigned short Bs[128 * 32];

    const int t = threadIdx.x;
    const int lane = t & 63, wave = t >> 6;
    const int wr = wave >> 1, wc = wave & 1;
    const int lr = lane & 15, lk = lane >> 4;
    const int m0 = blockIdx.y * 128, n0 = blockIdx.x * 128;

    f32x4 acc[4][4] = {};

    for (int k0 = 0; k0 < K; k0 += 32) {
#pragma unroll
        for (int c = 0; c < 2; c++) {
            int bo = t * 16 + c * 4096;
            int row = bo >> 6;
            int col = (bo & 63) >> 1;
            __builtin_amdgcn_global_load_lds(
                (const AS1 void*)(A + (size_t)(m0 + row) * K + k0 + col),
                (AS3 void*)(As + (bo >> 1)), 16, 0, 0);
            __builtin_amdgcn_global_load_lds(
                (const AS1 void*)(B + (size_t)(n0 + row) * K + k0 + col),
                (AS3 void*)(Bs + (bo >> 1)), 16, 0, 0);
        }
        __syncthreads();

        bf16x8 af[4], bfr[4];
#pragma unroll
        for (int mi = 0; mi < 4; mi++)
            af[mi] = *(const bf16x8*)(As + (wr * 64 + mi * 16 + lr) * 32 + lk * 8);
#pragma unroll
        for (int nj = 0; nj < 4; nj++)
            bfr[nj] = *(const bf16x8*)(Bs + (wc * 64 + nj * 16 + lr) * 32 + lk * 8);
#pragma unroll
        for (int mi = 0; mi < 4; mi++)
#pragma unroll
            for (int nj = 0; nj < 4; nj++)
                acc[mi][nj] = __builtin_amdgcn_mfma_f32_16x16x32_bf16(
                    af[mi], bfr[nj], acc[mi][nj], 0, 0, 0);
        __syncthreads();
    }

#pragma unroll
    for (int nj = 0; nj < 4; nj++) {
        int col = n0 + wc * 64 + nj * 16 + lr;
        float bv = bias ? bias[col] : 0.f;
#pragma unroll
        for (int mi = 0; mi < 4; mi++) {
            int row = m0 + wr * 64 + mi * 16 + lk * 4;
#pragma unroll
            for (int j = 0; j < 4; j++) {
                int r = row + j;
                if (r >= M) continue;
                float v = acc[mi][nj][j] + bv;
                if (ACT) v = v * sigmoidf_(v - 1.f);
                size_t off = (size_t)r * N + col;
                if (RES) v += res[off];
                if (WF32) C[off] = v;
                if (WBF) Cb[off] = f2bf(v);
            }
        }
    }
}

// ---------------------------------------------------------------------------
// bf16 MFMA GEMM, 128x64 tile (for small-N GEMMs: doubles grid occupancy)
// ---------------------------------------------------------------------------
template<int ACT, int RES, int WF32, int WBF>
__global__ __launch_bounds__(256) void mfma_gemm_n64(
    const unsigned short* __restrict__ A, const unsigned short* __restrict__ B,
    const float* __restrict__ bias, const float* __restrict__ res,
    float* __restrict__ C, unsigned short* __restrict__ Cb, int M, int N, int K)
{
    __shared__ __align__(16) unsigned short As[128 * 32];
    __shared__ __align__(16) unsigned short Bs[64 * 32];

    const int t = threadIdx.x;
    const int lane = t & 63, wave = t >> 6;
    const int wr = wave >> 1, wc = wave & 1;
    const int lr = lane & 15, lk = lane >> 4;
    const int m0 = blockIdx.y * 128, n0 = blockIdx.x * 64;

    f32x4 acc[4][2] = {};

    for (int k0 = 0; k0 < K; k0 += 32) {
#pragma unroll
        for (int c = 0; c < 2; c++) {
            int bo = t * 16 + c * 4096;
            int row = bo >> 6;
            int col = (bo & 63) >> 1;
            __builtin_amdgcn_global_load_lds(
                (const AS1 void*)(A + (size_t)(m0 + row) * K + k0 + col),
                (AS3 void*)(As + (bo >> 1)), 16, 0, 0);
        }
        {
            int bo = t * 16;                   // 4KB B tile
            int row = bo >> 6;
            int col = (bo & 63) >> 1;
            __builtin_amdgcn_global_load_lds(
                (const AS1 void*)(B + (size_t)(n0 + row) * K + k0 + col),
                (AS3 void*)(Bs + (bo >> 1)), 16, 0, 0);
        }
        __syncthreads();

        bf16x8 af[4], bfr[2];
#pragma unroll
        for (int mi = 0; mi < 4; mi++)
            af[mi] = *(const bf16x8*)(As + (wr * 64 + mi * 16 + lr) * 32 + lk * 8);
#pragma unroll
        for (int nj = 0; nj < 2; nj++)
            bfr[nj] = *(const bf16x8*)(Bs + (wc * 32 + nj * 16 + lr) * 32 + lk * 8);
#pragma unroll
        for (int mi = 0; mi < 4; mi++)
#pragma unroll
            for (int nj = 0; nj < 2; nj++)
                acc[mi][nj] = __builtin_amdgcn_mfma_f32_16x16x32_bf16(
                    af[mi], bfr[nj], acc[mi][nj], 0, 0, 0);
        __syncthreads();
    }

#pragma unroll
    for (int nj = 0; nj < 2; nj++) {
        int col = n0 + wc * 32 + nj * 16 + lr;
        float bv = bias ? bias[col] : 0.f;
#pragma unroll
        for (int mi = 0; mi < 4; mi++) {
            int row = m0 + wr * 64 + mi * 16 + lk * 4;
#pragma unroll
            for (int j = 0; j < 4; j++) {
                int r = row + j;
                float v = acc[mi][nj][j] + bv;
                if (ACT) v = v * sigmoidf_(v - 1.f);
                size_t off = (size_t)r * N + col;
                if (RES) v += res[off];
                if (WF32) C[off] = v;
                if (WBF) Cb[off] = f2bf(v);
            }
        }
    }
}

// ---------------------------------------------------------------------------
// qkv GEMM with fused split epilogue: N=768 fixed, K=512.
// col -> (part,h,dd); writes qub/qvb (+pos biases), kb, vt directly (bf16).
// ---------------------------------------------------------------------------
__global__ __launch_bounds__(256) void mfma_gemm_qkv(
    const unsigned short* __restrict__ A, const unsigned short* __restrict__ B,
    const float* __restrict__ bias,
    const float* __restrict__ pbu, const float* __restrict__ pbv,
    unsigned short* __restrict__ qub, unsigned short* __restrict__ qvb,
    unsigned short* __restrict__ kb, unsigned short* __restrict__ vt)
{
    __shared__ __align__(16) unsigned short As[128 * 32];
    __shared__ __align__(16) unsigned short Bs[64 * 32];

    const int t = threadIdx.x;
    const int lane = t & 63, wave = t >> 6;
    const int wr = wave >> 1, wc = wave & 1;
    const int lr = lane & 15, lk = lane >> 4;
    const int m0 = blockIdx.y * 128, n0 = blockIdx.x * 64;
    const int K = 512;

    f32x4 acc[4][2] = {};

    for (int k0 = 0; k0 < K; k0 += 32) {
#pragma unroll
        for (int c = 0; c < 2; c++) {
            int bo = t * 16 + c * 4096;
            int row = bo >> 6;
            int col = (bo & 63) >> 1;
            __builtin_amdgcn_global_load_lds(
                (const AS1 void*)(A + (size_t)(m0 + row) * K + k0 + col),
                (AS3 void*)(As + (bo >> 1)), 16, 0, 0);
        }
        {
            int bo = t * 16;
            int row = bo >> 6;
            int col = (bo & 63) >> 1;
            __builtin_amdgcn_global_load_lds(
                (const AS1 void*)(B + (size_t)(n0 + row) * K + k0 + col),
                (AS3 void*)(Bs + (bo >> 1)), 16, 0, 0);
        }
        __syncthreads();

        bf16x8 af[4], bfr[2];
#pragma unroll
        for (int mi = 0; mi < 4; mi++)
            af[mi] = *(const bf16x8*)(As + (wr * 64 + mi * 16 + lr) * 32 + lk * 8);
#pragma unroll
        for (int nj = 0; nj < 2; nj++)
            bfr[nj] = *(const bf16x8*)(Bs + (wc * 32 + nj * 16 + lr) * 32 + lk * 8);
#pragma unroll
        for (int mi = 0; mi < 4; mi++)
#pragma unroll
            for (int nj = 0; nj < 2; nj++)
                acc[mi][nj] = __builtin_amdgcn_mfma_f32_16x16x32_bf16(
                    af[mi], bfr[nj], acc[mi][nj], 0, 0, 0);
        __syncthreads();
    }

#pragma unroll
    for (int nj = 0; nj < 2; nj++) {
        int col = n0 + wc * 32 + nj * 16 + lr;        // [0,768)
        float bv = bias[col];
        int part = col >> 8;          // 0:q 1:k 2:v
        int h = (col >> 5) & 7;
        int dd = col & 31;
        float bu = (part == 0) ? pbu[h * 32 + dd] : 0.f;
        float bvv = (part == 0) ? pbv[h * 32 + dd] : 0.f;
#pragma unroll
        for (int mi = 0; mi < 4; mi++) {
            int row = m0 + wr * 64 + mi * 16 + lk * 4;
#pragma unroll
            for (int j = 0; j < 4; j++) {
                int r = row + j;          // l*4+n
                float v = acc[mi][nj][j] + bv;
                int l = r >> 2, nn = r & 3;
                size_t nhl = ((size_t)(nn * 8 + h) * 1024 + l);
                if (part == 0) {
                    qub[nhl * 32 + dd] = f2bf(v + bu);
                    qvb[nhl * 32 + dd] = f2bf(v + bvv);
                } else if (part == 1) {
                    kb[nhl * 32 + dd] = f2bf(v);
                } else {
                    vt[(size_t)(nn * 8 + h) * 32768 + dd * 1024 + l] = f2bf(v);
                }
            }
        }
    }
}

// ---------------------------------------------------------------------------
// Repack p (m,h,d) fp32 -> p2 (h,m,d) bf16
// ---------------------------------------------------------------------------
__global__ __launch_bounds__(256) void repack_p_kernel(
    const float* __restrict__ pb, unsigned short* __restrict__ p2b)
{
    int idx = blockIdx.x * 256 + threadIdx.x;
    if (idx >= 2047 * 256) return;
    int dd = idx & 31;
    int h  = (idx >> 5) & 7;
    int m  = idx >> 8;
    p2b[((size_t)h * 2047 + m) * 32 + dd] = f2bf(pb[idx]);
}

// ---------------------------------------------------------------------------
// scores_kernel v4 (MFMA): totb[n,i,h,j] = bf16((ac + bd) * scale)
// ---------------------------------------------------------------------------
__global__ __launch_bounds__(256) void scores_kernel(
    const unsigned short* __restrict__ qub_, const unsigned short* __restrict__ qvb_,
    const unsigned short* __restrict__ kb_, const unsigned short* __restrict__ p2b_,
    unsigned short* __restrict__ totb)
{
    __shared__ __align__(16) char smem[49920];
    unsigned short* Qu = (unsigned short*)smem;            // 4096 B
    unsigned short* Qv = (unsigned short*)(smem + 4096);   // 4096 B
    unsigned short* Kt = (unsigned short*)(smem + 8192);   // 4096 B
    unsigned short* Pt = (unsigned short*)(smem + 12288);  // 8192 B
    float* AC = (float*)smem;                              // 64*65*4 = 16640 B
    float* C2 = (float*)(smem + 16640);                    // 64*130*4 = 33280 B

    const int t = threadIdx.x;
    const int lane = t & 63, wave = t >> 6;
    const int wr = wave >> 1, wc = wave & 1;
    const int lr = lane & 15, lk = lane >> 4;
    const int j0 = blockIdx.x * 64, i0 = blockIdx.y * 64;
    const int nh = blockIdx.z;
    const int n = nh >> 3, h = nh & 7;
    const int m_base = 960 - i0 + j0;   // >= 0; rows m_base..m_base+126 used

    const unsigned short* qug = qub_ + ((size_t)nh * 1024 + i0) * 32;
    const unsigned short* qvg = qvb_ + ((size_t)nh * 1024 + i0) * 32;
    const unsigned short* kg  = kb_ + ((size_t)nh * 1024 + j0) * 32;
    const unsigned short* pg  = p2b_ + ((size_t)h * 2047 + m_base) * 32;

    __builtin_amdgcn_global_load_lds((const AS1 void*)(qug + t * 8),
                                     (AS3 void*)(Qu + t * 8), 16, 0, 0);
    __builtin_amdgcn_global_load_lds((const AS1 void*)(qvg + t * 8),
                                     (AS3 void*)(Qv + t * 8), 16, 0, 0);
    __builtin_amdgcn_global_load_lds((const AS1 void*)(kg + t * 8),
                                     (AS3 void*)(Kt + t * 8), 16, 0, 0);
#pragma unroll
    for (int c = 0; c < 2; c++)
        __builtin_amdgcn_global_load_lds((const AS1 void*)(pg + (t + 256 * c) * 8),
                                         (AS3 void*)(Pt + (t + 256 * c) * 8), 16, 0, 0);
    __syncthreads();

    bf16x8 aq[2], av[2], bk[2], bp[4];
#pragma unroll
    for (int f = 0; f < 2; f++) {
        aq[f] = *(const bf16x8*)(Qu + (wr * 32 + f * 16 + lr) * 32 + lk * 8);
        av[f] = *(const bf16x8*)(Qv + (wr * 32 + f * 16 + lr) * 32 + lk * 8);
        bk[f] = *(const bf16x8*)(Kt + (wc * 32 + f * 16 + lr) * 32 + lk * 8);
    }
#pragma unroll
    for (int f = 0; f < 4; f++)
        bp[f] = *(const bf16x8*)(Pt + (wc * 64 + f * 16 + lr) * 32 + lk * 8);

    f32x4 aacc[2][2] = {};
    f32x4 bacc[2][4] = {};
#pragma unroll
    for (int fi = 0; fi < 2; fi++) {
#pragma unroll
        for (int fj = 0; fj < 2; fj++)
            aacc[fi][fj] = __builtin_amdgcn_mfma_f32_16x16x32_bf16(
                aq[fi], bk[fj], aacc[fi][fj], 0, 0, 0);
#pragma unroll
        for (int fj = 0; fj < 4; fj++)
            bacc[fi][fj] = __builtin_amdgcn_mfma_f32_16x16x32_bf16(
                av[fi], bp[fj], bacc[fi][fj], 0, 0, 0);
    }
    __syncthreads();

#pragma unroll
    for (int fi = 0; fi < 2; fi++)
#pragma unroll
        for (int fj = 0; fj < 2; fj++)
#pragma unroll
            for (int jj = 0; jj < 4; jj++)
                AC[(wr * 32 + fi * 16 + lk * 4 + jj) * 65 + wc * 32 + fj * 16 + lr]
                    = aacc[fi][fj][jj];
#pragma unroll
    for (int fi = 0; fi < 2; fi++)
#pragma unroll
        for (int fj = 0; fj < 4; fj++)
#pragma unroll
            for (int jj = 0; jj < 4; jj++)
                C2[(wr * 32 + fi * 16 + lk * 4 + jj) * 130 + wc * 64 + fj * 16 + lr]
                    = bacc[fi][fj][jj];
    __syncthreads();

    const float scale = 0.17677669529663687f;
    int r = t >> 2, q = t & 3;
    unsigned short ov[16];
#pragma unroll
    for (int c16 = 0; c16 < 16; c16++) {
        int c = q * 16 + c16;
        float v = AC[r * 65 + c] + C2[r * 130 + 63 + c - r];
        ov[c16] = f2bf(v * scale);
    }
    unsigned short* o = totb + (((size_t)(n * 1024 + i0 + r)) * 8 + h) * 1024 + j0 + q * 16;
    *(u16x8*)o = *(const u16x8*)&ov[0];
    *(u16x8*)(o + 8) = *(const u16x8*)&ov[8];
}

// ---------------------------------------------------------------------------
// attn_finish_kernel: 256 threads, 4 j-cols/thread, (n,i,h,j) layout,
// ALL global loads hoisted up front for max memory-level parallelism.
// ---------------------------------------------------------------------------
__global__ __launch_bounds__(256) void attn_finish_kernel(
    unsigned short* __restrict__ totb, const float* __restrict__ as_,
    const float* __restrict__ proj_in, const float* __restrict__ proj_out,
    float* __restrict__ out_s)
{
    __shared__ float pin_s[64], po_s[64];
    __shared__ float redbuf[4][8];

    const int t = threadIdx.x;
    const int n = blockIdx.x >> 10;
    const int i = blockIdx.x & 1023;
    const int j0 = t * 4;
    const int wave = t >> 6, lane = t & 63;

    if (t < 64) { pin_s[t] = proj_in[t]; po_s[t] = proj_out[t]; }

    unsigned short* tbase = totb + ((size_t)(n * 1024 + i)) * 8192;
    const float4* as4 = (const float4*)(as_ + (((size_t)n * 1024 + i) * 1024 + j0) * 8);
    float4* os4 = (float4*)(out_s + (((size_t)n * 1024 + i) * 1024 + j0) * 8);

    ushort4 tu[8];
#pragma unroll
    for (int h = 0; h < 8; h++)
        tu[h] = *(const ushort4*)(tbase + h * 1024 + j0);
    float4 av4[8];
#pragma unroll
    for (int c = 0; c < 8; c++) av4[c] = as4[c];
    __syncthreads();

    float th[8][4];
#pragma unroll
    for (int h = 0; h < 8; h++) {
        th[h][0] = bf2f(tu[h].x); th[h][1] = bf2f(tu[h].y);
        th[h][2] = bf2f(tu[h].z); th[h][3] = bf2f(tu[h].w);
    }

#pragma unroll
    for (int jj = 0; jj < 4; jj++) {
        float4 alo = av4[jj * 2], ahi = av4[jj * 2 + 1];
        float ag[8] = {alo.x, alo.y, alo.z, alo.w, ahi.x, ahi.y, ahi.z, ahi.w};
#pragma unroll
        for (int h = 0; h < 8; h++) {
            float si = 0.f;
#pragma unroll
            for (int g = 0; g < 8; g++) si += ag[g] * pin_s[g * 8 + h];
            th[h][jj] += si;
        }
        float so[8];
#pragma unroll
        for (int g = 0; g < 8; g++) {
            float s = ag[g];
#pragma unroll
            for (int h = 0; h < 8; h++) s += th[h][jj] * po_s[h * 8 + g];
            so[g] = s;
        }
        float4 o0 = {so[0], so[1], so[2], so[3]};
        float4 o1 = {so[4], so[5], so[6], so[7]};
        os4[jj * 2] = o0;
        os4[jj * 2 + 1] = o1;
    }

    float sm[8];
#pragma unroll
    for (int h = 0; h < 8; h++) {
        float s = 0.f;
#pragma unroll
        for (int jj = 0; jj < 4; jj++) {
            th[h][jj] = __expf(th[h][jj]);
            s += th[h][jj];
        }
        sm[h] = s;
    }
#pragma unroll
    for (int d = 1; d < 64; d <<= 1)
#pragma unroll
        for (int h = 0; h < 8; h++) sm[h] += __shfl_xor(sm[h], d);
    if (lane == 0)
#pragma unroll
        for (int h = 0; h < 8; h++) redbuf[wave][h] = sm[h];
    __syncthreads();

#pragma unroll
    for (int h = 0; h < 8; h++) {
        float rs = 1.f / (redbuf[0][h] + redbuf[1][h] + redbuf[2][h] + redbuf[3][h]);
        ushort4 o = {f2bf(th[h][0] * rs), f2bf(th[h][1] * rs),
                     f2bf(th[h][2] * rs), f2bf(th[h][3] * rs)};
        *(ushort4*)(tbase + h * 1024 + j0) = o;
    }
}

// ---------------------------------------------------------------------------
// ctx_mfma_kernel: ctx[i,n,h*32+d] = sum_j attn[i,j]*vT[d,j] via MFMA
// ---------------------------------------------------------------------------
__global__ __launch_bounds__(256) void ctx_mfma_kernel(
    const unsigned short* __restrict__ attnb, const unsigned short* __restrict__ vt,
    unsigned short* __restrict__ ctx_b)
{
    __shared__ __align__(16) unsigned short As[128 * 32];
    __shared__ __align__(16) unsigned short Bs[32 * 32];

    const int t = threadIdx.x;
    const int lane = t & 63, wave = t >> 6;
    const int lr = lane & 15, lk = lane >> 4;
    const int i0 = blockIdx.x * 128;
    const int nh = blockIdx.y;
    const int n = nh >> 3, h = nh & 7;

    const unsigned short* Bbase = vt + (size_t)nh * 32768;

    f32x4 acc[2][2] = {};

    for (int k0 = 0; k0 < 1024; k0 += 32) {
#pragma unroll
        for (int c = 0; c < 2; c++) {
            int bo = t * 16 + c * 4096;
            int row = bo >> 6;
            int col = (bo & 63) >> 1;
            __builtin_amdgcn_global_load_lds(
                (const AS1 void*)(
                    attnb + (((size_t)(n * 1024 + i0 + row)) * 8 + h) * 1024 + k0 + col),
                (AS3 void*)(As + (bo >> 1)), 16, 0, 0);
        }
        if (t < 128) {
            int bo = t * 16;
            int row = bo >> 6;
            int col = (bo & 63) >> 1;
            __builtin_amdgcn_global_load_lds(
                (const AS1 void*)(Bbase + (size_t)row * 1024 + k0 + col),
                (AS3 void*)(Bs + (bo >> 1)), 16, 0, 0);
        }
        __syncthreads();

        bf16x8 af[2], bf_[2];
#pragma unroll
        for (int mi = 0; mi < 2; mi++)
            af[mi] = *(const bf16x8*)(As + (wave * 32 + mi * 16 + lr) * 32 + lk * 8);
#pragma unroll
        for (int nj = 0; nj < 2; nj++)
            bf_[nj] = *(const bf16x8*)(Bs + (nj * 16 + lr) * 32 + lk * 8);
#pragma unroll
        for (int mi = 0; mi < 2; mi++)
#pragma unroll
            for (int nj = 0; nj < 2; nj++)
                acc[mi][nj] = __builtin_amdgcn_mfma_f32_16x16x32_bf16(
                    af[mi], bf_[nj], acc[mi][nj], 0, 0, 0);
        __syncthreads();
    }

#pragma unroll
    for (int nj = 0; nj < 2; nj++) {
        int d = nj * 16 + lr;
#pragma unroll
        for (int mi = 0; mi < 2; mi++) {
            int ibase = i0 + wave * 32 + mi * 16 + lk * 4;
#pragma unroll
            for (int j = 0; j < 4; j++) {
                int i = ibase + j;
                ctx_b[((size_t)i * 4 + n) * 256 + h * 32 + d] = f2bf(acc[mi][nj][j]);
            }
        }
    }
}

// ---------------------------------------------------------------------------
// GLU (bf16 in -> bf16 out)
// ---------------------------------------------------------------------------
__global__ __launch_bounds__(256) void glu_kernel(
    const unsigned short* __restrict__ h1, unsigned short* __restrict__ g)
{
    int idx4 = blockIdx.x * 256 + threadIdx.x;     // over 4096*128
    int r = idx4 >> 7, c4 = idx4 & 127;
    const ushort4* row = (const ushort4*)(h1 + (size_t)r * 1024);
    ushort4 a = row[c4];
    ushort4 b = row[128 + c4];
    ushort4 o = {f2bf(bf2f(a.x) * sigmoidf_(bf2f(b.x))),
                 f2bf(bf2f(a.y) * sigmoidf_(bf2f(b.y))),
                 f2bf(bf2f(a.z) * sigmoidf_(bf2f(b.z))),
                 f2bf(bf2f(a.w) * sigmoidf_(bf2f(b.w)))};
    ((ushort4*)g)[idx4] = o;
}

// ---------------------------------------------------------------------------
// depthwise conv (K=31, pad 15) + bias + DoubleSwish; bf16 in -> bf16 out
// ---------------------------------------------------------------------------
__global__ __launch_bounds__(256) void dwconv_kernel(
    const unsigned short* __restrict__ g, const float* __restrict__ w_dw,
    const float* __restrict__ b_dw, unsigned short* __restrict__ out)
{
    int idx = blockIdx.x * 256 + threadIdx.x;
    int c = idx & 511;
    int r = idx >> 9;
    int nn = r & 3, l = r >> 2;
    float acc = b_dw[c];
#pragma unroll
    for (int kk = 0; kk < 31; kk++) {
        int l2 = l + kk - 15;
        if (l2 >= 0 && l2 < 1024)
            acc += bf2f(g[(((size_t)l2 * 4 + nn) << 9) + c]) * w_dw[c * 31 + kk];
    }
    out[idx] = f2bf(acc * sigmoidf_(acc - 1.f));
}

// ---------------------------------------------------------------------------
// BasicNorm
// ---------------------------------------------------------------------------
__global__ __launch_bounds__(256) void norm_kernel(
    const float* __restrict__ x, const float* __restrict__ eps_p,
    float* __restrict__ out)
{
    int r = blockIdx.x, t = threadIdx.x;
    float a = x[(size_t)r * 512 + t];
    float b = x[(size_t)r * 512 + 256 + t];
    float ss = a * a + b * b;
#pragma unroll
    for (int d = 1; d < 64; d <<= 1) ss += __shfl_xor(ss, d);
    __shared__ float red[4];
    if ((t & 63) == 0) red[t >> 6] = ss;
    __syncthreads();
    float tot = red[0] + red[1] + red[2] + red[3];
    float scale = rsqrtf(tot * (1.f / 512.f) + __expf(eps_p[0]));
    out[(size_t)r * 512 + t] = a * scale;
    out[(size_t)r * 512 + 256 + t] = b * scale;
}

// ---------------------------------------------------------------------------
extern "C" void kernel_launch(void* const* d_in, const int* in_sizes, int n_in,
                              void* d_out, int out_size, void* d_ws, size_t ws_size,
                              hipStream_t stream)
{
    const float* src   = (const float*)d_in[0];
    const float* pos   = (const float*)d_in[1];
    const float* as_   = (const float*)d_in[2];
    const float* w_in  = (const float*)d_in[3];
    const float* b_in  = (const float*)d_in[4];
    const float* w_pos = (const float*)d_in[5];
    const float* pbu   = (const float*)d_in[6];
    const float* pbv   = (const float*)d_in[7];
    const float* prin  = (const float*)d_in[8];
    const float* prout = (const float*)d_in[9];
    const float* w_out = (const float*)d_in[10];
    const float* b_out = (const float*)d_in[11];
    const float* w_ff1m = (const float*)d_in[12];
    const float* b_ff1m = (const float*)d_in[13];
    const float* w_ff2m = (const float*)d_in[14];
    const float* b_ff2m = (const float*)d_in[15];
    const float* w_ff1 = (const float*)d_in[16];
    const float* b_ff1 = (const float*)d_in[17];
    const float* w_ff2 = (const float*)d_in[18];
    const float* b_ff2 = (const float*)d_in[19];
    const float* w_pw1 = (const float*)d_in[20];
    const float* b_pw1 = (const float*)d_in[21];
    const float* w_dw  = (const float*)d_in[22];
    const float* b_dw  = (const float*)d_in[23];
    const float* w_pw2 = (const float*)d_in[24];
    const float* b_pw2 = (const float*)d_in[25];
    const float* neps  = (const float*)d_in[26];

    float* out_x = (float*)d_out;
    float* out_s = (float*)d_out + 2097152;

    // ---- workspace layout (float units) ----
    float* ws = (float*)d_ws;
    float* xbuf = ws;                               // 2,097,152
    float* U    = xbuf + 2097152;                   // 6,291,456
    float* sbbf = U + 6291456;                      // 1,048,576
    float* xb16f= sbbf + 1048576;                   // 1,048,576
    float* qkvb = xb16f + 1048576;                  // 3,145,728 (p2b region)
    float* qu   = qkvb + 3145728;                   // 1,048,576 (later ctxb)
    float* qv   = qu + 1048576;                     // 1,048,576
    float* kbuf = qv + 1048576;                     // 1,048,576
    float* vbuf = kbuf + 1048576;                   // 1,048,576 (vt bf16)
    float* pbuf = vbuf + 1048576;                   // 524,288
    float* posbf= pbuf + 524288;                    // 524,288
    float* totf = posbf + 524288;                   // 16,777,216
    float* Wreg = totf + 16777216;                  // weights bf16 region

    unsigned short* hb16  = (unsigned short*)U;
    unsigned short* gbuf  = (unsigned short*)(U + 4194304);
    unsigned short* sbb   = (unsigned short*)sbbf;
    unsigned short* dbufb = (unsigned short*)sbbf;
    unsigned short* xb16  = (unsigned short*)xb16f;
    unsigned short* ctxb  = (unsigned short*)qu;
    unsigned short* posb  = (unsigned short*)posbf;
    unsigned short* totb  = (unsigned short*)totf;
    unsigned short* vt    = (unsigned short*)vbuf;
    unsigned short* qub   = (unsigned short*)qu;
    unsigned short* qvb   = (unsigned short*)qv;
    unsigned short* kb    = (unsigned short*)kbuf;
    unsigned short* p2b   = (unsigned short*)qkvb;

    // per-weight bf16 buffers
    float* wp = Wreg;
    unsigned short* wff1m_b = (unsigned short*)wp; wp += 524288;
    unsigned short* wff2m_b = (unsigned short*)wp; wp += 524288;
    unsigned short* win_b   = (unsigned short*)wp; wp += 196608;
    unsigned short* wpos_b  = (unsigned short*)wp; wp += 65536;
    unsigned short* wout_b  = (unsigned short*)wp; wp += 65536;
    unsigned short* wpw1_b  = (unsigned short*)wp; wp += 262144;
    unsigned short* wpw2_b  = (unsigned short*)wp; wp += 131072;
    unsigned short* wff1_b  = (unsigned short*)wp; wp += 524288;
    unsigned short* wff2_b  = (unsigned short*)wp; wp += 524288;

    dim3 blk(256);
    const int M = 4096;

    // --- one mega-cast for src, pos, and all weights ---
    {
        CastJobs jobs;
        const float* srcs[11] = {src, pos, w_ff1m, w_ff2m, w_in, w_pos,
                                 w_out, w_pw1, w_pw2, w_ff1, w_ff2};
        unsigned short* dsts[11] = {sbb, posb, wff1m_b, wff2m_b, win_b, wpos_b,
                                    wout_b, wpw1_b, wpw2_b, wff1_b, wff2_b};
        int n4s[11] = {524288, 262016, 262144, 262144, 98304, 32768,
                       32768, 131072, 65536, 262144, 262144};
        int cum = 0;
        for (int s = 0; s < 11; s++) {
            jobs.src[s] = (const float4*)srcs[s];
            jobs.dst[s] = (ushort4*)dsts[s];
            cum += n4s[s];
            jobs.end[s] = cum;
        }
        cast_all_kernel<<<(cum + 255) / 256, blk, 0, stream>>>(jobs, cum);
    }

    // --- macaron FFN ---
    mfma_gemm<1,0,0,1><<<dim3(16, 32), blk, 0, stream>>>(
        sbb, wff1m_b, b_ff1m, nullptr, nullptr, hb16, M, 2048, 512);
    mfma_gemm_n64<0,1,1,1><<<dim3(8, 32), blk, 0, stream>>>(
        hb16, wff2m_b, b_ff2m, src, xbuf, xb16, M, 512, 2048);

    // --- attention ---
    mfma_gemm_qkv<<<dim3(12, 32), blk, 0, stream>>>(
        xb16, win_b, b_in, pbu, pbv, qub, qvb, kb, vt);
    mfma_gemm<0,0,1,0><<<dim3(2, 16), blk, 0, stream>>>(
        posb, wpos_b, nullptr, nullptr, pbuf, nullptr, 2047, 256, 512);
    repack_p_kernel<<<2047, blk, 0, stream>>>(pbuf, p2b);
    scores_kernel<<<dim3(16, 16, 32), blk, 0, stream>>>(qub, qvb, kb, p2b, totb);
    attn_finish_kernel<<<4096, blk, 0, stream>>>(totb, as_, prin, prout, out_s);
    ctx_mfma_kernel<<<dim3(8, 32), blk, 0, stream>>>(totb, vt, ctxb);
    mfma_gemm_n64<0,1,1,1><<<dim3(8, 32), blk, 0, stream>>>(
        ctxb, wout_b, b_out, xbuf, xbuf, xb16, M, 512, 256);

    // --- conv module ---
    mfma_gemm<0,0,0,1><<<dim3(8, 32), blk, 0, stream>>>(
        xb16, wpw1_b, b_pw1, nullptr, nullptr, hb16, M, 1024, 512);
    glu_kernel<<<2048, blk, 0, stream>>>(hb16, gbuf);
    dwconv_kernel<<<8192, blk, 0, stream>>>(gbuf, w_dw, b_dw, dbufb);
    mfma_gemm_n64<0,1,1,1><<<dim3(8, 32), blk, 0, stream>>>(
        dbufb, wpw2_b, b_pw2, xbuf, xbuf, xb16, M, 512, 512);

    // --- final FFN + BasicNorm ---
    mfma_gemm<1,0,0,1><<<dim3(16, 32), blk, 0, stream>>>(
        xb16, wff1_b, b_ff1, nullptr, nullptr, hb16, M, 2048, 512);
    mfma_gemm_n64<0,1,1,0><<<dim3(8, 32), blk, 0, stream>>>(
        hb16, wff2_b, b_ff2, xbuf, xbuf, nullptr, M, 512, 2048);
    norm_kernel<<<4096, blk, 0, stream>>>(xbuf, neps, out_x);
}